// Round 5
// baseline (1909.285 us; speedup 1.0000x reference)
//
#include <hip/hip_runtime.h>
#include <math.h>

#define CDIM  128
#define NHEAD 8
#define DHEAD 16
#define NPAT  50000
#define NICD  591
#define NNDC  2042
#define OUTN  90
#define NEDGE 250000
#define NLAYER 2
#define EPB   128   // edges per block in seg_agg

// concat offsets for CSR build (relation order: pi, ip, pn, np; dst sizes)
#define OFF0  0
#define OFF1  (NICD)
#define OFF2  (NICD + NPAT)
#define OFF3  (NICD + NPAT + NNDC)
#define NTOT  (NICD + NPAT + NNDC + NPAT)
#define GRPSZ ((4 * NEDGE) / 8)   // 125000 positions per scatter group

__device__ __forceinline__ float gelu_tanh(float x) {
    float x3 = x * x * x;
    return 0.5f * x * (1.0f + tanhf(0.7978845608028654f * (x + 0.044715f * x3)));
}

// ---------------------------------------------------------------------------
// Generic fp32 GEMM: C = act(A[MxK=128] @ W[128xN] + bias), optional gelu on A
// load, optional learned-skip combine: C = a*o + (1-a)*xold, a=sigmoid(skip).
// Tile 64x64, 256 threads, 4x4 micro-tile per thread.
// ---------------------------------------------------------------------------
__global__ __launch_bounds__(256) void gemm_k128(
    const float* __restrict__ A, const float* __restrict__ W,
    const float* __restrict__ bias, float* __restrict__ Co,
    int M, int N, int gelu_in, int act,          // act: 0 none, 1 relu, 2 sigmoid
    const float* __restrict__ xold, const float* __restrict__ skipv, int skipidx)
{
    __shared__ float As[16][68];
    __shared__ float Ws[16][68];
    int bm = blockIdx.x * 64, bn = blockIdx.y * 64;
    int tl = threadIdx.x;
    int tx = tl & 15, ty = tl >> 4;
    float acc[4][4] = {};

    for (int k0 = 0; k0 < 128; k0 += 16) {
        {
            int am = tl >> 2;            // 0..63
            int ak = (tl & 3) * 4;       // 0,4,8,12
            int row = bm + am;
            float4 v = make_float4(0.f, 0.f, 0.f, 0.f);
            if (row < M) v = *(const float4*)(A + (size_t)row * 128 + k0 + ak);
            if (gelu_in) { v.x = gelu_tanh(v.x); v.y = gelu_tanh(v.y);
                           v.z = gelu_tanh(v.z); v.w = gelu_tanh(v.w); }
            As[ak + 0][am] = v.x; As[ak + 1][am] = v.y;
            As[ak + 2][am] = v.z; As[ak + 3][am] = v.w;
        }
        {
            int wk = tl >> 4;            // 0..15
            int wn = (tl & 15) * 4;      // 0..60
            int col = bn + wn;
            float4 v = make_float4(0.f, 0.f, 0.f, 0.f);
            const float* wp = W + (size_t)(k0 + wk) * N;
            if (((N & 3) == 0) && (col + 3) < N) {
                v = *(const float4*)(wp + col);
            } else {
                if (col     < N) v.x = wp[col];
                if (col + 1 < N) v.y = wp[col + 1];
                if (col + 2 < N) v.z = wp[col + 2];
                if (col + 3 < N) v.w = wp[col + 3];
            }
            Ws[wk][wn] = v.x; Ws[wk][wn + 1] = v.y;
            Ws[wk][wn + 2] = v.z; Ws[wk][wn + 3] = v.w;
        }
        __syncthreads();
        #pragma unroll
        for (int kk = 0; kk < 16; kk++) {
            float4 av = *(const float4*)&As[kk][ty * 4];
            float4 wv = *(const float4*)&Ws[kk][tx * 4];
            float a_[4] = {av.x, av.y, av.z, av.w};
            float w_[4] = {wv.x, wv.y, wv.z, wv.w};
            #pragma unroll
            for (int i = 0; i < 4; i++)
                #pragma unroll
                for (int j = 0; j < 4; j++)
                    acc[i][j] += a_[i] * w_[j];
        }
        __syncthreads();
    }

    float aSk = 0.f, oneM = 0.f;
    if (skipv) {
        float sv = skipv[skipidx];
        aSk = 1.0f / (1.0f + expf(-sv));
        oneM = 1.0f - aSk;
    }
    for (int i = 0; i < 4; i++) {
        int row = bm + ty * 4 + i;
        if (row >= M) break;
        for (int j = 0; j < 4; j++) {
            int col = bn + tx * 4 + j;
            if (col >= N) continue;
            float v = acc[i][j] + (bias ? bias[col] : 0.f);
            if (act == 1) v = fmaxf(v, 0.f);
            else if (act == 2) v = 1.0f / (1.0f + expf(-v));
            if (skipv) v = aSk * v + oneM * xold[(size_t)row * N + col];
            Co[(size_t)row * N + col] = v;
        }
    }
}

// ---------------------------------------------------------------------------
// Batched CSR build over all 4 relations in one concatenated degree array.
// Each relation has exactly NEDGE edges, so the concat exclusive scan S gives
// relation-local rowptr as S - r*NEDGE, and S itself is the scatter cursor
// into one 4*NEDGE dst-sorted packed (src,dst) edge array.
// ---------------------------------------------------------------------------
__global__ void hist4_kernel(const int* __restrict__ d0, const int* __restrict__ d1,
                             const int* __restrict__ d2, const int* __restrict__ d3,
                             int* __restrict__ deg) {
    int t = blockIdx.x * blockDim.x + threadIdx.x;
    if (t >= 4 * NEDGE) return;
    int r = t / NEDGE, e = t - r * NEDGE;
    const int* dp = (r == 0) ? d0 : (r == 1) ? d1 : (r == 2) ? d2 : d3;
    int off = (r == 0) ? OFF0 : (r == 1) ? OFF1 : (r == 2) ? OFF2 : OFF3;
    atomicAdd(&deg[off + dp[e]], 1);
}

// Phase A: per-1024-chunk sums (256 thr x 4 elems)
__global__ __launch_bounds__(256) void scanA_kernel(
    const int* __restrict__ deg, int* __restrict__ part, int n)
{
    __shared__ int red[256];
    int b = blockIdx.x, t = threadIdx.x;
    int base = b * 1024 + t * 4;
    int s = 0;
    if (base + 3 < n) {
        int4 v = *(const int4*)(deg + base);
        s = v.x + v.y + v.z + v.w;
    } else {
        for (int i = 0; i < 4; i++) if (base + i < n) s += deg[base + i];
    }
    red[t] = s;
    __syncthreads();
    for (int o = 128; o; o >>= 1) { if (t < o) red[t] += red[t + o]; __syncthreads(); }
    if (t == 0) part[b] = red[0];
}

// Phase B: exclusive scan of block partials (nb <= 256)
__global__ __launch_bounds__(128) void scanB_kernel(int* __restrict__ part, int nb)
{
    __shared__ int s[256];
    int t = threadIdx.x;
    for (int i = t; i < nb; i += 128) s[i] = part[i];
    __syncthreads();
    if (t == 0) { int run = 0; for (int i = 0; i < nb; i++) { int v = s[i]; s[i] = run; run += v; } }
    __syncthreads();
    for (int i = t; i < nb; i += 128) part[i] = s[i];
}

// Phase C: in-chunk exclusive scan + base; writes cursor + pristine base copy
// (for the scatter's group test) and relation-local rowptrs (S - r*NEDGE).
__global__ __launch_bounds__(256) void scanC_kernel(
    const int* __restrict__ deg, const int* __restrict__ part,
    int* __restrict__ rp0, int* __restrict__ rp1,
    int* __restrict__ rp2, int* __restrict__ rp3,
    int* __restrict__ cursor, int* __restrict__ baseA, int n)
{
    __shared__ int red[256];
    int b = blockIdx.x, t = threadIdx.x;
    int base = b * 1024 + t * 4;
    int v[4] = {0, 0, 0, 0};
    if (base + 3 < n) {
        int4 q = *(const int4*)(deg + base);
        v[0] = q.x; v[1] = q.y; v[2] = q.z; v[3] = q.w;
    } else {
        for (int i = 0; i < 4; i++) if (base + i < n) v[i] = deg[base + i];
    }
    red[t] = v[0] + v[1] + v[2] + v[3];
    __syncthreads();
    for (int off = 1; off < 256; off <<= 1) {
        int y = (t >= off) ? red[t - off] : 0;
        __syncthreads();
        red[t] += y;
        __syncthreads();
    }
    int run = part[b] + ((t == 0) ? 0 : red[t - 1]);
    for (int i = 0; i < 4; i++) {
        int g = base + i;
        if (g < n) {
            cursor[g] = run;
            baseA[g]  = run;
            int r, loc;
            if      (g < OFF1) { r = 0; loc = g; }
            else if (g < OFF2) { r = 1; loc = g - OFF1; }
            else if (g < OFF3) { r = 2; loc = g - OFF2; }
            else               { r = 3; loc = g - OFF3; }
            int Sl = run - r * NEDGE;
            ((r == 0) ? rp0 : (r == 1) ? rp1 : (r == 2) ? rp2 : rp3)[loc] = Sl;
            run += v[i];
        }
    }
    if (b == 0 && t == 0) {
        rp0[NICD] = NEDGE; rp1[NPAT] = NEDGE; rp2[NNDC] = NEDGE; rp3[NPAT] = NEDGE;
    }
}

// Group-partitioned packed scatter: block handles group (blockIdx&7) == the
// 125000-position output window whose lines its XCD's L2 can own exclusively
// (consecutive blockIdx round-robin across the 8 XCDs). Non-matching edges
// are skipped; dst/base reads are cache-resident so the 8x read is cheap.
__global__ __launch_bounds__(256) void scatter_pack_kernel(
    const int* __restrict__ s0, const int* __restrict__ d0,
    const int* __restrict__ s1, const int* __restrict__ d1,
    const int* __restrict__ s2, const int* __restrict__ d2,
    const int* __restrict__ s3, const int* __restrict__ d3,
    const int* __restrict__ baseA, int* __restrict__ cursor,
    int2* __restrict__ es)
{
    int grp = blockIdx.x & 7;
    int nch = (4 * NEDGE + 255) / 256;
    int step = gridDim.x >> 3;
    for (int c = blockIdx.x >> 3; c < nch; c += step) {
        int t = c * 256 + threadIdx.x;
        if (t >= 4 * NEDGE) continue;
        int r = t / NEDGE, e = t - r * NEDGE;
        const int* dp = (r == 0) ? d0 : (r == 1) ? d1 : (r == 2) ? d2 : d3;
        int off = (r == 0) ? OFF0 : (r == 1) ? OFF1 : (r == 2) ? OFF2 : OFF3;
        int d = dp[e];
        int bp = baseA[off + d];
        if (bp / GRPSZ != grp) continue;
        const int* sp = (r == 0) ? s0 : (r == 1) ? s1 : (r == 2) ? s2 : s3;
        int p = atomicAdd(&cursor[off + d], 1);   // p includes r*NEDGE base
        es[p] = make_int2(sp[e], d);
    }
}

// ---------------------------------------------------------------------------
// x = relu(emb[idx]) gather
// ---------------------------------------------------------------------------
__global__ void gather_relu_kernel(const float* __restrict__ emb,
                                   const int* __restrict__ idx,
                                   float* __restrict__ out, int n) {
    int t = blockIdx.x * blockDim.x + threadIdx.x;
    if (t < n * CDIM) {
        int r = t >> 7, c = t & 127;
        out[t] = fmaxf(emb[(size_t)idx[r] * CDIM + c], 0.f);
    }
}

// ---------------------------------------------------------------------------
// kr[n,h,e] = sum_d k[n,h,d] * arel[h,d,e]   (per-head 16x16 transform)
// 256 threads, 2 rows per barrier.
// ---------------------------------------------------------------------------
__global__ __launch_bounds__(256) void rel_transform_kernel(
    const float* __restrict__ kin, const float* __restrict__ arel,
    float* __restrict__ kout, int n)
{
    __shared__ float aS[NHEAD * DHEAD * DHEAD];   // 2048
    __shared__ float rowS[2][CDIM];
    int t = threadIdx.x;
    for (int i = t; i < NHEAD * DHEAD * DHEAD; i += 256) aS[i] = arel[i];
    __syncthreads();
    int rl = t >> 7;          // 0..1
    int c  = t & 127;
    int h = c >> 4, e = c & 15;
    const float* ah = &aS[h * 256 + e];
    for (int row0 = blockIdx.x * 2; row0 < n; row0 += gridDim.x * 2) {
        int row = row0 + rl;
        rowS[rl][c] = (row < n) ? kin[(size_t)row * CDIM + c] : 0.f;
        __syncthreads();
        float acc = 0.f;
        const float* rp = &rowS[rl][h * 16];
        #pragma unroll
        for (int dd = 0; dd < 16; ++dd) acc += rp[dd] * ah[dd * 16];
        if (row < n) kout[(size_t)row * CDIM + c] = acc;
        __syncthreads();
    }
}

// ---------------------------------------------------------------------------
// alpha_s[i,h] = (q[dst[i],h,:] . kr[src[i],h,:]) * p_rel[h] / sqrt(D)
// edges come packed (src,dst) in dst-sorted order.
// ---------------------------------------------------------------------------
__global__ __launch_bounds__(256) void edge_logits_kernel(
    const int2* __restrict__ es,
    const float* __restrict__ q, const float* __restrict__ kr,
    const float* __restrict__ prel, float* __restrict__ alpha_s)
{
    int t = blockIdx.x * blockDim.x + threadIdx.x;
    if (t >= NEDGE * NHEAD) return;
    int i = t >> 3, h = t & 7;
    int2 ed = es[i];
    const float4* qp = (const float4*)(q  + (size_t)ed.y * CDIM + h * DHEAD);
    const float4* kp = (const float4*)(kr + (size_t)ed.x * CDIM + h * DHEAD);
    float acc = 0.f;
    #pragma unroll
    for (int k = 0; k < 4; k++) {
        float4 a = qp[k], b = kp[k];
        acc += a.x * b.x + a.y * b.y + a.z * b.z + a.w * b.w;
    }
    alpha_s[t] = acc * prel[h] * 0.25f;
}

// ---------------------------------------------------------------------------
// Segment softmax stats: one WAVE per dst node, all 8 heads at once.
// lane = j*8+h reads alpha_s[(r0+j)*8+h] -> fully coalesced 256B per iter.
// Reduce across j (lane bits 3..5). stats[d*8+h] = {m, 1/s}.
// ---------------------------------------------------------------------------
__global__ __launch_bounds__(256) void seg_stats_kernel(
    const int* __restrict__ rowptr, const float* __restrict__ alpha_s,
    float2* __restrict__ stats, int nd)
{
    int wid = (blockIdx.x * 256 + threadIdx.x) >> 6;   // wave id == dst node
    int lane = threadIdx.x & 63;
    if (wid >= nd) return;
    int r0 = rowptr[wid], r1 = rowptr[wid + 1];
    int h = lane & 7, j = lane >> 3;
    float mx = -1e30f;
    for (int i = r0 + j; i < r1; i += 8)
        mx = fmaxf(mx, alpha_s[(size_t)i * NHEAD + h]);
    mx = fmaxf(mx, __shfl_xor(mx, 8));
    mx = fmaxf(mx, __shfl_xor(mx, 16));
    mx = fmaxf(mx, __shfl_xor(mx, 32));
    float sm = 0.f;
    for (int i = r0 + j; i < r1; i += 8)
        sm += expf(alpha_s[(size_t)i * NHEAD + h] - mx);
    sm += __shfl_xor(sm, 8);
    sm += __shfl_xor(sm, 16);
    sm += __shfl_xor(sm, 32);
    if (j == 0)
        stats[(size_t)wid * NHEAD + h] = make_float2(mx, (sm > 0.f) ? 1.0f / sm : 0.f);
}

// ---------------------------------------------------------------------------
// Edge-chunk-parallel weighted segment sum over dst-sorted edges. Staging
// threads read 8 weights with two float4 loads; 128 channel-threads accumulate
// per dst-run, flushing with atomicAdd only at run boundaries.
// ---------------------------------------------------------------------------
__global__ __launch_bounds__(128) void seg_agg_kernel(
    const int2* __restrict__ es,
    const float* __restrict__ alpha_s, const float2* __restrict__ stats,
    const float* __restrict__ vr, float* __restrict__ agg, int ne)
{
    __shared__ int   sSrc[EPB];
    __shared__ int   sDst[EPB];
    __shared__ float sW[EPB][NHEAD];
    int i0 = blockIdx.x * EPB;
    int t  = threadIdx.x;
    int cnt = min(EPB, ne - i0);
    if (t < cnt) {
        int2 ed = es[i0 + t];
        sSrc[t] = ed.x;
        sDst[t] = ed.y;
        const float4* ap = (const float4*)(alpha_s + (size_t)(i0 + t) * NHEAD);
        float4 a0 = ap[0], a1 = ap[1];
        float w[8] = {a0.x, a0.y, a0.z, a0.w, a1.x, a1.y, a1.z, a1.w};
        const float2* st = stats + (size_t)ed.y * NHEAD;
        #pragma unroll
        for (int h = 0; h < NHEAD; h++) {
            float2 ms = st[h];
            sW[t][h] = expf(w[h] - ms.x) * ms.y;
        }
    }
    __syncthreads();
    int h = t >> 4;
    float acc = 0.f;
    int curd = sDst[0];
    for (int i = 0; i < cnt; i++) {
        int d = sDst[i];
        if (d != curd) {
            atomicAdd(&agg[(size_t)curd * CDIM + t], acc);
            acc = 0.f;
            curd = d;
        }
        acc += vr[(size_t)sSrc[i] * CDIM + t] * sW[i][h];
    }
    atomicAdd(&agg[(size_t)curd * CDIM + t], acc);
}

// ---------------------------------------------------------------------------
extern "C" void kernel_launch(void* const* d_in, const int* in_sizes, int n_in,
                              void* d_out, int out_size, void* d_ws, size_t ws_size,
                              hipStream_t stream)
{
    const float* x_patient = (const float*)d_in[0];
    const float* w_in      = (const float*)d_in[1];
    const float* b_in      = (const float*)d_in[2];
    const float* emb_icd   = (const float*)d_in[3];
    const float* emb_ndc   = (const float*)d_in[4];
    const float* kw        = (const float*)d_in[5];
    const float* kbias     = (const float*)d_in[6];
    const float* qw        = (const float*)d_in[7];
    const float* qbias     = (const float*)d_in[8];
    const float* vw        = (const float*)d_in[9];
    const float* vbias     = (const float*)d_in[10];
    const float* aw        = (const float*)d_in[11];
    const float* abias     = (const float*)d_in[12];
    const float* skip      = (const float*)d_in[13];
    const float* a_rel     = (const float*)d_in[14];
    const float* m_rel     = (const float*)d_in[15];
    const float* p_rel     = (const float*)d_in[16];
    const float* w_out     = (const float*)d_in[17];
    const float* b_out     = (const float*)d_in[18];
    const int*   x_icd     = (const int*)d_in[19];
    const int*   x_ndc     = (const int*)d_in[20];
    const int* esrc[4] = {(const int*)d_in[21], (const int*)d_in[23],
                          (const int*)d_in[25], (const int*)d_in[27]};
    const int* edst[4] = {(const int*)d_in[22], (const int*)d_in[24],
                          (const int*)d_in[26], (const int*)d_in[28]};

    const int st_[4] = {0, 1, 0, 2};
    const int dt_[4] = {1, 0, 2, 0};
    const int sizes[3] = {NPAT, NICD, NNDC};

    char* p = (char*)d_ws;
    auto alloc = [&](size_t bytes) -> void* {
        void* r = (void*)p;
        p += (bytes + 255) & ~(size_t)255;
        return r;
    };

    float *x[3], *kbuf[3], *qbuf[3], *vbuf[3];
    for (int t = 0; t < 3; t++) x[t]    = (float*)alloc((size_t)sizes[t] * CDIM * 4);
    for (int t = 0; t < 3; t++) kbuf[t] = (float*)alloc((size_t)sizes[t] * CDIM * 4);
    for (int t = 0; t < 3; t++) qbuf[t] = (float*)alloc((size_t)sizes[t] * CDIM * 4);
    for (int t = 0; t < 3; t++) vbuf[t] = (float*)alloc((size_t)sizes[t] * CDIM * 4);
    float* aggbase = (float*)alloc((size_t)(NPAT + NICD + NNDC) * CDIM * 4);
    float* agg[3];
    agg[0] = aggbase;
    agg[1] = aggbase + (size_t)NPAT * CDIM;
    agg[2] = agg[1] + (size_t)NICD * CDIM;
    float*  krbuf    = (float*)alloc((size_t)NPAT * CDIM * 4);
    float*  vrbuf    = (float*)alloc((size_t)NPAT * CDIM * 4);
    float*  alphabuf = (float*)alloc((size_t)NEDGE * NHEAD * 4);
    float2* statsbuf = (float2*)alloc((size_t)NPAT * NHEAD * 8);
    int2* esbig = (int2*)alloc((size_t)4 * NEDGE * 8);
    int* rowptr[4];
    rowptr[0] = (int*)alloc((size_t)(NICD + 1) * 4);
    rowptr[1] = (int*)alloc((size_t)(NPAT + 1) * 4);
    rowptr[2] = (int*)alloc((size_t)(NNDC + 1) * 4);
    rowptr[3] = (int*)alloc((size_t)(NPAT + 1) * 4);
    int* deg    = (int*)alloc((size_t)NTOT * 4);
    int* cursor = (int*)alloc((size_t)NTOT * 4);
    int* baseA  = (int*)alloc((size_t)NTOT * 4);
    int* part   = (int*)alloc((size_t)256 * 4);
    int2* esRel[4];
    for (int r = 0; r < 4; r++) esRel[r] = esbig + (size_t)r * NEDGE;

    auto gemm = [&](const float* A, const float* W, const float* bias, float* Co,
                    int M, int N, int gelu_in, int act,
                    const float* xold, const float* skipv, int skipidx) {
        dim3 grid((M + 63) / 64, (N + 63) / 64);
        gemm_k128<<<grid, dim3(256), 0, stream>>>(A, W, bias, Co, M, N,
                                                  gelu_in, act, xold, skipv, skipidx);
    };

    // ---- batched CSR build (by dst), once per launch, reused by both layers ----
    {
        const int NB = (NTOT + 1023) / 1024;   // 101
        hipMemsetAsync(deg, 0, (size_t)NTOT * 4, stream);
        hist4_kernel<<<(4 * NEDGE + 255) / 256, 256, 0, stream>>>(
            edst[0], edst[1], edst[2], edst[3], deg);
        scanA_kernel<<<NB, 256, 0, stream>>>(deg, part, NTOT);
        scanB_kernel<<<1, 128, 0, stream>>>(part, NB);
        scanC_kernel<<<NB, 256, 0, stream>>>(deg, part,
            rowptr[0], rowptr[1], rowptr[2], rowptr[3], cursor, baseA, NTOT);
        scatter_pack_kernel<<<8192, 256, 0, stream>>>(
            esrc[0], edst[0], esrc[1], edst[1], esrc[2], edst[2], esrc[3], edst[3],
            baseA, cursor, esbig);
    }

    // ---- input projections ----
    gemm(x_patient, w_in, b_in, x[0], NPAT, 128, 0, 1, nullptr, nullptr, 0);
    gather_relu_kernel<<<(NICD * CDIM + 255) / 256, 256, 0, stream>>>(emb_icd, x_icd, x[1], NICD);
    gather_relu_kernel<<<(NNDC * CDIM + 255) / 256, 256, 0, stream>>>(emb_ndc, x_ndc, x[2], NNDC);

    // ---- layers ----
    for (int l = 0; l < NLAYER; l++) {
        for (int t = 0; t < 3; t++) {
            int wi = l * 3 + t;
            gemm(x[t], kw + (size_t)wi * 16384, kbias + (size_t)wi * 128,
                 kbuf[t], sizes[t], 128, 0, 0, nullptr, nullptr, 0);
            gemm(x[t], qw + (size_t)wi * 16384, qbias + (size_t)wi * 128,
                 qbuf[t], sizes[t], 128, 0, 0, nullptr, nullptr, 0);
            gemm(x[t], vw + (size_t)wi * 16384, vbias + (size_t)wi * 128,
                 vbuf[t], sizes[t], 128, 0, 0, nullptr, nullptr, 0);
        }
        hipMemsetAsync(aggbase, 0, (size_t)(NPAT + NICD + NNDC) * CDIM * 4, stream);
        for (int r = 0; r < 4; r++) {
            int s = st_[r], d = dt_[r];
            int ns = sizes[s], nd = sizes[d];
            int grid_rt = min((ns + 1) / 2, 2048);
            rel_transform_kernel<<<grid_rt, 256, 0, stream>>>(
                kbuf[s], a_rel + (size_t)(l * 4 + r) * 2048, krbuf, ns);
            rel_transform_kernel<<<grid_rt, 256, 0, stream>>>(
                vbuf[s], m_rel + (size_t)(l * 4 + r) * 2048, vrbuf, ns);
            edge_logits_kernel<<<(NEDGE * NHEAD + 255) / 256, 256, 0, stream>>>(
                esRel[r], qbuf[d], krbuf,
                p_rel + (size_t)(l * 4 + r) * NHEAD, alphabuf);
            seg_stats_kernel<<<(nd + 3) / 4, 256, 0, stream>>>(
                rowptr[r], alphabuf, statsbuf, nd);
            seg_agg_kernel<<<(NEDGE + EPB - 1) / EPB, 128, 0, stream>>>(
                esRel[r], alphabuf, statsbuf, vrbuf, agg[d], NEDGE);
        }
        for (int t = 0; t < 3; t++) {
            int wi = l * 3 + t;
            gemm(agg[t], aw + (size_t)wi * 16384, abias + (size_t)wi * 128,
                 x[t], sizes[t], 128, 1, 0, x[t], skip, wi);
        }
    }

    // ---- output head ----
    gemm(x[0], w_out, b_out, (float*)d_out, NPAT, OUTN, 0, 2, nullptr, nullptr, 0);
}

// Round 6
// 1349.909 us; speedup vs baseline: 1.4144x; 1.4144x over previous
//
#include <hip/hip_runtime.h>
#include <math.h>

#define CDIM  128
#define NHEAD 8
#define DHEAD 16
#define NPAT  50000
#define NICD  591
#define NNDC  2042
#define OUTN  90
#define NEDGE 250000
#define NLAYER 2
#define EPB   128

// concat offsets for CSR build (relation order: pi, ip, pn, np; dst sizes)
#define OFF0  0
#define OFF1  (NICD)
#define OFF2  (NICD + NPAT)
#define OFF3  (NICD + NPAT + NNDC)
#define NTOT  (NICD + NPAT + NNDC + NPAT)

#define LDP 40   // LDS row stride (bf16 elems): 80B rows -> 16B aligned, 2-way-free banks

typedef __attribute__((ext_vector_type(8))) short bf16x8;
typedef __attribute__((ext_vector_type(4))) float f32x4;

__device__ __forceinline__ float gelu_tanh(float x) {
    float x3 = x * x * x;
    return 0.5f * x * (1.0f + tanhf(0.7978845608028654f * (x + 0.044715f * x3)));
}
__device__ __forceinline__ float b2f(unsigned short u) {
    union { unsigned int i; float f; } v; v.i = ((unsigned int)u) << 16; return v.f;
}
__device__ __forceinline__ unsigned short f2b(float f) {
    union { float ff; unsigned int i; } v; v.ff = f;
    unsigned int i = v.i;
    return (unsigned short)((i + 0x7FFFu + ((i >> 16) & 1u)) >> 16);  // RNE
}
__device__ __forceinline__ float2 b2x2(unsigned int u) {
    union { unsigned int i; float f; } lo, hi;
    lo.i = u << 16; hi.i = u & 0xFFFF0000u;
    return make_float2(lo.f, hi.f);
}

// ---------------------------------------------------------------------------
// bf16 MFMA GEMM: D = act(A[MxK=128] @ Wt^T + bias), Wt stored [N][128] bf16.
// a_mode: 0 = A bf16[M][lda]; 1 = A fp32; 2 = A fp32 + gelu on load.
// c_mode: 0 = bf16 out; 1 = fp32 out. act: 0 none, 1 relu, 2 sigmoid.
// Optional learned-skip: D = a*o + (1-a)*xold(bf16), a = sigmoid(skipv[skipidx]).
// 64x64 tile, 256 thr (4 waves), each wave 2x2 of 16x16x32 MFMA, K in 4 steps.
// ---------------------------------------------------------------------------
__global__ __launch_bounds__(256) void gemm_mfma(
    const void* __restrict__ Ap, int a_mode, int lda,
    const unsigned short* __restrict__ Wt, const float* __restrict__ bias,
    void* __restrict__ Cp, int c_mode, int ldc,
    int M, int N, int act,
    const unsigned short* __restrict__ xold, int ldx,
    const float* __restrict__ skipv, int skipidx)
{
    __shared__ unsigned short Al[64 * LDP];
    __shared__ unsigned short Bl[64 * LDP];
    int bm = blockIdx.x * 64, bn = blockIdx.y * 64;
    int t = threadIdx.x;
    int lane = t & 63, w = t >> 6;
    int wr = w >> 1, wc = w & 1;
    int quad = lane >> 4, lm = lane & 15;
    f32x4 acc[2][2] = {};
    const int srow = t >> 2;
    const int skq  = (t & 3) * 8;

    for (int k0 = 0; k0 < 128; k0 += 32) {
        // stage A (64 rows x 32 k)
        {
            int row = bm + srow;
            uint4 u = make_uint4(0, 0, 0, 0);
            if (a_mode == 0) {
                if (row < M)
                    u = *(const uint4*)((const unsigned short*)Ap + (size_t)row * lda + k0 + skq);
            } else {
                float f[8] = {0.f,0.f,0.f,0.f,0.f,0.f,0.f,0.f};
                if (row < M) {
                    const float4* ap = (const float4*)((const float*)Ap + (size_t)row * lda + k0 + skq);
                    float4 u0 = ap[0], u1 = ap[1];
                    f[0]=u0.x; f[1]=u0.y; f[2]=u0.z; f[3]=u0.w;
                    f[4]=u1.x; f[5]=u1.y; f[6]=u1.z; f[7]=u1.w;
                    if (a_mode == 2)
                        for (int i = 0; i < 8; i++) f[i] = gelu_tanh(f[i]);
                }
                unsigned short v[8];
                for (int i = 0; i < 8; i++) v[i] = f2b(f[i]);
                u = *(uint4*)v;
            }
            *(uint4*)&Al[srow * LDP + skq] = u;
        }
        // stage B (64 n-rows x 32 k) from Wt[n][128]
        {
            int n = bn + srow;
            uint4 u = make_uint4(0, 0, 0, 0);
            if (n < N) u = *(const uint4*)(Wt + (size_t)n * 128 + k0 + skq);
            *(uint4*)&Bl[srow * LDP + skq] = u;
        }
        __syncthreads();
        bf16x8 af[2], bfr[2];
        #pragma unroll
        for (int i = 0; i < 2; i++) {
            af[i]  = *(const bf16x8*)&Al[(wr * 32 + i * 16 + lm) * LDP + quad * 8];
            bfr[i] = *(const bf16x8*)&Bl[(wc * 32 + i * 16 + lm) * LDP + quad * 8];
        }
        acc[0][0] = __builtin_amdgcn_mfma_f32_16x16x32_bf16(af[0], bfr[0], acc[0][0], 0, 0, 0);
        acc[0][1] = __builtin_amdgcn_mfma_f32_16x16x32_bf16(af[0], bfr[1], acc[0][1], 0, 0, 0);
        acc[1][0] = __builtin_amdgcn_mfma_f32_16x16x32_bf16(af[1], bfr[0], acc[1][0], 0, 0, 0);
        acc[1][1] = __builtin_amdgcn_mfma_f32_16x16x32_bf16(af[1], bfr[1], acc[1][1], 0, 0, 0);
        __syncthreads();
    }

    float aSk = 0.f, oneM = 0.f;
    if (skipv) {
        float sv = skipv[skipidx];
        aSk = 1.0f / (1.0f + expf(-sv));
        oneM = 1.0f - aSk;
    }
    #pragma unroll
    for (int tm = 0; tm < 2; tm++)
    #pragma unroll
    for (int tn = 0; tn < 2; tn++)
    #pragma unroll
    for (int r = 0; r < 4; r++) {
        int row = bm + wr * 32 + tm * 16 + quad * 4 + r;
        int col = bn + wc * 32 + tn * 16 + lm;
        if (row >= M || col >= N) continue;
        float v = acc[tm][tn][r] + (bias ? bias[col] : 0.f);
        if (act == 1) v = fmaxf(v, 0.f);
        else if (act == 2) v = 1.0f / (1.0f + expf(-v));
        if (skipv) v = aSk * v + oneM * b2f(xold[(size_t)row * ldx + col]);
        if (c_mode == 0) ((unsigned short*)Cp)[(size_t)row * ldc + col] = f2b(v);
        else             ((float*)Cp)[(size_t)row * ldc + col] = v;
    }
}

// ---------------------------------------------------------------------------
// Weight prep: transpose+convert fp32 [g][K][N] -> bf16 dst rows:
// dst + g*gstride + (n + nofs)*128 + k. 32x32 tiles via LDS.
// ---------------------------------------------------------------------------
__global__ __launch_bounds__(256) void wprep_kernel(
    const float* __restrict__ src, unsigned short* __restrict__ dst,
    int K, int N, size_t sstride, size_t gstride, int nofs)
{
    __shared__ float tile[32][33];
    int g = blockIdx.z;
    int k0 = blockIdx.x * 32, n0 = blockIdx.y * 32;
    int tx = threadIdx.x & 31, ty = threadIdx.x >> 5;   // ty 0..7
    const float* s = src + (size_t)g * sstride;
    for (int i = 0; i < 32; i += 8) {
        int k = k0 + ty + i, n = n0 + tx;
        tile[ty + i][tx] = (k < K && n < N) ? s[(size_t)k * N + n] : 0.f;
    }
    __syncthreads();
    unsigned short* d = dst + (size_t)g * gstride;
    for (int i = 0; i < 32; i += 8) {
        int n = n0 + ty + i, k = k0 + tx;
        if (n < N && k < K) d[(size_t)(n + nofs) * 128 + k] = f2b(tile[tx][ty + i]);
    }
}

__global__ void biaspack_kernel(const float* __restrict__ kb, const float* __restrict__ qb,
                                const float* __restrict__ vb, float* __restrict__ out) {
    int t = blockIdx.x * blockDim.x + threadIdx.x;
    if (t >= 6 * 384) return;
    int g = t / 384, c = t - g * 384;
    float v = (c < 128) ? kb[g * 128 + c]
            : (c < 256) ? qb[g * 128 + c - 128]
                        : vb[g * 128 + c - 256];
    out[t] = v;
}

// ---------------------------------------------------------------------------
// Batched CSR build (as round 3/4; simple packed scatter, no group partition)
// ---------------------------------------------------------------------------
__global__ void hist4_kernel(const int* __restrict__ d0, const int* __restrict__ d1,
                             const int* __restrict__ d2, const int* __restrict__ d3,
                             int* __restrict__ deg) {
    int t = blockIdx.x * blockDim.x + threadIdx.x;
    if (t >= 4 * NEDGE) return;
    int r = t / NEDGE, e = t - r * NEDGE;
    const int* dp = (r == 0) ? d0 : (r == 1) ? d1 : (r == 2) ? d2 : d3;
    int off = (r == 0) ? OFF0 : (r == 1) ? OFF1 : (r == 2) ? OFF2 : OFF3;
    atomicAdd(&deg[off + dp[e]], 1);
}

__global__ __launch_bounds__(256) void scanA_kernel(
    const int* __restrict__ deg, int* __restrict__ part, int n)
{
    __shared__ int red[256];
    int b = blockIdx.x, t = threadIdx.x;
    int base = b * 1024 + t * 4;
    int s = 0;
    if (base + 3 < n) {
        int4 v = *(const int4*)(deg + base);
        s = v.x + v.y + v.z + v.w;
    } else {
        for (int i = 0; i < 4; i++) if (base + i < n) s += deg[base + i];
    }
    red[t] = s;
    __syncthreads();
    for (int o = 128; o; o >>= 1) { if (t < o) red[t] += red[t + o]; __syncthreads(); }
    if (t == 0) part[b] = red[0];
}

__global__ __launch_bounds__(128) void scanB_kernel(int* __restrict__ part, int nb)
{
    __shared__ int s[256];
    int t = threadIdx.x;
    for (int i = t; i < nb; i += 128) s[i] = part[i];
    __syncthreads();
    if (t == 0) { int run = 0; for (int i = 0; i < nb; i++) { int v = s[i]; s[i] = run; run += v; } }
    __syncthreads();
    for (int i = t; i < nb; i += 128) part[i] = s[i];
}

__global__ __launch_bounds__(256) void scanC_kernel(
    const int* __restrict__ deg, const int* __restrict__ part,
    int* __restrict__ rp0, int* __restrict__ rp1,
    int* __restrict__ rp2, int* __restrict__ rp3,
    int* __restrict__ cursor, int n)
{
    __shared__ int red[256];
    int b = blockIdx.x, t = threadIdx.x;
    int base = b * 1024 + t * 4;
    int v[4] = {0, 0, 0, 0};
    if (base + 3 < n) {
        int4 q = *(const int4*)(deg + base);
        v[0] = q.x; v[1] = q.y; v[2] = q.z; v[3] = q.w;
    } else {
        for (int i = 0; i < 4; i++) if (base + i < n) v[i] = deg[base + i];
    }
    red[t] = v[0] + v[1] + v[2] + v[3];
    __syncthreads();
    for (int off = 1; off < 256; off <<= 1) {
        int y = (t >= off) ? red[t - off] : 0;
        __syncthreads();
        red[t] += y;
        __syncthreads();
    }
    int run = part[b] + ((t == 0) ? 0 : red[t - 1]);
    for (int i = 0; i < 4; i++) {
        int g = base + i;
        if (g < n) {
            cursor[g] = run;
            int r, loc;
            if      (g < OFF1) { r = 0; loc = g; }
            else if (g < OFF2) { r = 1; loc = g - OFF1; }
            else if (g < OFF3) { r = 2; loc = g - OFF2; }
            else               { r = 3; loc = g - OFF3; }
            int Sl = run - r * NEDGE;
            ((r == 0) ? rp0 : (r == 1) ? rp1 : (r == 2) ? rp2 : rp3)[loc] = Sl;
            run += v[i];
        }
    }
    if (b == 0 && t == 0) {
        rp0[NICD] = NEDGE; rp1[NPAT] = NEDGE; rp2[NNDC] = NEDGE; rp3[NPAT] = NEDGE;
    }
}

__global__ void scatter_pack_kernel(
    const int* __restrict__ s0, const int* __restrict__ d0,
    const int* __restrict__ s1, const int* __restrict__ d1,
    const int* __restrict__ s2, const int* __restrict__ d2,
    const int* __restrict__ s3, const int* __restrict__ d3,
    int* __restrict__ cursor, int2* __restrict__ es)
{
    int t = blockIdx.x * blockDim.x + threadIdx.x;
    if (t >= 4 * NEDGE) return;
    int r = t / NEDGE, e = t - r * NEDGE;
    const int* sp = (r == 0) ? s0 : (r == 1) ? s1 : (r == 2) ? s2 : s3;
    const int* dp = (r == 0) ? d0 : (r == 1) ? d1 : (r == 2) ? d2 : d3;
    int off = (r == 0) ? OFF0 : (r == 1) ? OFF1 : (r == 2) ? OFF2 : OFF3;
    int d = dp[e];
    int p = atomicAdd(&cursor[off + d], 1);   // includes r*NEDGE base
    es[p] = make_int2(sp[e], d);
}

// ---------------------------------------------------------------------------
// x = relu(emb[idx]) gather -> bf16
// ---------------------------------------------------------------------------
__global__ void gather_relu_kernel(const float* __restrict__ emb,
                                   const int* __restrict__ idx,
                                   unsigned short* __restrict__ out, int n) {
    int t = blockIdx.x * blockDim.x + threadIdx.x;
    if (t < n * CDIM) {
        int r = t >> 7, c = t & 127;
        out[t] = f2b(fmaxf(emb[(size_t)idx[r] * CDIM + c], 0.f));
    }
}

// ---------------------------------------------------------------------------
// Fused relation transform: blockIdx.y = 0 -> kr from k (arel), 1 -> vr (mrel)
// src = kqv buffer [n][384] bf16 (k at +0, v at +256); out [n][128] bf16.
// ---------------------------------------------------------------------------
__global__ __launch_bounds__(256) void rel_transform_kernel(
    const unsigned short* __restrict__ kqv,
    const float* __restrict__ arel, const float* __restrict__ mrel,
    unsigned short* __restrict__ kr, unsigned short* __restrict__ vr, int n)
{
    __shared__ float aS[2048];
    __shared__ float rowS[2][CDIM];
    int which = blockIdx.y;
    const unsigned short* src = kqv + (which ? 256 : 0);
    const float* am = which ? mrel : arel;
    unsigned short* out = which ? vr : kr;
    int t = threadIdx.x;
    for (int i = t; i < 2048; i += 256) aS[i] = am[i];
    __syncthreads();
    int rl = t >> 7, c = t & 127;
    int h = c >> 4, e = c & 15;
    const float* ah = &aS[h * 256 + e];
    for (int row0 = blockIdx.x * 2; row0 < n; row0 += gridDim.x * 2) {
        int row = row0 + rl;
        rowS[rl][c] = (row < n) ? b2f(src[(size_t)row * 384 + c]) : 0.f;
        __syncthreads();
        float acc = 0.f;
        const float* rp = &rowS[rl][h * 16];
        #pragma unroll
        for (int dd = 0; dd < 16; ++dd) acc += rp[dd] * ah[dd * 16];
        if (row < n) out[(size_t)row * CDIM + c] = f2b(acc);
        __syncthreads();
    }
}

// ---------------------------------------------------------------------------
// alpha_s[i,h] = (q[dst,h,:] . kr[src,h,:]) * p_rel[h] / 4   (bf16 inputs)
// ---------------------------------------------------------------------------
__global__ __launch_bounds__(256) void edge_logits_kernel(
    const int2* __restrict__ es,
    const unsigned short* __restrict__ q, int ldq,
    const unsigned short* __restrict__ kr,
    const float* __restrict__ prel, float* __restrict__ alpha_s)
{
    int t = blockIdx.x * blockDim.x + threadIdx.x;
    if (t >= NEDGE * NHEAD) return;
    int i = t >> 3, h = t & 7;
    int2 ed = es[i];
    const uint4* qp = (const uint4*)(q  + (size_t)ed.y * ldq + h * DHEAD);
    const uint4* kp = (const uint4*)(kr + (size_t)ed.x * CDIM + h * DHEAD);
    uint4 qa = qp[0], qb = qp[1];
    uint4 ka = kp[0], kb = kp[1];
    float acc = 0.f;
    unsigned int qu[8] = {qa.x, qa.y, qa.z, qa.w, qb.x, qb.y, qb.z, qb.w};
    unsigned int ku[8] = {ka.x, ka.y, ka.z, ka.w, kb.x, kb.y, kb.z, kb.w};
    #pragma unroll
    for (int j = 0; j < 8; j++) {
        float2 a = b2x2(qu[j]), b = b2x2(ku[j]);
        acc += a.x * b.x + a.y * b.y;
    }
    alpha_s[t] = acc * prel[h] * 0.25f;
}

// ---------------------------------------------------------------------------
// Segment softmax stats (one wave per dst, all heads; fp32 alpha)
// ---------------------------------------------------------------------------
__global__ __launch_bounds__(256) void seg_stats_kernel(
    const int* __restrict__ rowptr, const float* __restrict__ alpha_s,
    float2* __restrict__ stats, int nd)
{
    int wid = (blockIdx.x * 256 + threadIdx.x) >> 6;
    int lane = threadIdx.x & 63;
    if (wid >= nd) return;
    int r0 = rowptr[wid], r1 = rowptr[wid + 1];
    int h = lane & 7, j = lane >> 3;
    float mx = -1e30f;
    for (int i = r0 + j; i < r1; i += 8)
        mx = fmaxf(mx, alpha_s[(size_t)i * NHEAD + h]);
    mx = fmaxf(mx, __shfl_xor(mx, 8));
    mx = fmaxf(mx, __shfl_xor(mx, 16));
    mx = fmaxf(mx, __shfl_xor(mx, 32));
    float sm = 0.f;
    for (int i = r0 + j; i < r1; i += 8)
        sm += expf(alpha_s[(size_t)i * NHEAD + h] - mx);
    sm += __shfl_xor(sm, 8);
    sm += __shfl_xor(sm, 16);
    sm += __shfl_xor(sm, 32);
    if (j == 0)
        stats[(size_t)wid * NHEAD + h] = make_float2(mx, (sm > 0.f) ? 1.0f / sm : 0.f);
}

// ---------------------------------------------------------------------------
// Edge-chunk weighted segment sum; vr bf16; agg fp32 (+atomic run flush)
// ---------------------------------------------------------------------------
__global__ __launch_bounds__(128) void seg_agg_kernel(
    const int2* __restrict__ es,
    const float* __restrict__ alpha_s, const float2* __restrict__ stats,
    const unsigned short* __restrict__ vr, float* __restrict__ agg, int ne)
{
    __shared__ int   sSrc[EPB];
    __shared__ int   sDst[EPB];
    __shared__ float sW[EPB][NHEAD];
    int i0 = blockIdx.x * EPB;
    int t  = threadIdx.x;
    int cnt = min(EPB, ne - i0);
    if (t < cnt) {
        int2 ed = es[i0 + t];
        sSrc[t] = ed.x;
        sDst[t] = ed.y;
        const float4* ap = (const float4*)(alpha_s + (size_t)(i0 + t) * NHEAD);
        float4 a0 = ap[0], a1 = ap[1];
        float wv[8] = {a0.x, a0.y, a0.z, a0.w, a1.x, a1.y, a1.z, a1.w};
        const float2* st = stats + (size_t)ed.y * NHEAD;
        #pragma unroll
        for (int h = 0; h < NHEAD; h++) {
            float2 ms = st[h];
            sW[t][h] = expf(wv[h] - ms.x) * ms.y;
        }
    }
    __syncthreads();
    int h = t >> 4;
    float acc = 0.f;
    int curd = sDst[0];
    for (int i = 0; i < cnt; i++) {
        int d = sDst[i];
        if (d != curd) {
            atomicAdd(&agg[(size_t)curd * CDIM + t], acc);
            acc = 0.f;
            curd = d;
        }
        acc += b2f(vr[(size_t)sSrc[i] * CDIM + t]) * sW[i][h];
    }
    atomicAdd(&agg[(size_t)curd * CDIM + t], acc);
}

// ---------------------------------------------------------------------------
extern "C" void kernel_launch(void* const* d_in, const int* in_sizes, int n_in,
                              void* d_out, int out_size, void* d_ws, size_t ws_size,
                              hipStream_t stream)
{
    const float* x_patient = (const float*)d_in[0];
    const float* w_in      = (const float*)d_in[1];
    const float* b_in      = (const float*)d_in[2];
    const float* emb_icd   = (const float*)d_in[3];
    const float* emb_ndc   = (const float*)d_in[4];
    const float* kw        = (const float*)d_in[5];
    const float* kbias     = (const float*)d_in[6];
    const float* qw        = (const float*)d_in[7];
    const float* qbias     = (const float*)d_in[8];
    const float* vw        = (const float*)d_in[9];
    const float* vbias     = (const float*)d_in[10];
    const float* aw        = (const float*)d_in[11];
    const float* abias     = (const float*)d_in[12];
    const float* skip      = (const float*)d_in[13];
    const float* a_rel     = (const float*)d_in[14];
    const float* m_rel     = (const float*)d_in[15];
    const float* p_rel     = (const float*)d_in[16];
    const float* w_out     = (const float*)d_in[17];
    const float* b_out     = (const float*)d_in[18];
    const int*   x_icd     = (const int*)d_in[19];
    const int*   x_ndc     = (const int*)d_in[20];
    const int* esrc[4] = {(const int*)d_in[21], (const int*)d_in[23],
                          (const int*)d_in[25], (const int*)d_in[27]};
    const int* edst[4] = {(const int*)d_in[22], (const int*)d_in[24],
                          (const int*)d_in[26], (const int*)d_in[28]};

    const int st_[4] = {0, 1, 0, 2};
    const int dt_[4] = {1, 0, 2, 0};
    const int sizes[3] = {NPAT, NICD, NNDC};

    char* p = (char*)d_ws;
    auto alloc = [&](size_t bytes) -> void* {
        void* r = (void*)p;
        p += (bytes + 255) & ~(size_t)255;
        return r;
    };

    // activations: x bf16 [n][128]; kqv bf16 [n][384]; kr/vr bf16 [n][128]
    unsigned short *xb[3], *kqv[3];
    for (int t = 0; t < 3; t++) xb[t]  = (unsigned short*)alloc((size_t)sizes[t] * CDIM * 2);
    for (int t = 0; t < 3; t++) kqv[t] = (unsigned short*)alloc((size_t)sizes[t] * 384 * 2);
    float* aggbase = (float*)alloc((size_t)(NPAT + NICD + NNDC) * CDIM * 4);
    float* agg[3];
    agg[0] = aggbase;
    agg[1] = aggbase + (size_t)NPAT * CDIM;
    agg[2] = agg[1] + (size_t)NICD * CDIM;
    unsigned short* krbuf = (unsigned short*)alloc((size_t)NPAT * CDIM * 2);
    unsigned short* vrbuf = (unsigned short*)alloc((size_t)NPAT * CDIM * 2);
    float*  alphabuf = (float*)alloc((size_t)NEDGE * NHEAD * 4);
    float2* statsbuf = (float2*)alloc((size_t)NPAT * NHEAD * 8);
    int2* esbig = (int2*)alloc((size_t)4 * NEDGE * 8);
    int* rowptr[4];
    rowptr[0] = (int*)alloc((size_t)(NICD + 1) * 4);
    rowptr[1] = (int*)alloc((size_t)(NPAT + 1) * 4);
    rowptr[2] = (int*)alloc((size_t)(NNDC + 1) * 4);
    rowptr[3] = (int*)alloc((size_t)(NPAT + 1) * 4);
    int* deg    = (int*)alloc((size_t)NTOT * 4);
    int* cursor = (int*)alloc((size_t)NTOT * 4);
    int* part   = (int*)alloc((size_t)256 * 4);
    // prepped weights (bf16, transposed [n][k])
    unsigned short* Wtkqv = (unsigned short*)alloc((size_t)6 * 384 * 128 * 2);
    unsigned short* Wtaw  = (unsigned short*)alloc((size_t)6 * 128 * 128 * 2);
    unsigned short* Wtin  = (unsigned short*)alloc((size_t)128 * 128 * 2);
    unsigned short* Wtout = (unsigned short*)alloc((size_t)OUTN * 128 * 2);
    float* bkqv = (float*)alloc((size_t)6 * 384 * 4);
    int2* esRel[4];
    for (int r = 0; r < 4; r++) esRel[r] = esbig + (size_t)r * NEDGE;

    auto gemm = [&](const void* A, int a_mode, int lda,
                    const unsigned short* Wt, const float* bias,
                    void* C, int c_mode, int ldc, int M, int N, int act,
                    const unsigned short* xold, int ldx,
                    const float* skipv, int skipidx) {
        dim3 grid((M + 63) / 64, (N + 63) / 64);
        gemm_mfma<<<grid, dim3(256), 0, stream>>>(A, a_mode, lda, Wt, bias,
            C, c_mode, ldc, M, N, act, xold, ldx, skipv, skipidx);
    };

    // ---- weight prep (bf16 transposed) ----
    {
        dim3 g44(4, 12, 6);   // K=128 (4 tiles) x N=128 (but nofs packs into 384-wide) -> use (4,4,6) per family
        dim3 g(4, 4, 6);
        wprep_kernel<<<g, 256, 0, stream>>>(kw, Wtkqv, 128, 128,
            (size_t)128 * 128, (size_t)384 * 128, 0);
        wprep_kernel<<<g, 256, 0, stream>>>(qw, Wtkqv, 128, 128,
            (size_t)128 * 128, (size_t)384 * 128, 128);
        wprep_kernel<<<g, 256, 0, stream>>>(vw, Wtkqv, 128, 128,
            (size_t)128 * 128, (size_t)384 * 128, 256);
        wprep_kernel<<<g, 256, 0, stream>>>(aw, Wtaw, 128, 128,
            (size_t)128 * 128, (size_t)128 * 128, 0);
        wprep_kernel<<<dim3(4, 4, 1), 256, 0, stream>>>(w_in, Wtin, 128, 128,
            0, 0, 0);
        wprep_kernel<<<dim3(4, 3, 1), 256, 0, stream>>>(w_out, Wtout, 128, OUTN,
            0, 0, 0);
        biaspack_kernel<<<(6 * 384 + 255) / 256, 256, 0, stream>>>(kbias, qbias, vbias, bkqv);
    }

    // ---- batched CSR build ----
    {
        const int NB = (NTOT + 1023) / 1024;
        hipMemsetAsync(deg, 0, (size_t)NTOT * 4, stream);
        hist4_kernel<<<(4 * NEDGE + 255) / 256, 256, 0, stream>>>(
            edst[0], edst[1], edst[2], edst[3], deg);
        scanA_kernel<<<NB, 256, 0, stream>>>(deg, part, NTOT);
        scanB_kernel<<<1, 128, 0, stream>>>(part, NB);
        scanC_kernel<<<NB, 256, 0, stream>>>(deg, part,
            rowptr[0], rowptr[1], rowptr[2], rowptr[3], cursor, NTOT);
        scatter_pack_kernel<<<(4 * NEDGE + 255) / 256, 256, 0, stream>>>(
            esrc[0], edst[0], esrc[1], edst[1], esrc[2], edst[2], esrc[3], edst[3],
            cursor, esbig);
    }

    // ---- input projections ----
    gemm(x_patient, 1, 128, Wtin, b_in, xb[0], 0, 128, NPAT, 128, 1, nullptr, 0, nullptr, 0);
    gather_relu_kernel<<<(NICD * CDIM + 255) / 256, 256, 0, stream>>>(emb_icd, x_icd, xb[1], NICD);
    gather_relu_kernel<<<(NNDC * CDIM + 255) / 256, 256, 0, stream>>>(emb_ndc, x_ndc, xb[2], NNDC);

    // ---- layers ----
    for (int l = 0; l < NLAYER; l++) {
        for (int t = 0; t < 3; t++) {
            int wi = l * 3 + t;
            gemm(xb[t], 0, 128, Wtkqv + (size_t)wi * 384 * 128, bkqv + (size_t)wi * 384,
                 kqv[t], 0, 384, sizes[t], 384, 0, nullptr, 0, nullptr, 0);
        }
        hipMemsetAsync(aggbase, 0, (size_t)(NPAT + NICD + NNDC) * CDIM * 4, stream);
        for (int r = 0; r < 4; r++) {
            int s = st_[r], d = dt_[r];
            int ns = sizes[s], nd = sizes[d];
            int grid_rt = min((ns + 1) / 2, 2048);
            rel_transform_kernel<<<dim3(grid_rt, 2), 256, 0, stream>>>(
                kqv[s], a_rel + (size_t)(l * 4 + r) * 2048,
                m_rel + (size_t)(l * 4 + r) * 2048, krbuf, vrbuf, ns);
            edge_logits_kernel<<<(NEDGE * NHEAD + 255) / 256, 256, 0, stream>>>(
                esRel[r], kqv[d] + 128, 384, krbuf,
                p_rel + (size_t)(l * 4 + r) * NHEAD, alphabuf);
            seg_stats_kernel<<<(nd + 3) / 4, 256, 0, stream>>>(
                rowptr[r], alphabuf, statsbuf, nd);
            seg_agg_kernel<<<(NEDGE + EPB - 1) / EPB, 128, 0, stream>>>(
                esRel[r], alphabuf, statsbuf, vrbuf, agg[d], NEDGE);
        }
        for (int t = 0; t < 3; t++) {
            int wi = l * 3 + t;
            gemm(agg[t], 2, 128, Wtaw + (size_t)wi * 128 * 128, abias + (size_t)wi * 128,
                 xb[t], 0, 128, sizes[t], 128, 0, xb[t], 128, skip, wi);
        }
    }

    // ---- output head (fp32 out) ----
    gemm(xb[0], 0, 128, Wtout, b_out, d_out, 1, OUTN, NPAT, OUTN, 2, nullptr, 0, nullptr, 0);
}

// Round 7
// 1344.773 us; speedup vs baseline: 1.4198x; 1.0038x over previous
//
#include <hip/hip_runtime.h>
#include <math.h>

#define CDIM  128
#define NHEAD 8
#define DHEAD 16
#define NPAT  50000
#define NICD  591
#define NNDC  2042
#define OUTN  90
#define NEDGE 250000
#define NLAYER 2
#define EPB   128

// concat offsets for CSR build (relation order: pi, ip, pn, np; dst sizes)
#define OFF0  0
#define OFF1  (NICD)
#define OFF2  (NICD + NPAT)
#define OFF3  (NICD + NPAT + NNDC)
#define NTOT  (NICD + NPAT + NNDC + NPAT)

#define LDP 40   // LDS row stride (bf16 elems): 80B rows -> 16B aligned, 2-way-free banks

typedef __attribute__((ext_vector_type(8))) short bf16x8;
typedef __attribute__((ext_vector_type(4))) float f32x4;

__device__ __forceinline__ float gelu_tanh(float x) {
    float x3 = x * x * x;
    return 0.5f * x * (1.0f + tanhf(0.7978845608028654f * (x + 0.044715f * x3)));
}
__device__ __forceinline__ float b2f(unsigned short u) {
    union { unsigned int i; float f; } v; v.i = ((unsigned int)u) << 16; return v.f;
}
__device__ __forceinline__ unsigned short f2b(float f) {
    union { float ff; unsigned int i; } v; v.ff = f;
    unsigned int i = v.i;
    return (unsigned short)((i + 0x7FFFu + ((i >> 16) & 1u)) >> 16);  // RNE
}
__device__ __forceinline__ float2 b2x2(unsigned int u) {
    union { unsigned int i; float f; } lo, hi;
    lo.i = u << 16; hi.i = u & 0xFFFF0000u;
    return make_float2(lo.f, hi.f);
}

// ---------------------------------------------------------------------------
// bf16 MFMA GEMM: D = act(A[MxK=128] @ Wt^T + bias), Wt stored [N][128] bf16.
// a_mode: 0 = A bf16[M][lda]; 1 = A fp32; 2 = A fp32 + gelu on load.
// c_mode: 0 = bf16 out; 1 = fp32 out. act: 0 none, 1 relu, 2 sigmoid.
// Optional learned-skip: D = a*o + (1-a)*xold(bf16), a = sigmoid(skipv[skipidx]).
// 64x64 tile, 256 thr (4 waves), each wave 2x2 of 16x16x32 MFMA, K in 4 steps.
// ---------------------------------------------------------------------------
__global__ __launch_bounds__(256) void gemm_mfma(
    const void* __restrict__ Ap, int a_mode, int lda,
    const unsigned short* __restrict__ Wt, const float* __restrict__ bias,
    void* __restrict__ Cp, int c_mode, int ldc,
    int M, int N, int act,
    const unsigned short* __restrict__ xold, int ldx,
    const float* __restrict__ skipv, int skipidx)
{
    __shared__ unsigned short Al[64 * LDP];
    __shared__ unsigned short Bl[64 * LDP];
    int bm = blockIdx.x * 64, bn = blockIdx.y * 64;
    int t = threadIdx.x;
    int lane = t & 63, w = t >> 6;
    int wr = w >> 1, wc = w & 1;
    int quad = lane >> 4, lm = lane & 15;
    f32x4 acc[2][2] = {};
    const int srow = t >> 2;
    const int skq  = (t & 3) * 8;

    for (int k0 = 0; k0 < 128; k0 += 32) {
        // stage A (64 rows x 32 k)
        {
            int row = bm + srow;
            uint4 u = make_uint4(0, 0, 0, 0);
            if (a_mode == 0) {
                if (row < M)
                    u = *(const uint4*)((const unsigned short*)Ap + (size_t)row * lda + k0 + skq);
            } else {
                float f[8] = {0.f,0.f,0.f,0.f,0.f,0.f,0.f,0.f};
                if (row < M) {
                    const float4* ap = (const float4*)((const float*)Ap + (size_t)row * lda + k0 + skq);
                    float4 u0 = ap[0], u1 = ap[1];
                    f[0]=u0.x; f[1]=u0.y; f[2]=u0.z; f[3]=u0.w;
                    f[4]=u1.x; f[5]=u1.y; f[6]=u1.z; f[7]=u1.w;
                    if (a_mode == 2)
                        for (int i = 0; i < 8; i++) f[i] = gelu_tanh(f[i]);
                }
                unsigned short v[8];
                for (int i = 0; i < 8; i++) v[i] = f2b(f[i]);
                u = *(uint4*)v;
            }
            *(uint4*)&Al[srow * LDP + skq] = u;
        }
        // stage B (64 n-rows x 32 k) from Wt[n][128]
        {
            int n = bn + srow;
            uint4 u = make_uint4(0, 0, 0, 0);
            if (n < N) u = *(const uint4*)(Wt + (size_t)n * 128 + k0 + skq);
            *(uint4*)&Bl[srow * LDP + skq] = u;
        }
        __syncthreads();
        bf16x8 af[2], bfr[2];
        #pragma unroll
        for (int i = 0; i < 2; i++) {
            af[i]  = *(const bf16x8*)&Al[(wr * 32 + i * 16 + lm) * LDP + quad * 8];
            bfr[i] = *(const bf16x8*)&Bl[(wc * 32 + i * 16 + lm) * LDP + quad * 8];
        }
        acc[0][0] = __builtin_amdgcn_mfma_f32_16x16x32_bf16(af[0], bfr[0], acc[0][0], 0, 0, 0);
        acc[0][1] = __builtin_amdgcn_mfma_f32_16x16x32_bf16(af[0], bfr[1], acc[0][1], 0, 0, 0);
        acc[1][0] = __builtin_amdgcn_mfma_f32_16x16x32_bf16(af[1], bfr[0], acc[1][0], 0, 0, 0);
        acc[1][1] = __builtin_amdgcn_mfma_f32_16x16x32_bf16(af[1], bfr[1], acc[1][1], 0, 0, 0);
        __syncthreads();
    }

    float aSk = 0.f, oneM = 0.f;
    if (skipv) {
        float sv = skipv[skipidx];
        aSk = 1.0f / (1.0f + expf(-sv));
        oneM = 1.0f - aSk;
    }
    #pragma unroll
    for (int tm = 0; tm < 2; tm++)
    #pragma unroll
    for (int tn = 0; tn < 2; tn++)
    #pragma unroll
    for (int r = 0; r < 4; r++) {
        int row = bm + wr * 32 + tm * 16 + quad * 4 + r;
        int col = bn + wc * 32 + tn * 16 + lm;
        if (row >= M || col >= N) continue;
        float v = acc[tm][tn][r] + (bias ? bias[col] : 0.f);
        if (act == 1) v = fmaxf(v, 0.f);
        else if (act == 2) v = 1.0f / (1.0f + expf(-v));
        if (skipv) v = aSk * v + oneM * b2f(xold[(size_t)row * ldx + col]);
        if (c_mode == 0) ((unsigned short*)Cp)[(size_t)row * ldc + col] = f2b(v);
        else             ((float*)Cp)[(size_t)row * ldc + col] = v;
    }
}

// ---------------------------------------------------------------------------
// Weight prep: transpose+convert fp32 [g][K][N] -> bf16 dst rows:
// dst + g*gstride + (n + nofs)*128 + k. 32x32 tiles via LDS.
// ---------------------------------------------------------------------------
__global__ __launch_bounds__(256) void wprep_kernel(
    const float* __restrict__ src, unsigned short* __restrict__ dst,
    int K, int N, size_t sstride, size_t gstride, int nofs)
{
    __shared__ float tile[32][33];
    int g = blockIdx.z;
    int k0 = blockIdx.x * 32, n0 = blockIdx.y * 32;
    int tx = threadIdx.x & 31, ty = threadIdx.x >> 5;   // ty 0..7
    const float* s = src + (size_t)g * sstride;
    for (int i = 0; i < 32; i += 8) {
        int k = k0 + ty + i, n = n0 + tx;
        tile[ty + i][tx] = (k < K && n < N) ? s[(size_t)k * N + n] : 0.f;
    }
    __syncthreads();
    unsigned short* d = dst + (size_t)g * gstride;
    for (int i = 0; i < 32; i += 8) {
        int n = n0 + ty + i, k = k0 + tx;
        if (n < N && k < K) d[(size_t)(n + nofs) * 128 + k] = f2b(tile[tx][ty + i]);
    }
}

__global__ void biaspack_kernel(const float* __restrict__ kb, const float* __restrict__ qb,
                                const float* __restrict__ vb, float* __restrict__ out) {
    int t = blockIdx.x * blockDim.x + threadIdx.x;
    if (t >= 6 * 384) return;
    int g = t / 384, c = t - g * 384;
    float v = (c < 128) ? kb[g * 128 + c]
            : (c < 256) ? qb[g * 128 + c - 128]
                        : vb[g * 128 + c - 256];
    out[t] = v;
}

// ---------------------------------------------------------------------------
// Batched CSR build; edges packed (src<<16)|dst into ONE 32-bit word (all
// node counts < 65536) -> scattered store is 4 B, halving partial-line drain.
// ---------------------------------------------------------------------------
__global__ void hist4_kernel(const int* __restrict__ d0, const int* __restrict__ d1,
                             const int* __restrict__ d2, const int* __restrict__ d3,
                             int* __restrict__ deg) {
    int t = blockIdx.x * blockDim.x + threadIdx.x;
    if (t >= 4 * NEDGE) return;
    int r = t / NEDGE, e = t - r * NEDGE;
    const int* dp = (r == 0) ? d0 : (r == 1) ? d1 : (r == 2) ? d2 : d3;
    int off = (r == 0) ? OFF0 : (r == 1) ? OFF1 : (r == 2) ? OFF2 : OFF3;
    atomicAdd(&deg[off + dp[e]], 1);
}

__global__ __launch_bounds__(256) void scanA_kernel(
    const int* __restrict__ deg, int* __restrict__ part, int n)
{
    __shared__ int red[256];
    int b = blockIdx.x, t = threadIdx.x;
    int base = b * 1024 + t * 4;
    int s = 0;
    if (base + 3 < n) {
        int4 v = *(const int4*)(deg + base);
        s = v.x + v.y + v.z + v.w;
    } else {
        for (int i = 0; i < 4; i++) if (base + i < n) s += deg[base + i];
    }
    red[t] = s;
    __syncthreads();
    for (int o = 128; o; o >>= 1) { if (t < o) red[t] += red[t + o]; __syncthreads(); }
    if (t == 0) part[b] = red[0];
}

__global__ __launch_bounds__(128) void scanB_kernel(int* __restrict__ part, int nb)
{
    __shared__ int s[256];
    int t = threadIdx.x;
    for (int i = t; i < nb; i += 128) s[i] = part[i];
    __syncthreads();
    if (t == 0) { int run = 0; for (int i = 0; i < nb; i++) { int v = s[i]; s[i] = run; run += v; } }
    __syncthreads();
    for (int i = t; i < nb; i += 128) part[i] = s[i];
}

__global__ __launch_bounds__(256) void scanC_kernel(
    const int* __restrict__ deg, const int* __restrict__ part,
    int* __restrict__ rp0, int* __restrict__ rp1,
    int* __restrict__ rp2, int* __restrict__ rp3,
    int* __restrict__ cursor, int n)
{
    __shared__ int red[256];
    int b = blockIdx.x, t = threadIdx.x;
    int base = b * 1024 + t * 4;
    int v[4] = {0, 0, 0, 0};
    if (base + 3 < n) {
        int4 q = *(const int4*)(deg + base);
        v[0] = q.x; v[1] = q.y; v[2] = q.z; v[3] = q.w;
    } else {
        for (int i = 0; i < 4; i++) if (base + i < n) v[i] = deg[base + i];
    }
    red[t] = v[0] + v[1] + v[2] + v[3];
    __syncthreads();
    for (int off = 1; off < 256; off <<= 1) {
        int y = (t >= off) ? red[t - off] : 0;
        __syncthreads();
        red[t] += y;
        __syncthreads();
    }
    int run = part[b] + ((t == 0) ? 0 : red[t - 1]);
    for (int i = 0; i < 4; i++) {
        int g = base + i;
        if (g < n) {
            cursor[g] = run;
            int r, loc;
            if      (g < OFF1) { r = 0; loc = g; }
            else if (g < OFF2) { r = 1; loc = g - OFF1; }
            else if (g < OFF3) { r = 2; loc = g - OFF2; }
            else               { r = 3; loc = g - OFF3; }
            int Sl = run - r * NEDGE;
            ((r == 0) ? rp0 : (r == 1) ? rp1 : (r == 2) ? rp2 : rp3)[loc] = Sl;
            run += v[i];
        }
    }
    if (b == 0 && t == 0) {
        rp0[NICD] = NEDGE; rp1[NPAT] = NEDGE; rp2[NNDC] = NEDGE; rp3[NPAT] = NEDGE;
    }
}

__global__ void scatter_pack_kernel(
    const int* __restrict__ s0, const int* __restrict__ d0,
    const int* __restrict__ s1, const int* __restrict__ d1,
    const int* __restrict__ s2, const int* __restrict__ d2,
    const int* __restrict__ s3, const int* __restrict__ d3,
    int* __restrict__ cursor, unsigned int* __restrict__ es)
{
    int t = blockIdx.x * blockDim.x + threadIdx.x;
    if (t >= 4 * NEDGE) return;
    int r = t / NEDGE, e = t - r * NEDGE;
    const int* sp = (r == 0) ? s0 : (r == 1) ? s1 : (r == 2) ? s2 : s3;
    const int* dp = (r == 0) ? d0 : (r == 1) ? d1 : (r == 2) ? d2 : d3;
    int off = (r == 0) ? OFF0 : (r == 1) ? OFF1 : (r == 2) ? OFF2 : OFF3;
    int d = dp[e];
    int p = atomicAdd(&cursor[off + d], 1);   // includes r*NEDGE base
    es[p] = ((unsigned int)sp[e] << 16) | (unsigned int)d;
}

// ---------------------------------------------------------------------------
// x = relu(emb[idx]) gather -> bf16
// ---------------------------------------------------------------------------
__global__ void gather_relu_kernel(const float* __restrict__ emb,
                                   const int* __restrict__ idx,
                                   unsigned short* __restrict__ out, int n) {
    int t = blockIdx.x * blockDim.x + threadIdx.x;
    if (t < n * CDIM) {
        int r = t >> 7, c = t & 127;
        out[t] = f2b(fmaxf(emb[(size_t)idx[r] * CDIM + c], 0.f));
    }
}

// ---------------------------------------------------------------------------
// Fused relation transform: blockIdx.y = 0 -> kr from k (arel), 1 -> vr (mrel)
// src = kqv buffer [n][384] bf16 (k at +0, v at +256); out [n][128] bf16.
// ---------------------------------------------------------------------------
__global__ __launch_bounds__(256) void rel_transform_kernel(
    const unsigned short* __restrict__ kqv,
    const float* __restrict__ arel, const float* __restrict__ mrel,
    unsigned short* __restrict__ kr, unsigned short* __restrict__ vr, int n)
{
    __shared__ float aS[2048];
    __shared__ float rowS[2][CDIM];
    int which = blockIdx.y;
    const unsigned short* src = kqv + (which ? 256 : 0);
    const float* am = which ? mrel : arel;
    unsigned short* out = which ? vr : kr;
    int t = threadIdx.x;
    for (int i = t; i < 2048; i += 256) aS[i] = am[i];
    __syncthreads();
    int rl = t >> 7, c = t & 127;
    int h = c >> 4, e = c & 15;
    const float* ah = &aS[h * 256 + e];
    for (int row0 = blockIdx.x * 2; row0 < n; row0 += gridDim.x * 2) {
        int row = row0 + rl;
        rowS[rl][c] = (row < n) ? b2f(src[(size_t)row * 384 + c]) : 0.f;
        __syncthreads();
        float acc = 0.f;
        const float* rp = &rowS[rl][h * 16];
        #pragma unroll
        for (int dd = 0; dd < 16; ++dd) acc += rp[dd] * ah[dd * 16];
        if (row < n) out[(size_t)row * CDIM + c] = f2b(acc);
        __syncthreads();
    }
}

// ---------------------------------------------------------------------------
// alpha_s[i,h] = (q[dst,h,:] . kr[src,h,:]) * p_rel[h] / 4   (bf16 inputs)
// ---------------------------------------------------------------------------
__global__ __launch_bounds__(256) void edge_logits_kernel(
    const unsigned int* __restrict__ es,
    const unsigned short* __restrict__ q, int ldq,
    const unsigned short* __restrict__ kr,
    const float* __restrict__ prel, float* __restrict__ alpha_s)
{
    int t = blockIdx.x * blockDim.x + threadIdx.x;
    if (t >= NEDGE * NHEAD) return;
    int i = t >> 3, h = t & 7;
    unsigned int ed = es[i];
    int dn = ed & 0xFFFFu, sn = ed >> 16;
    const uint4* qp = (const uint4*)(q  + (size_t)dn * ldq + h * DHEAD);
    const uint4* kp = (const uint4*)(kr + (size_t)sn * CDIM + h * DHEAD);
    uint4 qa = qp[0], qb = qp[1];
    uint4 ka = kp[0], kb = kp[1];
    float acc = 0.f;
    unsigned int qu[8] = {qa.x, qa.y, qa.z, qa.w, qb.x, qb.y, qb.z, qb.w};
    unsigned int ku[8] = {ka.x, ka.y, ka.z, ka.w, kb.x, kb.y, kb.z, kb.w};
    #pragma unroll
    for (int j = 0; j < 8; j++) {
        float2 a = b2x2(qu[j]), b = b2x2(ku[j]);
        acc += a.x * b.x + a.y * b.y;
    }
    alpha_s[t] = acc * prel[h] * 0.25f;
}

// ---------------------------------------------------------------------------
// Segment softmax stats (one wave per dst, all heads; fp32 alpha)
// ---------------------------------------------------------------------------
__global__ __launch_bounds__(256) void seg_stats_kernel(
    const int* __restrict__ rowptr, const float* __restrict__ alpha_s,
    float2* __restrict__ stats, int nd)
{
    int wid = (blockIdx.x * 256 + threadIdx.x) >> 6;
    int lane = threadIdx.x & 63;
    if (wid >= nd) return;
    int r0 = rowptr[wid], r1 = rowptr[wid + 1];
    int h = lane & 7, j = lane >> 3;
    float mx = -1e30f;
    for (int i = r0 + j; i < r1; i += 8)
        mx = fmaxf(mx, alpha_s[(size_t)i * NHEAD + h]);
    mx = fmaxf(mx, __shfl_xor(mx, 8));
    mx = fmaxf(mx, __shfl_xor(mx, 16));
    mx = fmaxf(mx, __shfl_xor(mx, 32));
    float sm = 0.f;
    for (int i = r0 + j; i < r1; i += 8)
        sm += expf(alpha_s[(size_t)i * NHEAD + h] - mx);
    sm += __shfl_xor(sm, 8);
    sm += __shfl_xor(sm, 16);
    sm += __shfl_xor(sm, 32);
    if (j == 0)
        stats[(size_t)wid * NHEAD + h] = make_float2(mx, (sm > 0.f) ? 1.0f / sm : 0.f);
}

// ---------------------------------------------------------------------------
// Edge-chunk weighted segment sum; vr bf16; agg fp32 (+atomic run flush)
// ---------------------------------------------------------------------------
__global__ __launch_bounds__(128) void seg_agg_kernel(
    const unsigned int* __restrict__ es,
    const float* __restrict__ alpha_s, const float2* __restrict__ stats,
    const unsigned short* __restrict__ vr, float* __restrict__ agg, int ne)
{
    __shared__ unsigned int sE[EPB];
    __shared__ float sW[EPB][NHEAD];
    int i0 = blockIdx.x * EPB;
    int t  = threadIdx.x;
    int cnt = min(EPB, ne - i0);
    if (t < cnt) {
        unsigned int ed = es[i0 + t];
        sE[t] = ed;
        int dn = ed & 0xFFFFu;
        const float4* ap = (const float4*)(alpha_s + (size_t)(i0 + t) * NHEAD);
        float4 a0 = ap[0], a1 = ap[1];
        float wv[8] = {a0.x, a0.y, a0.z, a0.w, a1.x, a1.y, a1.z, a1.w};
        const float2* st = stats + (size_t)dn * NHEAD;
        #pragma unroll
        for (int h = 0; h < NHEAD; h++) {
            float2 ms = st[h];
            sW[t][h] = expf(wv[h] - ms.x) * ms.y;
        }
    }
    __syncthreads();
    int h = t >> 4;
    float acc = 0.f;
    int curd = (int)(sE[0] & 0xFFFFu);
    for (int i = 0; i < cnt; i++) {
        unsigned int ed = sE[i];
        int d = (int)(ed & 0xFFFFu);
        if (d != curd) {
            atomicAdd(&agg[(size_t)curd * CDIM + t], acc);
            acc = 0.f;
            curd = d;
        }
        acc += b2f(vr[(size_t)(ed >> 16) * CDIM + t]) * sW[i][h];
    }
    atomicAdd(&agg[(size_t)curd * CDIM + t], acc);
}

// ---------------------------------------------------------------------------
extern "C" void kernel_launch(void* const* d_in, const int* in_sizes, int n_in,
                              void* d_out, int out_size, void* d_ws, size_t ws_size,
                              hipStream_t stream)
{
    const float* x_patient = (const float*)d_in[0];
    const float* w_in      = (const float*)d_in[1];
    const float* b_in      = (const float*)d_in[2];
    const float* emb_icd   = (const float*)d_in[3];
    const float* emb_ndc   = (const float*)d_in[4];
    const float* kw        = (const float*)d_in[5];
    const float* kbias     = (const float*)d_in[6];
    const float* qw        = (const float*)d_in[7];
    const float* qbias     = (const float*)d_in[8];
    const float* vw        = (const float*)d_in[9];
    const float* vbias     = (const float*)d_in[10];
    const float* aw        = (const float*)d_in[11];
    const float* abias     = (const float*)d_in[12];
    const float* skip      = (const float*)d_in[13];
    const float* a_rel     = (const float*)d_in[14];
    const float* m_rel     = (const float*)d_in[15];
    const float* p_rel     = (const float*)d_in[16];
    const float* w_out     = (const float*)d_in[17];
    const float* b_out     = (const float*)d_in[18];
    const int*   x_icd     = (const int*)d_in[19];
    const int*   x_ndc     = (const int*)d_in[20];
    const int* esrc[4] = {(const int*)d_in[21], (const int*)d_in[23],
                          (const int*)d_in[25], (const int*)d_in[27]};
    const int* edst[4] = {(const int*)d_in[22], (const int*)d_in[24],
                          (const int*)d_in[26], (const int*)d_in[28]};

    const int st_[4] = {0, 1, 0, 2};
    const int dt_[4] = {1, 0, 2, 0};
    const int sizes[3] = {NPAT, NICD, NNDC};

    char* p = (char*)d_ws;
    auto alloc = [&](size_t bytes) -> void* {
        void* r = (void*)p;
        p += (bytes + 255) & ~(size_t)255;
        return r;
    };

    // activations: x bf16 [n][128]; kqv bf16 [n][384]; kr/vr bf16 [n][128]
    unsigned short *xb[3], *kqv[3];
    for (int t = 0; t < 3; t++) xb[t]  = (unsigned short*)alloc((size_t)sizes[t] * CDIM * 2);
    for (int t = 0; t < 3; t++) kqv[t] = (unsigned short*)alloc((size_t)sizes[t] * 384 * 2);
    float* aggbase = (float*)alloc((size_t)(NPAT + NICD + NNDC) * CDIM * 4);
    float* agg[3];
    agg[0] = aggbase;
    agg[1] = aggbase + (size_t)NPAT * CDIM;
    agg[2] = agg[1] + (size_t)NICD * CDIM;
    unsigned short* krbuf = (unsigned short*)alloc((size_t)NPAT * CDIM * 2);
    unsigned short* vrbuf = (unsigned short*)alloc((size_t)NPAT * CDIM * 2);
    float*  alphabuf = (float*)alloc((size_t)NEDGE * NHEAD * 4);
    float2* statsbuf = (float2*)alloc((size_t)NPAT * NHEAD * 8);
    unsigned int* esbig = (unsigned int*)alloc((size_t)4 * NEDGE * 4);
    int* rowptr[4];
    rowptr[0] = (int*)alloc((size_t)(NICD + 1) * 4);
    rowptr[1] = (int*)alloc((size_t)(NPAT + 1) * 4);
    rowptr[2] = (int*)alloc((size_t)(NNDC + 1) * 4);
    rowptr[3] = (int*)alloc((size_t)(NPAT + 1) * 4);
    int* deg    = (int*)alloc((size_t)NTOT * 4);
    int* cursor = (int*)alloc((size_t)NTOT * 4);
    int* part   = (int*)alloc((size_t)256 * 4);
    // prepped weights (bf16, transposed [n][k])
    unsigned short* Wtkqv = (unsigned short*)alloc((size_t)6 * 384 * 128 * 2);
    unsigned short* Wtaw  = (unsigned short*)alloc((size_t)6 * 128 * 128 * 2);
    unsigned short* Wtin  = (unsigned short*)alloc((size_t)128 * 128 * 2);
    unsigned short* Wtout = (unsigned short*)alloc((size_t)OUTN * 128 * 2);
    float* bkqv = (float*)alloc((size_t)6 * 384 * 4);
    unsigned int* esRel[4];
    for (int r = 0; r < 4; r++) esRel[r] = esbig + (size_t)r * NEDGE;

    auto gemm = [&](const void* A, int a_mode, int lda,
                    const unsigned short* Wt, const float* bias,
                    void* C, int c_mode, int ldc, int M, int N, int act,
                    const unsigned short* xold, int ldx,
                    const float* skipv, int skipidx) {
        dim3 grid((M + 63) / 64, (N + 63) / 64);
        gemm_mfma<<<grid, dim3(256), 0, stream>>>(A, a_mode, lda, Wt, bias,
            C, c_mode, ldc, M, N, act, xold, ldx, skipv, skipidx);
    };

    // ---- weight prep (bf16 transposed) ----
    {
        dim3 g(4, 4, 6);
        wprep_kernel<<<g, 256, 0, stream>>>(kw, Wtkqv, 128, 128,
            (size_t)128 * 128, (size_t)384 * 128, 0);
        wprep_kernel<<<g, 256, 0, stream>>>(qw, Wtkqv, 128, 128,
            (size_t)128 * 128, (size_t)384 * 128, 128);
        wprep_kernel<<<g, 256, 0, stream>>>(vw, Wtkqv, 128, 128,
            (size_t)128 * 128, (size_t)384 * 128, 256);
        wprep_kernel<<<g, 256, 0, stream>>>(aw, Wtaw, 128, 128,
            (size_t)128 * 128, (size_t)128 * 128, 0);
        wprep_kernel<<<dim3(4, 4, 1), 256, 0, stream>>>(w_in, Wtin, 128, 128,
            0, 0, 0);
        wprep_kernel<<<dim3(4, 3, 1), 256, 0, stream>>>(w_out, Wtout, 128, OUTN,
            0, 0, 0);
        biaspack_kernel<<<(6 * 384 + 255) / 256, 256, 0, stream>>>(kbias, qbias, vbias, bkqv);
    }

    // ---- batched CSR build ----
    {
        const int NB = (NTOT + 1023) / 1024;
        hipMemsetAsync(deg, 0, (size_t)NTOT * 4, stream);
        hist4_kernel<<<(4 * NEDGE + 255) / 256, 256, 0, stream>>>(
            edst[0], edst[1], edst[2], edst[3], deg);
        scanA_kernel<<<NB, 256, 0, stream>>>(deg, part, NTOT);
        scanB_kernel<<<1, 128, 0, stream>>>(part, NB);
        scanC_kernel<<<NB, 256, 0, stream>>>(deg, part,
            rowptr[0], rowptr[1], rowptr[2], rowptr[3], cursor, NTOT);
        scatter_pack_kernel<<<(4 * NEDGE + 255) / 256, 256, 0, stream>>>(
            esrc[0], edst[0], esrc[1], edst[1], esrc[2], edst[2], esrc[3], edst[3],
            cursor, esbig);
    }

    // ---- input projections ----
    gemm(x_patient, 1, 128, Wtin, b_in, xb[0], 0, 128, NPAT, 128, 1, nullptr, 0, nullptr, 0);
    gather_relu_kernel<<<(NICD * CDIM + 255) / 256, 256, 0, stream>>>(emb_icd, x_icd, xb[1], NICD);
    gather_relu_kernel<<<(NNDC * CDIM + 255) / 256, 256, 0, stream>>>(emb_ndc, x_ndc, xb[2], NNDC);

    // ---- layers ----
    for (int l = 0; l < NLAYER; l++) {
        for (int t = 0; t < 3; t++) {
            int wi = l * 3 + t;
            gemm(xb[t], 0, 128, Wtkqv + (size_t)wi * 384 * 128, bkqv + (size_t)wi * 384,
                 kqv[t], 0, 384, sizes[t], 384, 0, nullptr, 0, nullptr, 0);
        }
        hipMemsetAsync(aggbase, 0, (size_t)(NPAT + NICD + NNDC) * CDIM * 4, stream);
        for (int r = 0; r < 4; r++) {
            int s = st_[r], d = dt_[r];
            int ns = sizes[s], nd = sizes[d];
            int grid_rt = min((ns + 1) / 2, 2048);
            rel_transform_kernel<<<dim3(grid_rt, 2), 256, 0, stream>>>(
                kqv[s], a_rel + (size_t)(l * 4 + r) * 2048,
                m_rel + (size_t)(l * 4 + r) * 2048, krbuf, vrbuf, ns);
            edge_logits_kernel<<<(NEDGE * NHEAD + 255) / 256, 256, 0, stream>>>(
                esRel[r], kqv[d] + 128, 384, krbuf,
                p_rel + (size_t)(l * 4 + r) * NHEAD, alphabuf);
            seg_stats_kernel<<<(nd + 3) / 4, 256, 0, stream>>>(
                rowptr[r], alphabuf, statsbuf, nd);
            seg_agg_kernel<<<(NEDGE + EPB - 1) / EPB, 128, 0, stream>>>(
                esRel[r], alphabuf, statsbuf, vrbuf, agg[d], NEDGE);
        }
        for (int t = 0; t < 3; t++) {
            int wi = l * 3 + t;
            gemm(agg[t], 2, 128, Wtaw + (size_t)wi * 128 * 128, abias + (size_t)wi * 128,
                 xb[t], 0, 128, sizes[t], 128, 0, xb[t], 128, skip, wi);
        }
    }

    // ---- output head (fp32 out) ----
    gemm(xb[0], 0, 128, Wtout, b_out, d_out, 1, OUTN, NPAT, OUTN, 2, nullptr, 0, nullptr, 0);
}

// Round 8
// 1230.296 us; speedup vs baseline: 1.5519x; 1.0930x over previous
//
#include <hip/hip_runtime.h>
#include <math.h>

#define CDIM  128
#define NHEAD 8
#define DHEAD 16
#define NPAT  50000
#define NICD  591
#define NNDC  2042
#define OUTN  90
#define NEDGE 250000
#define NLAYER 2
#define EPB   128

// concat offsets for CSR build (relation order: pi, ip, pn, np; dst sizes)
#define OFF0  0
#define OFF1  (NICD)
#define OFF2  (NICD + NPAT)
#define OFF3  (NICD + NPAT + NNDC)
#define NTOT  (NICD + NPAT + NNDC + NPAT)

#define LDP 40   // LDS row stride (bf16 elems): 80B rows -> 16B aligned, 2-way-free banks

typedef __attribute__((ext_vector_type(8))) short bf16x8;
typedef __attribute__((ext_vector_type(4))) float f32x4;

__device__ __forceinline__ float gelu_tanh(float x) {
    float x3 = x * x * x;
    return 0.5f * x * (1.0f + tanhf(0.7978845608028654f * (x + 0.044715f * x3)));
}
__device__ __forceinline__ float b2f(unsigned short u) {
    union { unsigned int i; float f; } v; v.i = ((unsigned int)u) << 16; return v.f;
}
__device__ __forceinline__ unsigned short f2b(float f) {
    union { float ff; unsigned int i; } v; v.ff = f;
    unsigned int i = v.i;
    return (unsigned short)((i + 0x7FFFu + ((i >> 16) & 1u)) >> 16);  // RNE
}
__device__ __forceinline__ float2 b2x2(unsigned int u) {
    union { unsigned int i; float f; } lo, hi;
    lo.i = u << 16; hi.i = u & 0xFFFF0000u;
    return make_float2(lo.f, hi.f);
}

// ---------------------------------------------------------------------------
// bf16 MFMA GEMM (as round 6): D = act(A @ Wt^T + bias), Wt [N][128] bf16.
// ---------------------------------------------------------------------------
__global__ __launch_bounds__(256) void gemm_mfma(
    const void* __restrict__ Ap, int a_mode, int lda,
    const unsigned short* __restrict__ Wt, const float* __restrict__ bias,
    void* __restrict__ Cp, int c_mode, int ldc,
    int M, int N, int act,
    const unsigned short* __restrict__ xold, int ldx,
    const float* __restrict__ skipv, int skipidx)
{
    __shared__ unsigned short Al[64 * LDP];
    __shared__ unsigned short Bl[64 * LDP];
    int bm = blockIdx.x * 64, bn = blockIdx.y * 64;
    int t = threadIdx.x;
    int lane = t & 63, w = t >> 6;
    int wr = w >> 1, wc = w & 1;
    int quad = lane >> 4, lm = lane & 15;
    f32x4 acc[2][2] = {};
    const int srow = t >> 2;
    const int skq  = (t & 3) * 8;

    for (int k0 = 0; k0 < 128; k0 += 32) {
        {
            int row = bm + srow;
            uint4 u = make_uint4(0, 0, 0, 0);
            if (a_mode == 0) {
                if (row < M)
                    u = *(const uint4*)((const unsigned short*)Ap + (size_t)row * lda + k0 + skq);
            } else {
                float f[8] = {0.f,0.f,0.f,0.f,0.f,0.f,0.f,0.f};
                if (row < M) {
                    const float4* ap = (const float4*)((const float*)Ap + (size_t)row * lda + k0 + skq);
                    float4 u0 = ap[0], u1 = ap[1];
                    f[0]=u0.x; f[1]=u0.y; f[2]=u0.z; f[3]=u0.w;
                    f[4]=u1.x; f[5]=u1.y; f[6]=u1.z; f[7]=u1.w;
                    if (a_mode == 2)
                        for (int i = 0; i < 8; i++) f[i] = gelu_tanh(f[i]);
                }
                unsigned short v[8];
                for (int i = 0; i < 8; i++) v[i] = f2b(f[i]);
                u = *(uint4*)v;
            }
            *(uint4*)&Al[srow * LDP + skq] = u;
        }
        {
            int n = bn + srow;
            uint4 u = make_uint4(0, 0, 0, 0);
            if (n < N) u = *(const uint4*)(Wt + (size_t)n * 128 + k0 + skq);
            *(uint4*)&Bl[srow * LDP + skq] = u;
        }
        __syncthreads();
        bf16x8 af[2], bfr[2];
        #pragma unroll
        for (int i = 0; i < 2; i++) {
            af[i]  = *(const bf16x8*)&Al[(wr * 32 + i * 16 + lm) * LDP + quad * 8];
            bfr[i] = *(const bf16x8*)&Bl[(wc * 32 + i * 16 + lm) * LDP + quad * 8];
        }
        acc[0][0] = __builtin_amdgcn_mfma_f32_16x16x32_bf16(af[0], bfr[0], acc[0][0], 0, 0, 0);
        acc[0][1] = __builtin_amdgcn_mfma_f32_16x16x32_bf16(af[0], bfr[1], acc[0][1], 0, 0, 0);
        acc[1][0] = __builtin_amdgcn_mfma_f32_16x16x32_bf16(af[1], bfr[0], acc[1][0], 0, 0, 0);
        acc[1][1] = __builtin_amdgcn_mfma_f32_16x16x32_bf16(af[1], bfr[1], acc[1][1], 0, 0, 0);
        __syncthreads();
    }

    float aSk = 0.f, oneM = 0.f;
    if (skipv) {
        float sv = skipv[skipidx];
        aSk = 1.0f / (1.0f + expf(-sv));
        oneM = 1.0f - aSk;
    }
    #pragma unroll
    for (int tm = 0; tm < 2; tm++)
    #pragma unroll
    for (int tn = 0; tn < 2; tn++)
    #pragma unroll
    for (int r = 0; r < 4; r++) {
        int row = bm + wr * 32 + tm * 16 + quad * 4 + r;
        int col = bn + wc * 32 + tn * 16 + lm;
        if (row >= M || col >= N) continue;
        float v = acc[tm][tn][r] + (bias ? bias[col] : 0.f);
        if (act == 1) v = fmaxf(v, 0.f);
        else if (act == 2) v = 1.0f / (1.0f + expf(-v));
        if (skipv) v = aSk * v + oneM * b2f(xold[(size_t)row * ldx + col]);
        if (c_mode == 0) ((unsigned short*)Cp)[(size_t)row * ldc + col] = f2b(v);
        else             ((float*)Cp)[(size_t)row * ldc + col] = v;
    }
}

// ---------------------------------------------------------------------------
// Weight prep: transpose+convert fp32 [g][K][N] -> bf16 [n+nofs][128]
// ---------------------------------------------------------------------------
__global__ __launch_bounds__(256) void wprep_kernel(
    const float* __restrict__ src, unsigned short* __restrict__ dst,
    int K, int N, size_t sstride, size_t gstride, int nofs)
{
    __shared__ float tile[32][33];
    int g = blockIdx.z;
    int k0 = blockIdx.x * 32, n0 = blockIdx.y * 32;
    int tx = threadIdx.x & 31, ty = threadIdx.x >> 5;
    const float* s = src + (size_t)g * sstride;
    for (int i = 0; i < 32; i += 8) {
        int k = k0 + ty + i, n = n0 + tx;
        tile[ty + i][tx] = (k < K && n < N) ? s[(size_t)k * N + n] : 0.f;
    }
    __syncthreads();
    unsigned short* d = dst + (size_t)g * gstride;
    for (int i = 0; i < 32; i += 8) {
        int n = n0 + ty + i, k = k0 + tx;
        if (n < N && k < K) d[(size_t)(n + nofs) * 128 + k] = f2b(tile[tx][ty + i]);
    }
}

__global__ void biaspack_kernel(const float* __restrict__ kb, const float* __restrict__ qb,
                                const float* __restrict__ vb, float* __restrict__ out) {
    int t = blockIdx.x * blockDim.x + threadIdx.x;
    if (t >= 6 * 384) return;
    int g = t / 384, c = t - g * 384;
    float v = (c < 128) ? kb[g * 128 + c]
            : (c < 256) ? qb[g * 128 + c - 128]
                        : vb[g * 128 + c - 256];
    out[t] = v;
}

// ---------------------------------------------------------------------------
// Histogram: grid (64, 4). Relations 0 (icd, 591 bins) and 2 (ndc, 2042 bins)
// pre-aggregate in LDS (hit density is high) -> ~3x fewer device atomics for
// those halves. Patient-dst relations (1,3) stay plain (density too low).
// ---------------------------------------------------------------------------
__global__ __launch_bounds__(256) void hist4_kernel(
    const int* __restrict__ d0, const int* __restrict__ d1,
    const int* __restrict__ d2, const int* __restrict__ d3,
    int* __restrict__ deg)
{
    __shared__ int lh[2048];
    int rel = blockIdx.y;
    int t = threadIdx.x;
    const int* dp = (rel == 0) ? d0 : (rel == 1) ? d1 : (rel == 2) ? d2 : d3;
    int off = (rel == 0) ? OFF0 : (rel == 1) ? OFF1 : (rel == 2) ? OFF2 : OFF3;
    if (rel == 1 || rel == 3) {
        for (int e = blockIdx.x * 256 + t; e < NEDGE; e += gridDim.x * 256)
            atomicAdd(&deg[off + dp[e]], 1);
    } else {
        int nb = (rel == 0) ? NICD : NNDC;
        for (int i = t; i < nb; i += 256) lh[i] = 0;
        __syncthreads();
        for (int e = blockIdx.x * 256 + t; e < NEDGE; e += gridDim.x * 256)
            atomicAdd(&lh[dp[e]], 1);
        __syncthreads();
        for (int i = t; i < nb; i += 256) {
            int v = lh[i];
            if (v) atomicAdd(&deg[off + i], v);
        }
    }
}

__global__ __launch_bounds__(256) void scanA_kernel(
    const int* __restrict__ deg, int* __restrict__ part, int n)
{
    __shared__ int red[256];
    int b = blockIdx.x, t = threadIdx.x;
    int base = b * 1024 + t * 4;
    int s = 0;
    if (base + 3 < n) {
        int4 v = *(const int4*)(deg + base);
        s = v.x + v.y + v.z + v.w;
    } else {
        for (int i = 0; i < 4; i++) if (base + i < n) s += deg[base + i];
    }
    red[t] = s;
    __syncthreads();
    for (int o = 128; o; o >>= 1) { if (t < o) red[t] += red[t + o]; __syncthreads(); }
    if (t == 0) part[b] = red[0];
}

__global__ __launch_bounds__(128) void scanB_kernel(int* __restrict__ part, int nb)
{
    __shared__ int s[256];
    int t = threadIdx.x;
    for (int i = t; i < nb; i += 128) s[i] = part[i];
    __syncthreads();
    if (t == 0) { int run = 0; for (int i = 0; i < nb; i++) { int v = s[i]; s[i] = run; run += v; } }
    __syncthreads();
    for (int i = t; i < nb; i += 128) part[i] = s[i];
}

__global__ __launch_bounds__(256) void scanC_kernel(
    const int* __restrict__ deg, const int* __restrict__ part,
    int* __restrict__ rp0, int* __restrict__ rp1,
    int* __restrict__ rp2, int* __restrict__ rp3,
    int* __restrict__ cursor, int n)
{
    __shared__ int red[256];
    int b = blockIdx.x, t = threadIdx.x;
    int base = b * 1024 + t * 4;
    int v[4] = {0, 0, 0, 0};
    if (base + 3 < n) {
        int4 q = *(const int4*)(deg + base);
        v[0] = q.x; v[1] = q.y; v[2] = q.z; v[3] = q.w;
    } else {
        for (int i = 0; i < 4; i++) if (base + i < n) v[i] = deg[base + i];
    }
    red[t] = v[0] + v[1] + v[2] + v[3];
    __syncthreads();
    for (int off = 1; off < 256; off <<= 1) {
        int y = (t >= off) ? red[t - off] : 0;
        __syncthreads();
        red[t] += y;
        __syncthreads();
    }
    int run = part[b] + ((t == 0) ? 0 : red[t - 1]);
    for (int i = 0; i < 4; i++) {
        int g = base + i;
        if (g < n) {
            cursor[g] = run;
            int r, loc;
            if      (g < OFF1) { r = 0; loc = g; }
            else if (g < OFF2) { r = 1; loc = g - OFF1; }
            else if (g < OFF3) { r = 2; loc = g - OFF2; }
            else               { r = 3; loc = g - OFF3; }
            int Sl = run - r * NEDGE;
            ((r == 0) ? rp0 : (r == 1) ? rp1 : (r == 2) ? rp2 : rp3)[loc] = Sl;
            run += v[i];
        }
    }
    if (b == 0 && t == 0) {
        rp0[NICD] = NEDGE; rp1[NPAT] = NEDGE; rp2[NNDC] = NEDGE; rp3[NPAT] = NEDGE;
    }
}

__global__ void scatter_pack_kernel(
    const int* __restrict__ s0, const int* __restrict__ d0,
    const int* __restrict__ s1, const int* __restrict__ d1,
    const int* __restrict__ s2, const int* __restrict__ d2,
    const int* __restrict__ s3, const int* __restrict__ d3,
    int* __restrict__ cursor, unsigned int* __restrict__ es)
{
    int t = blockIdx.x * blockDim.x + threadIdx.x;
    if (t >= 4 * NEDGE) return;
    int r = t / NEDGE, e = t - r * NEDGE;
    const int* sp = (r == 0) ? s0 : (r == 1) ? s1 : (r == 2) ? s2 : s3;
    const int* dp = (r == 0) ? d0 : (r == 1) ? d1 : (r == 2) ? d2 : d3;
    int off = (r == 0) ? OFF0 : (r == 1) ? OFF1 : (r == 2) ? OFF2 : OFF3;
    int d = dp[e];
    int p = atomicAdd(&cursor[off + d], 1);   // includes r*NEDGE base
    es[p] = ((unsigned int)sp[e] << 16) | (unsigned int)d;
}

// ---------------------------------------------------------------------------
// x = relu(emb[idx]) gather -> bf16
// ---------------------------------------------------------------------------
__global__ void gather_relu_kernel(const float* __restrict__ emb,
                                   const int* __restrict__ idx,
                                   unsigned short* __restrict__ out, int n) {
    int t = blockIdx.x * blockDim.x + threadIdx.x;
    if (t < n * CDIM) {
        int r = t >> 7, c = t & 127;
        out[t] = f2b(fmaxf(emb[(size_t)idx[r] * CDIM + c], 0.f));
    }
}

// ---------------------------------------------------------------------------
// Fused relation transform (as round 6)
// ---------------------------------------------------------------------------
__global__ __launch_bounds__(256) void rel_transform_kernel(
    const unsigned short* __restrict__ kqv,
    const float* __restrict__ arel, const float* __restrict__ mrel,
    unsigned short* __restrict__ kr, unsigned short* __restrict__ vr, int n)
{
    __shared__ float aS[2048];
    __shared__ float rowS[2][CDIM];
    int which = blockIdx.y;
    const unsigned short* src = kqv + (which ? 256 : 0);
    const float* am = which ? mrel : arel;
    unsigned short* out = which ? vr : kr;
    int t = threadIdx.x;
    for (int i = t; i < 2048; i += 256) aS[i] = am[i];
    __syncthreads();
    int rl = t >> 7, c = t & 127;
    int h = c >> 4, e = c & 15;
    const float* ah = &aS[h * 256 + e];
    for (int row0 = blockIdx.x * 2; row0 < n; row0 += gridDim.x * 2) {
        int row = row0 + rl;
        rowS[rl][c] = (row < n) ? b2f(src[(size_t)row * 384 + c]) : 0.f;
        __syncthreads();
        float acc = 0.f;
        const float* rp = &rowS[rl][h * 16];
        #pragma unroll
        for (int dd = 0; dd < 16; ++dd) acc += rp[dd] * ah[dd * 16];
        if (row < n) out[(size_t)row * CDIM + c] = f2b(acc);
        __syncthreads();
    }
}

__device__ __forceinline__ float dot16_bf(const unsigned short* a,
                                          const unsigned short* b) {
    const uint4* ap = (const uint4*)a;
    const uint4* bp = (const uint4*)b;
    uint4 a0 = ap[0], a1 = ap[1], b0 = bp[0], b1 = bp[1];
    unsigned int au[8] = {a0.x, a0.y, a0.z, a0.w, a1.x, a1.y, a1.z, a1.w};
    unsigned int bu[8] = {b0.x, b0.y, b0.z, b0.w, b1.x, b1.y, b1.z, b1.w};
    float acc = 0.f;
    #pragma unroll
    for (int j = 0; j < 8; j++) {
        float2 x = b2x2(au[j]), y = b2x2(bu[j]);
        acc += x.x * y.x + x.y * y.y;
    }
    return acc;
}

// ---------------------------------------------------------------------------
// Per-edge logits (old path; used for icd/ndc-dst relations)
// ---------------------------------------------------------------------------
__global__ __launch_bounds__(256) void edge_logits_kernel(
    const unsigned int* __restrict__ es,
    const unsigned short* __restrict__ q, int ldq,
    const unsigned short* __restrict__ kr,
    const float* __restrict__ prel, float* __restrict__ alpha_s)
{
    int t = blockIdx.x * blockDim.x + threadIdx.x;
    if (t >= NEDGE * NHEAD) return;
    int i = t >> 3, h = t & 7;
    unsigned int ed = es[i];
    int dn = ed & 0xFFFFu, sn = ed >> 16;
    float acc = dot16_bf(q + (size_t)dn * ldq + h * DHEAD,
                         kr + (size_t)sn * CDIM + h * DHEAD);
    alpha_s[t] = acc * prel[h] * 0.25f;
}

__global__ __launch_bounds__(256) void seg_stats_kernel(
    const int* __restrict__ rowptr, const float* __restrict__ alpha_s,
    float2* __restrict__ stats, int nd)
{
    int wid = (blockIdx.x * 256 + threadIdx.x) >> 6;
    int lane = threadIdx.x & 63;
    if (wid >= nd) return;
    int r0 = rowptr[wid], r1 = rowptr[wid + 1];
    int h = lane & 7, j = lane >> 3;
    float mx = -1e30f;
    for (int i = r0 + j; i < r1; i += 8)
        mx = fmaxf(mx, alpha_s[(size_t)i * NHEAD + h]);
    mx = fmaxf(mx, __shfl_xor(mx, 8));
    mx = fmaxf(mx, __shfl_xor(mx, 16));
    mx = fmaxf(mx, __shfl_xor(mx, 32));
    float sm = 0.f;
    for (int i = r0 + j; i < r1; i += 8)
        sm += expf(alpha_s[(size_t)i * NHEAD + h] - mx);
    sm += __shfl_xor(sm, 8);
    sm += __shfl_xor(sm, 16);
    sm += __shfl_xor(sm, 32);
    if (j == 0)
        stats[(size_t)wid * NHEAD + h] = make_float2(mx, (sm > 0.f) ? 1.0f / sm : 0.f);
}

// ---------------------------------------------------------------------------
// FUSED logits+softmax for patient-dst relations: one wave per dst node.
// lane=(h,j): h head, j edge-slot; computes logits for its segment, reduces
// max & sum via shuffles over lane bits 3..5, writes PRE-NORMALIZED weights
// (wout[i*8+h]; lane offset == lane -> fully coalesced). Fast path deg<=8.
// ---------------------------------------------------------------------------
__global__ __launch_bounds__(256) void edge_softmax_kernel(
    const int* __restrict__ rowptr, const unsigned int* __restrict__ es,
    const unsigned short* __restrict__ q, int ldq,
    const unsigned short* __restrict__ kr,
    const float* __restrict__ prel, float* __restrict__ wout, int nd)
{
    int wid = (blockIdx.x * 256 + threadIdx.x) >> 6;   // wave id == dst node
    int lane = threadIdx.x & 63;
    if (wid >= nd) return;
    int r0 = rowptr[wid], r1 = rowptr[wid + 1];
    int deg = r1 - r0;
    if (deg <= 0) return;
    int h = lane & 7, j = lane >> 3;
    const unsigned short* qrow = q + (size_t)wid * ldq + h * DHEAD;
    float ph = prel[h] * 0.25f;

    if (deg <= 8) {
        bool val = j < deg;
        float a = -1e30f;
        if (val) {
            int sn = es[r0 + j] >> 16;
            a = dot16_bf(qrow, kr + (size_t)sn * CDIM + h * DHEAD) * ph;
        }
        float m = a;
        m = fmaxf(m, __shfl_xor(m, 8));
        m = fmaxf(m, __shfl_xor(m, 16));
        m = fmaxf(m, __shfl_xor(m, 32));
        float e = val ? expf(a - m) : 0.f;
        float s = e;
        s += __shfl_xor(s, 8);
        s += __shfl_xor(s, 16);
        s += __shfl_xor(s, 32);
        float si = (s > 0.f) ? 1.0f / s : 0.f;
        if (val) wout[(size_t)(r0 + j) * NHEAD + h] = e * si;
    } else {
        float m = -1e30f;
        for (int i = r0 + j; i < r1; i += 8) {
            int sn = es[i] >> 16;
            float a = dot16_bf(qrow, kr + (size_t)sn * CDIM + h * DHEAD) * ph;
            wout[(size_t)i * NHEAD + h] = a;
            m = fmaxf(m, a);
        }
        m = fmaxf(m, __shfl_xor(m, 8));
        m = fmaxf(m, __shfl_xor(m, 16));
        m = fmaxf(m, __shfl_xor(m, 32));
        float s = 0.f;
        for (int i = r0 + j; i < r1; i += 8) {
            float e = expf(wout[(size_t)i * NHEAD + h] - m);
            wout[(size_t)i * NHEAD + h] = e;
            s += e;
        }
        s += __shfl_xor(s, 8);
        s += __shfl_xor(s, 16);
        s += __shfl_xor(s, 32);
        float si = (s > 0.f) ? 1.0f / s : 0.f;
        for (int i = r0 + j; i < r1; i += 8)
            wout[(size_t)i * NHEAD + h] *= si;
    }
}

// ---------------------------------------------------------------------------
// Edge-chunk weighted segment sum — stats variant (icd/ndc-dst path)
// ---------------------------------------------------------------------------
__global__ __launch_bounds__(128) void seg_agg_kernel(
    const unsigned int* __restrict__ es,
    const float* __restrict__ alpha_s, const float2* __restrict__ stats,
    const unsigned short* __restrict__ vr, float* __restrict__ agg, int ne)
{
    __shared__ unsigned int sE[EPB];
    __shared__ float sW[EPB][NHEAD];
    int i0 = blockIdx.x * EPB;
    int t  = threadIdx.x;
    int cnt = min(EPB, ne - i0);
    if (t < cnt) {
        unsigned int ed = es[i0 + t];
        sE[t] = ed;
        int dn = ed & 0xFFFFu;
        const float4* ap = (const float4*)(alpha_s + (size_t)(i0 + t) * NHEAD);
        float4 a0 = ap[0], a1 = ap[1];
        float wv[8] = {a0.x, a0.y, a0.z, a0.w, a1.x, a1.y, a1.z, a1.w};
        const float2* st = stats + (size_t)dn * NHEAD;
        #pragma unroll
        for (int h = 0; h < NHEAD; h++) {
            float2 ms = st[h];
            sW[t][h] = expf(wv[h] - ms.x) * ms.y;
        }
    }
    __syncthreads();
    int h = t >> 4;
    float acc = 0.f;
    int curd = (int)(sE[0] & 0xFFFFu);
    for (int i = 0; i < cnt; i++) {
        unsigned int ed = sE[i];
        int d = (int)(ed & 0xFFFFu);
        if (d != curd) {
            atomicAdd(&agg[(size_t)curd * CDIM + t], acc);
            acc = 0.f;
            curd = d;
        }
        acc += b2f(vr[(size_t)(ed >> 16) * CDIM + t]) * sW[i][h];
    }
    atomicAdd(&agg[(size_t)curd * CDIM + t], acc);
}

// ---------------------------------------------------------------------------
// Edge-chunk weighted segment sum — pre-normalized weights (fused path)
// ---------------------------------------------------------------------------
__global__ __launch_bounds__(128) void seg_agg_pre_kernel(
    const unsigned int* __restrict__ es,
    const float* __restrict__ wbuf,
    const unsigned short* __restrict__ vr, float* __restrict__ agg, int ne)
{
    __shared__ unsigned int sE[EPB];
    __shared__ float sW[EPB][NHEAD];
    int i0 = blockIdx.x * EPB;
    int t  = threadIdx.x;
    int cnt = min(EPB, ne - i0);
    if (t < cnt) {
        sE[t] = es[i0 + t];
        const float4* ap = (const float4*)(wbuf + (size_t)(i0 + t) * NHEAD);
        float4 a0 = ap[0], a1 = ap[1];
        sW[t][0] = a0.x; sW[t][1] = a0.y; sW[t][2] = a0.z; sW[t][3] = a0.w;
        sW[t][4] = a1.x; sW[t][5] = a1.y; sW[t][6] = a1.z; sW[t][7] = a1.w;
    }
    __syncthreads();
    int h = t >> 4;
    float acc = 0.f;
    int curd = (int)(sE[0] & 0xFFFFu);
    for (int i = 0; i < cnt; i++) {
        unsigned int ed = sE[i];
        int d = (int)(ed & 0xFFFFu);
        if (d != curd) {
            atomicAdd(&agg[(size_t)curd * CDIM + t], acc);
            acc = 0.f;
            curd = d;
        }
        acc += b2f(vr[(size_t)(ed >> 16) * CDIM + t]) * sW[i][h];
    }
    atomicAdd(&agg[(size_t)curd * CDIM + t], acc);
}

// ---------------------------------------------------------------------------
extern "C" void kernel_launch(void* const* d_in, const int* in_sizes, int n_in,
                              void* d_out, int out_size, void* d_ws, size_t ws_size,
                              hipStream_t stream)
{
    const float* x_patient = (const float*)d_in[0];
    const float* w_in      = (const float*)d_in[1];
    const float* b_in      = (const float*)d_in[2];
    const float* emb_icd   = (const float*)d_in[3];
    const float* emb_ndc   = (const float*)d_in[4];
    const float* kw        = (const float*)d_in[5];
    const float* kbias     = (const float*)d_in[6];
    const float* qw        = (const float*)d_in[7];
    const float* qbias     = (const float*)d_in[8];
    const float* vw        = (const float*)d_in[9];
    const float* vbias     = (const float*)d_in[10];
    const float* aw        = (const float*)d_in[11];
    const float* abias     = (const float*)d_in[12];
    const float* skip      = (const float*)d_in[13];
    const float* a_rel     = (const float*)d_in[14];
    const float* m_rel     = (const float*)d_in[15];
    const float* p_rel     = (const float*)d_in[16];
    const float* w_out     = (const float*)d_in[17];
    const float* b_out     = (const float*)d_in[18];
    const int*   x_icd     = (const int*)d_in[19];
    const int*   x_ndc     = (const int*)d_in[20];
    const int* esrc[4] = {(const int*)d_in[21], (const int*)d_in[23],
                          (const int*)d_in[25], (const int*)d_in[27]};
    const int* edst[4] = {(const int*)d_in[22], (const int*)d_in[24],
                          (const int*)d_in[26], (const int*)d_in[28]};

    const int st_[4] = {0, 1, 0, 2};
    const int dt_[4] = {1, 0, 2, 0};
    const int sizes[3] = {NPAT, NICD, NNDC};

    char* p = (char*)d_ws;
    auto alloc = [&](size_t bytes) -> void* {
        void* r = (void*)p;
        p += (bytes + 255) & ~(size_t)255;
        return r;
    };

    unsigned short *xb[3], *kqv[3];
    for (int t = 0; t < 3; t++) xb[t]  = (unsigned short*)alloc((size_t)sizes[t] * CDIM * 2);
    for (int t = 0; t < 3; t++) kqv[t] = (unsigned short*)alloc((size_t)sizes[t] * 384 * 2);
    float* aggbase = (float*)alloc((size_t)(NPAT + NICD + NNDC) * CDIM * 4);
    float* agg[3];
    agg[0] = aggbase;
    agg[1] = aggbase + (size_t)NPAT * CDIM;
    agg[2] = agg[1] + (size_t)NICD * CDIM;
    unsigned short* krbuf = (unsigned short*)alloc((size_t)NPAT * CDIM * 2);
    unsigned short* vrbuf = (unsigned short*)alloc((size_t)NPAT * CDIM * 2);
    float*  alphabuf = (float*)alloc((size_t)NEDGE * NHEAD * 4);
    float2* statsbuf = (float2*)alloc((size_t)NPAT * NHEAD * 8);
    unsigned int* esbig = (unsigned int*)alloc((size_t)4 * NEDGE * 4);
    int* rowptr[4];
    rowptr[0] = (int*)alloc((size_t)(NICD + 1) * 4);
    rowptr[1] = (int*)alloc((size_t)(NPAT + 1) * 4);
    rowptr[2] = (int*)alloc((size_t)(NNDC + 1) * 4);
    rowptr[3] = (int*)alloc((size_t)(NPAT + 1) * 4);
    int* deg    = (int*)alloc((size_t)NTOT * 4);
    int* cursor = (int*)alloc((size_t)NTOT * 4);
    int* part   = (int*)alloc((size_t)256 * 4);
    unsigned short* Wtkqv = (unsigned short*)alloc((size_t)6 * 384 * 128 * 2);
    unsigned short* Wtaw  = (unsigned short*)alloc((size_t)6 * 128 * 128 * 2);
    unsigned short* Wtin  = (unsigned short*)alloc((size_t)128 * 128 * 2);
    unsigned short* Wtout = (unsigned short*)alloc((size_t)OUTN * 128 * 2);
    float* bkqv = (float*)alloc((size_t)6 * 384 * 4);
    unsigned int* esRel[4];
    for (int r = 0; r < 4; r++) esRel[r] = esbig + (size_t)r * NEDGE;

    auto gemm = [&](const void* A, int a_mode, int lda,
                    const unsigned short* Wt, const float* bias,
                    void* C, int c_mode, int ldc, int M, int N, int act,
                    const unsigned short* xold, int ldx,
                    const float* skipv, int skipidx) {
        dim3 grid((M + 63) / 64, (N + 63) / 64);
        gemm_mfma<<<grid, dim3(256), 0, stream>>>(A, a_mode, lda, Wt, bias,
            C, c_mode, ldc, M, N, act, xold, ldx, skipv, skipidx);
    };

    // ---- weight prep (bf16 transposed) ----
    {
        dim3 g(4, 4, 6);
        wprep_kernel<<<g, 256, 0, stream>>>(kw, Wtkqv, 128, 128,
            (size_t)128 * 128, (size_t)384 * 128, 0);
        wprep_kernel<<<g, 256, 0, stream>>>(qw, Wtkqv, 128, 128,
            (size_t)128 * 128, (size_t)384 * 128, 128);
        wprep_kernel<<<g, 256, 0, stream>>>(vw, Wtkqv, 128, 128,
            (size_t)128 * 128, (size_t)384 * 128, 256);
        wprep_kernel<<<g, 256, 0, stream>>>(aw, Wtaw, 128, 128,
            (size_t)128 * 128, (size_t)128 * 128, 0);
        wprep_kernel<<<dim3(4, 4, 1), 256, 0, stream>>>(w_in, Wtin, 128, 128,
            0, 0, 0);
        wprep_kernel<<<dim3(4, 3, 1), 256, 0, stream>>>(w_out, Wtout, 128, OUTN,
            0, 0, 0);
        biaspack_kernel<<<(6 * 384 + 255) / 256, 256, 0, stream>>>(kbias, qbias, vbias, bkqv);
    }

    // ---- batched CSR build ----
    {
        const int NB = (NTOT + 1023) / 1024;
        hipMemsetAsync(deg, 0, (size_t)NTOT * 4, stream);
        hist4_kernel<<<dim3(64, 4), 256, 0, stream>>>(
            edst[0], edst[1], edst[2], edst[3], deg);
        scanA_kernel<<<NB, 256, 0, stream>>>(deg, part, NTOT);
        scanB_kernel<<<1, 128, 0, stream>>>(part, NB);
        scanC_kernel<<<NB, 256, 0, stream>>>(deg, part,
            rowptr[0], rowptr[1], rowptr[2], rowptr[3], cursor, NTOT);
        scatter_pack_kernel<<<(4 * NEDGE + 255) / 256, 256, 0, stream>>>(
            esrc[0], edst[0], esrc[1], edst[1], esrc[2], edst[2], esrc[3], edst[3],
            cursor, esbig);
    }

    // ---- input projections ----
    gemm(x_patient, 1, 128, Wtin, b_in, xb[0], 0, 128, NPAT, 128, 1, nullptr, 0, nullptr, 0);
    gather_relu_kernel<<<(NICD * CDIM + 255) / 256, 256, 0, stream>>>(emb_icd, x_icd, xb[1], NICD);
    gather_relu_kernel<<<(NNDC * CDIM + 255) / 256, 256, 0, stream>>>(emb_ndc, x_ndc, xb[2], NNDC);

    // ---- layers ----
    for (int l = 0; l < NLAYER; l++) {
        for (int t = 0; t < 3; t++) {
            int wi = l * 3 + t;
            gemm(xb[t], 0, 128, Wtkqv + (size_t)wi * 384 * 128, bkqv + (size_t)wi * 384,
                 kqv[t], 0, 384, sizes[t], 384, 0, nullptr, 0, nullptr, 0);
        }
        hipMemsetAsync(aggbase, 0, (size_t)(NPAT + NICD + NNDC) * CDIM * 4, stream);
        for (int r = 0; r < 4; r++) {
            int s = st_[r], d = dt_[r];
            int ns = sizes[s], nd = sizes[d];
            int grid_rt = min((ns + 1) / 2, 2048);
            rel_transform_kernel<<<dim3(grid_rt, 2), 256, 0, stream>>>(
                kqv[s], a_rel + (size_t)(l * 4 + r) * 2048,
                m_rel + (size_t)(l * 4 + r) * 2048, krbuf, vrbuf, ns);
            if (d == 0) {
                // patient-dst: fused logits+softmax (wave per dst), prenorm weights
                edge_softmax_kernel<<<(nd + 3) / 4, 256, 0, stream>>>(
                    rowptr[r], esRel[r], kqv[d] + 128, 384, krbuf,
                    p_rel + (size_t)(l * 4 + r) * NHEAD, alphabuf, nd);
                seg_agg_pre_kernel<<<(NEDGE + EPB - 1) / EPB, 128, 0, stream>>>(
                    esRel[r], alphabuf, vrbuf, agg[d], NEDGE);
            } else {
                // icd/ndc-dst: too few segments for wave-per-dst logits
                edge_logits_kernel<<<(NEDGE * NHEAD + 255) / 256, 256, 0, stream>>>(
                    esRel[r], kqv[d] + 128, 384, krbuf,
                    p_rel + (size_t)(l * 4 + r) * NHEAD, alphabuf);
                seg_stats_kernel<<<(nd + 3) / 4, 256, 0, stream>>>(
                    rowptr[r], alphabuf, statsbuf, nd);
                seg_agg_kernel<<<(NEDGE + EPB - 1) / EPB, 128, 0, stream>>>(
                    esRel[r], alphabuf, statsbuf, vrbuf, agg[d], NEDGE);
            }
        }
        for (int t = 0; t < 3; t++) {
            int wi = l * 3 + t;
            gemm(agg[t], 2, 128, Wtaw + (size_t)wi * 128 * 128, abias + (size_t)wi * 128,
                 xb[t], 0, 128, sizes[t], 128, 0, xb[t], 128, skip, wi);
        }
    }

    // ---- output head (fp32 out) ----
    gemm(xb[0], 0, 128, Wtout, b_out, d_out, 1, OUTN, NPAT, OUTN, 2, nullptr, 0, nullptr, 0);
}

// Round 9
// 1048.672 us; speedup vs baseline: 1.8207x; 1.1732x over previous
//
#include <hip/hip_runtime.h>
#include <math.h>

#define CDIM  128
#define NHEAD 8
#define DHEAD 16
#define NPAT  50000
#define NICD  591
#define NNDC  2042
#define OUTN  90
#define NEDGE 250000
#define NLAYER 2
#define EPB   128

// concat offsets for CSR build (relation order: pi, ip, pn, np; dst sizes)
#define OFF0  0
#define OFF1  (NICD)
#define OFF2  (NICD + NPAT)
#define OFF3  (NICD + NPAT + NNDC)
#define NTOT  (NICD + NPAT + NNDC + NPAT)

#define LDP 40   // LDS row stride (bf16 elems): 80B rows -> 16B aligned, 2-way-free banks

typedef __attribute__((ext_vector_type(8))) short bf16x8;
typedef __attribute__((ext_vector_type(4))) float f32x4;

__device__ __forceinline__ float gelu_tanh(float x) {
    float x3 = x * x * x;
    return 0.5f * x * (1.0f + tanhf(0.7978845608028654f * (x + 0.044715f * x3)));
}
__device__ __forceinline__ float b2f(unsigned short u) {
    union { unsigned int i; float f; } v; v.i = ((unsigned int)u) << 16; return v.f;
}
__device__ __forceinline__ unsigned short f2b(float f) {
    union { float ff; unsigned int i; } v; v.ff = f;
    unsigned int i = v.i;
    return (unsigned short)((i + 0x7FFFu + ((i >> 16) & 1u)) >> 16);  // RNE
}
__device__ __forceinline__ float2 b2x2(unsigned int u) {
    union { unsigned int i; float f; } lo, hi;
    lo.i = u << 16; hi.i = u & 0xFFFF0000u;
    return make_float2(lo.f, hi.f);
}

// ---------------------------------------------------------------------------
// bf16 MFMA GEMM: D = act(A @ Wt^T + bias), Wt [N][128] bf16.
// ---------------------------------------------------------------------------
__global__ __launch_bounds__(256) void gemm_mfma(
    const void* __restrict__ Ap, int a_mode, int lda,
    const unsigned short* __restrict__ Wt, const float* __restrict__ bias,
    void* __restrict__ Cp, int c_mode, int ldc,
    int M, int N, int act,
    const unsigned short* __restrict__ xold, int ldx,
    const float* __restrict__ skipv, int skipidx)
{
    __shared__ unsigned short Al[64 * LDP];
    __shared__ unsigned short Bl[64 * LDP];
    int bm = blockIdx.x * 64, bn = blockIdx.y * 64;
    int t = threadIdx.x;
    int lane = t & 63, w = t >> 6;
    int wr = w >> 1, wc = w & 1;
    int quad = lane >> 4, lm = lane & 15;
    f32x4 acc[2][2] = {};
    const int srow = t >> 2;
    const int skq  = (t & 3) * 8;

    for (int k0 = 0; k0 < 128; k0 += 32) {
        {
            int row = bm + srow;
            uint4 u = make_uint4(0, 0, 0, 0);
            if (a_mode == 0) {
                if (row < M)
                    u = *(const uint4*)((const unsigned short*)Ap + (size_t)row * lda + k0 + skq);
            } else {
                float f[8] = {0.f,0.f,0.f,0.f,0.f,0.f,0.f,0.f};
                if (row < M) {
                    const float4* ap = (const float4*)((const float*)Ap + (size_t)row * lda + k0 + skq);
                    float4 u0 = ap[0], u1 = ap[1];
                    f[0]=u0.x; f[1]=u0.y; f[2]=u0.z; f[3]=u0.w;
                    f[4]=u1.x; f[5]=u1.y; f[6]=u1.z; f[7]=u1.w;
                    if (a_mode == 2)
                        for (int i = 0; i < 8; i++) f[i] = gelu_tanh(f[i]);
                }
                unsigned short v[8];
                for (int i = 0; i < 8; i++) v[i] = f2b(f[i]);
                u = *(uint4*)v;
            }
            *(uint4*)&Al[srow * LDP + skq] = u;
        }
        {
            int n = bn + srow;
            uint4 u = make_uint4(0, 0, 0, 0);
            if (n < N) u = *(const uint4*)(Wt + (size_t)n * 128 + k0 + skq);
            *(uint4*)&Bl[srow * LDP + skq] = u;
        }
        __syncthreads();
        bf16x8 af[2], bfr[2];
        #pragma unroll
        for (int i = 0; i < 2; i++) {
            af[i]  = *(const bf16x8*)&Al[(wr * 32 + i * 16 + lm) * LDP + quad * 8];
            bfr[i] = *(const bf16x8*)&Bl[(wc * 32 + i * 16 + lm) * LDP + quad * 8];
        }
        acc[0][0] = __builtin_amdgcn_mfma_f32_16x16x32_bf16(af[0], bfr[0], acc[0][0], 0, 0, 0);
        acc[0][1] = __builtin_amdgcn_mfma_f32_16x16x32_bf16(af[0], bfr[1], acc[0][1], 0, 0, 0);
        acc[1][0] = __builtin_amdgcn_mfma_f32_16x16x32_bf16(af[1], bfr[0], acc[1][0], 0, 0, 0);
        acc[1][1] = __builtin_amdgcn_mfma_f32_16x16x32_bf16(af[1], bfr[1], acc[1][1], 0, 0, 0);
        __syncthreads();
    }

    float aSk = 0.f, oneM = 0.f;
    if (skipv) {
        float sv = skipv[skipidx];
        aSk = 1.0f / (1.0f + expf(-sv));
        oneM = 1.0f - aSk;
    }
    #pragma unroll
    for (int tm = 0; tm < 2; tm++)
    #pragma unroll
    for (int tn = 0; tn < 2; tn++)
    #pragma unroll
    for (int r = 0; r < 4; r++) {
        int row = bm + wr * 32 + tm * 16 + quad * 4 + r;
        int col = bn + wc * 32 + tn * 16 + lm;
        if (row >= M || col >= N) continue;
        float v = acc[tm][tn][r] + (bias ? bias[col] : 0.f);
        if (act == 1) v = fmaxf(v, 0.f);
        else if (act == 2) v = 1.0f / (1.0f + expf(-v));
        if (skipv) v = aSk * v + oneM * b2f(xold[(size_t)row * ldx + col]);
        if (c_mode == 0) ((unsigned short*)Cp)[(size_t)row * ldc + col] = f2b(v);
        else             ((float*)Cp)[(size_t)row * ldc + col] = v;
    }
}

// ---------------------------------------------------------------------------
// Weight prep: transpose+convert fp32 [g][K][N] -> bf16 [n+nofs][128]
// ---------------------------------------------------------------------------
__global__ __launch_bounds__(256) void wprep_kernel(
    const float* __restrict__ src, unsigned short* __restrict__ dst,
    int K, int N, size_t sstride, size_t gstride, int nofs)
{
    __shared__ float tile[32][33];
    int g = blockIdx.z;
    int k0 = blockIdx.x * 32, n0 = blockIdx.y * 32;
    int tx = threadIdx.x & 31, ty = threadIdx.x >> 5;
    const float* s = src + (size_t)g * sstride;
    for (int i = 0; i < 32; i += 8) {
        int k = k0 + ty + i, n = n0 + tx;
        tile[ty + i][tx] = (k < K && n < N) ? s[(size_t)k * N + n] : 0.f;
    }
    __syncthreads();
    unsigned short* d = dst + (size_t)g * gstride;
    for (int i = 0; i < 32; i += 8) {
        int n = n0 + ty + i, k = k0 + tx;
        if (n < N && k < K) d[(size_t)(n + nofs) * 128 + k] = f2b(tile[tx][ty + i]);
    }
}

__global__ void biaspack_kernel(const float* __restrict__ kb, const float* __restrict__ qb,
                                const float* __restrict__ vb, float* __restrict__ out) {
    int t = blockIdx.x * blockDim.x + threadIdx.x;
    if (t >= 6 * 384) return;
    int g = t / 384, c = t - g * 384;
    float v = (c < 128) ? kb[g * 128 + c]
            : (c < 256) ? qb[g * 128 + c - 128]
                        : vb[g * 128 + c - 256];
    out[t] = v;
}

// ---------------------------------------------------------------------------
// Histogram: grid (64, 4). icd/ndc relations pre-aggregate in LDS.
// ---------------------------------------------------------------------------
__global__ __launch_bounds__(256) void hist4_kernel(
    const int* __restrict__ d0, const int* __restrict__ d1,
    const int* __restrict__ d2, const int* __restrict__ d3,
    int* __restrict__ deg)
{
    __shared__ int lh[2048];
    int rel = blockIdx.y;
    int t = threadIdx.x;
    const int* dp = (rel == 0) ? d0 : (rel == 1) ? d1 : (rel == 2) ? d2 : d3;
    int off = (rel == 0) ? OFF0 : (rel == 1) ? OFF1 : (rel == 2) ? OFF2 : OFF3;
    if (rel == 1 || rel == 3) {
        for (int e = blockIdx.x * 256 + t; e < NEDGE; e += gridDim.x * 256)
            atomicAdd(&deg[off + dp[e]], 1);
    } else {
        int nb = (rel == 0) ? NICD : NNDC;
        for (int i = t; i < nb; i += 256) lh[i] = 0;
        __syncthreads();
        for (int e = blockIdx.x * 256 + t; e < NEDGE; e += gridDim.x * 256)
            atomicAdd(&lh[dp[e]], 1);
        __syncthreads();
        for (int i = t; i < nb; i += 256) {
            int v = lh[i];
            if (v) atomicAdd(&deg[off + i], v);
        }
    }
}

__global__ __launch_bounds__(256) void scanA_kernel(
    const int* __restrict__ deg, int* __restrict__ part, int n)
{
    __shared__ int red[256];
    int b = blockIdx.x, t = threadIdx.x;
    int base = b * 1024 + t * 4;
    int s = 0;
    if (base + 3 < n) {
        int4 v = *(const int4*)(deg + base);
        s = v.x + v.y + v.z + v.w;
    } else {
        for (int i = 0; i < 4; i++) if (base + i < n) s += deg[base + i];
    }
    red[t] = s;
    __syncthreads();
    for (int o = 128; o; o >>= 1) { if (t < o) red[t] += red[t + o]; __syncthreads(); }
    if (t == 0) part[b] = red[0];
}

__global__ __launch_bounds__(128) void scanB_kernel(int* __restrict__ part, int nb)
{
    __shared__ int s[256];
    int t = threadIdx.x;
    for (int i = t; i < nb; i += 128) s[i] = part[i];
    __syncthreads();
    if (t == 0) { int run = 0; for (int i = 0; i < nb; i++) { int v = s[i]; s[i] = run; run += v; } }
    __syncthreads();
    for (int i = t; i < nb; i += 128) part[i] = s[i];
}

__global__ __launch_bounds__(256) void scanC_kernel(
    const int* __restrict__ deg, const int* __restrict__ part,
    int* __restrict__ rp0, int* __restrict__ rp1,
    int* __restrict__ rp2, int* __restrict__ rp3,
    int* __restrict__ cursor, int n)
{
    __shared__ int red[256];
    int b = blockIdx.x, t = threadIdx.x;
    int base = b * 1024 + t * 4;
    int v[4] = {0, 0, 0, 0};
    if (base + 3 < n) {
        int4 q = *(const int4*)(deg + base);
        v[0] = q.x; v[1] = q.y; v[2] = q.z; v[3] = q.w;
    } else {
        for (int i = 0; i < 4; i++) if (base + i < n) v[i] = deg[base + i];
    }
    red[t] = v[0] + v[1] + v[2] + v[3];
    __syncthreads();
    for (int off = 1; off < 256; off <<= 1) {
        int y = (t >= off) ? red[t - off] : 0;
        __syncthreads();
        red[t] += y;
        __syncthreads();
    }
    int run = part[b] + ((t == 0) ? 0 : red[t - 1]);
    for (int i = 0; i < 4; i++) {
        int g = base + i;
        if (g < n) {
            cursor[g] = run;
            int r, loc;
            if      (g < OFF1) { r = 0; loc = g; }
            else if (g < OFF2) { r = 1; loc = g - OFF1; }
            else if (g < OFF3) { r = 2; loc = g - OFF2; }
            else               { r = 3; loc = g - OFF3; }
            int Sl = run - r * NEDGE;
            ((r == 0) ? rp0 : (r == 1) ? rp1 : (r == 2) ? rp2 : rp3)[loc] = Sl;
            run += v[i];
        }
    }
    if (b == 0 && t == 0) {
        rp0[NICD] = NEDGE; rp1[NPAT] = NEDGE; rp2[NNDC] = NEDGE; rp3[NPAT] = NEDGE;
    }
}

// ---------------------------------------------------------------------------
// Scatter, grid (64, 4). Patient relations (1,3): plain returning atomics.
// icd/ndc (0,2): block-level LDS reservation — count chunk's bins in LDS,
// ONE global atomicAdd per (block,bin) reserves a contiguous range, then
// place edges at base + local rank (LDS atomics). ~3x fewer global atomics.
// ---------------------------------------------------------------------------
__global__ __launch_bounds__(256) void scatter_pack_kernel(
    const int* __restrict__ s0, const int* __restrict__ d0,
    const int* __restrict__ s1, const int* __restrict__ d1,
    const int* __restrict__ s2, const int* __restrict__ d2,
    const int* __restrict__ s3, const int* __restrict__ d3,
    int* __restrict__ cursor, unsigned int* __restrict__ es)
{
    __shared__ int lcnt[2048];
    __shared__ int lbase[2048];
    int rel = blockIdx.y;
    int t = threadIdx.x;
    const int* sp = (rel == 0) ? s0 : (rel == 1) ? s1 : (rel == 2) ? s2 : s3;
    const int* dp = (rel == 0) ? d0 : (rel == 1) ? d1 : (rel == 2) ? d2 : d3;
    int off = (rel == 0) ? OFF0 : (rel == 1) ? OFF1 : (rel == 2) ? OFF2 : OFF3;
    if (rel == 1 || rel == 3) {
        for (int e = blockIdx.x * 256 + t; e < NEDGE; e += gridDim.x * 256) {
            int d = dp[e];
            int p = atomicAdd(&cursor[off + d], 1);
            es[p] = ((unsigned int)sp[e] << 16) | (unsigned int)d;
        }
    } else {
        int nb = (rel == 0) ? NICD : NNDC;
        int per = (NEDGE + gridDim.x - 1) / gridDim.x;
        int e0 = blockIdx.x * per, e1 = min(e0 + per, NEDGE);
        for (int i = t; i < nb; i += 256) lcnt[i] = 0;
        __syncthreads();
        for (int e = e0 + t; e < e1; e += 256) atomicAdd(&lcnt[dp[e]], 1);
        __syncthreads();
        for (int i = t; i < nb; i += 256) {
            int c = lcnt[i];
            lbase[i] = c ? atomicAdd(&cursor[off + i], c) : 0;
            lcnt[i] = 0;
        }
        __syncthreads();
        for (int e = e0 + t; e < e1; e += 256) {
            int d = dp[e];
            int p = lbase[d] + atomicAdd(&lcnt[d], 1);
            es[p] = ((unsigned int)sp[e] << 16) | (unsigned int)d;
        }
    }
}

// ---------------------------------------------------------------------------
// x = relu(emb[idx]) gather -> bf16
// ---------------------------------------------------------------------------
__global__ void gather_relu_kernel(const float* __restrict__ emb,
                                   const int* __restrict__ idx,
                                   unsigned short* __restrict__ out, int n) {
    int t = blockIdx.x * blockDim.x + threadIdx.x;
    if (t < n * CDIM) {
        int r = t >> 7, c = t & 127;
        out[t] = f2b(fmaxf(emb[(size_t)idx[r] * CDIM + c], 0.f));
    }
}

// ---------------------------------------------------------------------------
// Fused relation transform
// ---------------------------------------------------------------------------
__global__ __launch_bounds__(256) void rel_transform_kernel(
    const unsigned short* __restrict__ kqv,
    const float* __restrict__ arel, const float* __restrict__ mrel,
    unsigned short* __restrict__ kr, unsigned short* __restrict__ vr, int n)
{
    __shared__ float aS[2048];
    __shared__ float rowS[2][CDIM];
    int which = blockIdx.y;
    const unsigned short* src = kqv + (which ? 256 : 0);
    const float* am = which ? mrel : arel;
    unsigned short* out = which ? vr : kr;
    int t = threadIdx.x;
    for (int i = t; i < 2048; i += 256) aS[i] = am[i];
    __syncthreads();
    int rl = t >> 7, c = t & 127;
    int h = c >> 4, e = c & 15;
    const float* ah = &aS[h * 256 + e];
    for (int row0 = blockIdx.x * 2; row0 < n; row0 += gridDim.x * 2) {
        int row = row0 + rl;
        rowS[rl][c] = (row < n) ? b2f(src[(size_t)row * 384 + c]) : 0.f;
        __syncthreads();
        float acc = 0.f;
        const float* rp = &rowS[rl][h * 16];
        #pragma unroll
        for (int dd = 0; dd < 16; ++dd) acc += rp[dd] * ah[dd * 16];
        if (row < n) out[(size_t)row * CDIM + c] = f2b(acc);
        __syncthreads();
    }
}

__device__ __forceinline__ float dot16_bf(const unsigned short* a,
                                          const unsigned short* b) {
    const uint4* ap = (const uint4*)a;
    const uint4* bp = (const uint4*)b;
    uint4 a0 = ap[0], a1 = ap[1], b0 = bp[0], b1 = bp[1];
    unsigned int au[8] = {a0.x, a0.y, a0.z, a0.w, a1.x, a1.y, a1.z, a1.w};
    unsigned int bu[8] = {b0.x, b0.y, b0.z, b0.w, b1.x, b1.y, b1.z, b1.w};
    float acc = 0.f;
    #pragma unroll
    for (int j = 0; j < 8; j++) {
        float2 x = b2x2(au[j]), y = b2x2(bu[j]);
        acc += x.x * y.x + x.y * y.y;
    }
    return acc;
}

// ---------------------------------------------------------------------------
// Per-edge logits (icd/ndc-dst path)
// ---------------------------------------------------------------------------
__global__ __launch_bounds__(256) void edge_logits_kernel(
    const unsigned int* __restrict__ es,
    const unsigned short* __restrict__ q, int ldq,
    const unsigned short* __restrict__ kr,
    const float* __restrict__ prel, float* __restrict__ alpha_s)
{
    int t = blockIdx.x * blockDim.x + threadIdx.x;
    if (t >= NEDGE * NHEAD) return;
    int i = t >> 3, h = t & 7;
    unsigned int ed = es[i];
    int dn = ed & 0xFFFFu, sn = ed >> 16;
    float acc = dot16_bf(q + (size_t)dn * ldq + h * DHEAD,
                         kr + (size_t)sn * CDIM + h * DHEAD);
    alpha_s[t] = acc * prel[h] * 0.25f;
}

__global__ __launch_bounds__(256) void seg_stats_kernel(
    const int* __restrict__ rowptr, const float* __restrict__ alpha_s,
    float2* __restrict__ stats, int nd)
{
    int wid = (blockIdx.x * 256 + threadIdx.x) >> 6;
    int lane = threadIdx.x & 63;
    if (wid >= nd) return;
    int r0 = rowptr[wid], r1 = rowptr[wid + 1];
    int h = lane & 7, j = lane >> 3;
    float mx = -1e30f;
    for (int i = r0 + j; i < r1; i += 8)
        mx = fmaxf(mx, alpha_s[(size_t)i * NHEAD + h]);
    mx = fmaxf(mx, __shfl_xor(mx, 8));
    mx = fmaxf(mx, __shfl_xor(mx, 16));
    mx = fmaxf(mx, __shfl_xor(mx, 32));
    float sm = 0.f;
    for (int i = r0 + j; i < r1; i += 8)
        sm += expf(alpha_s[(size_t)i * NHEAD + h] - mx);
    sm += __shfl_xor(sm, 8);
    sm += __shfl_xor(sm, 16);
    sm += __shfl_xor(sm, 32);
    if (j == 0)
        stats[(size_t)wid * NHEAD + h] = make_float2(mx, (sm > 0.f) ? 1.0f / sm : 0.f);
}

// ---------------------------------------------------------------------------
// FULLY FUSED patient-dst path: one wave per dst node does logits + softmax
// + aggregation. Weights staged in LDS (deg<=64 — always true here; rare
// fallback recomputes). Phase 2: lane owns channels (2*lane, 2*lane+1); vr
// row read is one coalesced 4B word/lane; agg updated with a NON-ATOMIC
// read-modify-write (exactly one wave owns each dst; dispatches serialized).
// ---------------------------------------------------------------------------
__global__ __launch_bounds__(256) void edge_softmax_agg_kernel(
    const int* __restrict__ rowptr, const unsigned int* __restrict__ es,
    const unsigned short* __restrict__ q, int ldq,
    const unsigned short* __restrict__ kr, const unsigned short* __restrict__ vr,
    const float* __restrict__ prel, float* __restrict__ agg, int nd)
{
    __shared__ float wls[4][64 * NHEAD];   // 8 KB
    int wv  = threadIdx.x >> 6;
    int wid = (blockIdx.x * 256 + threadIdx.x) >> 6;   // wave id == dst node
    int lane = threadIdx.x & 63;
    if (wid >= nd) return;
    int r0 = rowptr[wid], r1 = rowptr[wid + 1];
    int deg = r1 - r0;
    if (deg <= 0) return;
    float* wl = wls[wv];
    int h = lane & 7, j = lane >> 3;
    const unsigned short* qrow = q + (size_t)wid * ldq + h * DHEAD;
    float ph = prel[h] * 0.25f;
    bool small = (deg <= 64);

    // phase 1: logits + softmax stats (lane = (h, j))
    float m = -1e30f;
    for (int i = j; i < deg; i += 8) {
        int sn = es[r0 + i] >> 16;
        float a = dot16_bf(qrow, kr + (size_t)sn * CDIM + h * DHEAD) * ph;
        if (small) wl[i * NHEAD + h] = a;
        m = fmaxf(m, a);
    }
    m = fmaxf(m, __shfl_xor(m, 8));
    m = fmaxf(m, __shfl_xor(m, 16));
    m = fmaxf(m, __shfl_xor(m, 32));
    float s = 0.f;
    for (int i = j; i < deg; i += 8) {
        float a;
        if (small) a = wl[i * NHEAD + h];
        else {
            int sn = es[r0 + i] >> 16;
            a = dot16_bf(qrow, kr + (size_t)sn * CDIM + h * DHEAD) * ph;
        }
        float e = expf(a - m);
        if (small) wl[i * NHEAD + h] = e;
        s += e;
    }
    s += __shfl_xor(s, 8);
    s += __shfl_xor(s, 16);
    s += __shfl_xor(s, 32);
    float si = (s > 0.f) ? 1.0f / s : 0.f;
    if (small)
        for (int i = j; i < deg; i += 8)
            wl[i * NHEAD + h] *= si;

    // phase 2: aggregation. lane -> channels c0=2*lane, c1=2*lane+1 (head hc)
    int hc = lane >> 3;
    float m_hc  = __shfl(m, hc);
    float si_hc = __shfl(si, hc);
    float ph_hc = __shfl(ph, hc);
    const unsigned short* qrow_hc = q + (size_t)wid * ldq + hc * DHEAD;
    float acc0 = 0.f, acc1 = 0.f;
    for (int i = 0; i < deg; i++) {
        unsigned int sv = es[r0 + i] >> 16;
        unsigned int pv = *(const unsigned int*)(vr + (size_t)sv * CDIM + 2 * lane);
        float2 v = b2x2(pv);
        float wgt;
        if (small) wgt = wl[i * NHEAD + hc];
        else {
            float a = dot16_bf(qrow_hc, kr + (size_t)sv * CDIM + hc * DHEAD) * ph_hc;
            wgt = expf(a - m_hc) * si_hc;
        }
        acc0 += wgt * v.x;
        acc1 += wgt * v.y;
    }
    float2* ap = (float2*)(agg + (size_t)wid * CDIM + 2 * lane);
    float2 old = *ap;
    *ap = make_float2(old.x + acc0, old.y + acc1);
}

// ---------------------------------------------------------------------------
// Edge-chunk weighted segment sum — stats variant (icd/ndc-dst path)
// ---------------------------------------------------------------------------
__global__ __launch_bounds__(128) void seg_agg_kernel(
    const unsigned int* __restrict__ es,
    const float* __restrict__ alpha_s, const float2* __restrict__ stats,
    const unsigned short* __restrict__ vr, float* __restrict__ agg, int ne)
{
    __shared__ unsigned int sE[EPB];
    __shared__ float sW[EPB][NHEAD];
    int i0 = blockIdx.x * EPB;
    int t  = threadIdx.x;
    int cnt = min(EPB, ne - i0);
    if (t < cnt) {
        unsigned int ed = es[i0 + t];
        sE[t] = ed;
        int dn = ed & 0xFFFFu;
        const float4* ap = (const float4*)(alpha_s + (size_t)(i0 + t) * NHEAD);
        float4 a0 = ap[0], a1 = ap[1];
        float wv[8] = {a0.x, a0.y, a0.z, a0.w, a1.x, a1.y, a1.z, a1.w};
        const float2* st = stats + (size_t)dn * NHEAD;
        #pragma unroll
        for (int h = 0; h < NHEAD; h++) {
            float2 ms = st[h];
            sW[t][h] = expf(wv[h] - ms.x) * ms.y;
        }
    }
    __syncthreads();
    int h = t >> 4;
    float acc = 0.f;
    int curd = (int)(sE[0] & 0xFFFFu);
    for (int i = 0; i < cnt; i++) {
        unsigned int ed = sE[i];
        int d = (int)(ed & 0xFFFFu);
        if (d != curd) {
            atomicAdd(&agg[(size_t)curd * CDIM + t], acc);
            acc = 0.f;
            curd = d;
        }
        acc += b2f(vr[(size_t)(ed >> 16) * CDIM + t]) * sW[i][h];
    }
    atomicAdd(&agg[(size_t)curd * CDIM + t], acc);
}

// ---------------------------------------------------------------------------
extern "C" void kernel_launch(void* const* d_in, const int* in_sizes, int n_in,
                              void* d_out, int out_size, void* d_ws, size_t ws_size,
                              hipStream_t stream)
{
    const float* x_patient = (const float*)d_in[0];
    const float* w_in      = (const float*)d_in[1];
    const float* b_in      = (const float*)d_in[2];
    const float* emb_icd   = (const float*)d_in[3];
    const float* emb_ndc   = (const float*)d_in[4];
    const float* kw        = (const float*)d_in[5];
    const float* kbias     = (const float*)d_in[6];
    const float* qw        = (const float*)d_in[7];
    const float* qbias     = (const float*)d_in[8];
    const float* vw        = (const float*)d_in[9];
    const float* vbias     = (const float*)d_in[10];
    const float* aw        = (const float*)d_in[11];
    const float* abias     = (const float*)d_in[12];
    const float* skip      = (const float*)d_in[13];
    const float* a_rel     = (const float*)d_in[14];
    const float* m_rel     = (const float*)d_in[15];
    const float* p_rel     = (const float*)d_in[16];
    const float* w_out     = (const float*)d_in[17];
    const float* b_out     = (const float*)d_in[18];
    const int*   x_icd     = (const int*)d_in[19];
    const int*   x_ndc     = (const int*)d_in[20];
    const int* esrc[4] = {(const int*)d_in[21], (const int*)d_in[23],
                          (const int*)d_in[25], (const int*)d_in[27]};
    const int* edst[4] = {(const int*)d_in[22], (const int*)d_in[24],
                          (const int*)d_in[26], (const int*)d_in[28]};

    const int st_[4] = {0, 1, 0, 2};
    const int dt_[4] = {1, 0, 2, 0};
    const int sizes[3] = {NPAT, NICD, NNDC};

    char* p = (char*)d_ws;
    auto alloc = [&](size_t bytes) -> void* {
        void* r = (void*)p;
        p += (bytes + 255) & ~(size_t)255;
        return r;
    };

    unsigned short *xb[3], *kqv[3];
    for (int t = 0; t < 3; t++) xb[t]  = (unsigned short*)alloc((size_t)sizes[t] * CDIM * 2);
    for (int t = 0; t < 3; t++) kqv[t] = (unsigned short*)alloc((size_t)sizes[t] * 384 * 2);
    float* aggbase = (float*)alloc((size_t)(NPAT + NICD + NNDC) * CDIM * 4);
    float* agg[3];
    agg[0] = aggbase;
    agg[1] = aggbase + (size_t)NPAT * CDIM;
    agg[2] = agg[1] + (size_t)NICD * CDIM;
    unsigned short* krbuf = (unsigned short*)alloc((size_t)NPAT * CDIM * 2);
    unsigned short* vrbuf = (unsigned short*)alloc((size_t)NPAT * CDIM * 2);
    float*  alphabuf = (float*)alloc((size_t)NEDGE * NHEAD * 4);
    float2* statsbuf = (float2*)alloc((size_t)NPAT * NHEAD * 8);
    unsigned int* esbig = (unsigned int*)alloc((size_t)4 * NEDGE * 4);
    int* rowptr[4];
    rowptr[0] = (int*)alloc((size_t)(NICD + 1) * 4);
    rowptr[1] = (int*)alloc((size_t)(NPAT + 1) * 4);
    rowptr[2] = (int*)alloc((size_t)(NNDC + 1) * 4);
    rowptr[3] = (int*)alloc((size_t)(NPAT + 1) * 4);
    int* deg    = (int*)alloc((size_t)NTOT * 4);
    int* cursor = (int*)alloc((size_t)NTOT * 4);
    int* part   = (int*)alloc((size_t)256 * 4);
    unsigned short* Wtkqv = (unsigned short*)alloc((size_t)6 * 384 * 128 * 2);
    unsigned short* Wtaw  = (unsigned short*)alloc((size_t)6 * 128 * 128 * 2);
    unsigned short* Wtin  = (unsigned short*)alloc((size_t)128 * 128 * 2);
    unsigned short* Wtout = (unsigned short*)alloc((size_t)OUTN * 128 * 2);
    float* bkqv = (float*)alloc((size_t)6 * 384 * 4);
    unsigned int* esRel[4];
    for (int r = 0; r < 4; r++) esRel[r] = esbig + (size_t)r * NEDGE;

    auto gemm = [&](const void* A, int a_mode, int lda,
                    const unsigned short* Wt, const float* bias,
                    void* C, int c_mode, int ldc, int M, int N, int act,
                    const unsigned short* xold, int ldx,
                    const float* skipv, int skipidx) {
        dim3 grid((M + 63) / 64, (N + 63) / 64);
        gemm_mfma<<<grid, dim3(256), 0, stream>>>(A, a_mode, lda, Wt, bias,
            C, c_mode, ldc, M, N, act, xold, ldx, skipv, skipidx);
    };

    // ---- weight prep (bf16 transposed) ----
    {
        dim3 g(4, 4, 6);
        wprep_kernel<<<g, 256, 0, stream>>>(kw, Wtkqv, 128, 128,
            (size_t)128 * 128, (size_t)384 * 128, 0);
        wprep_kernel<<<g, 256, 0, stream>>>(qw, Wtkqv, 128, 128,
            (size_t)128 * 128, (size_t)384 * 128, 128);
        wprep_kernel<<<g, 256, 0, stream>>>(vw, Wtkqv, 128, 128,
            (size_t)128 * 128, (size_t)384 * 128, 256);
        wprep_kernel<<<g, 256, 0, stream>>>(aw, Wtaw, 128, 128,
            (size_t)128 * 128, (size_t)128 * 128, 0);
        wprep_kernel<<<dim3(4, 4, 1), 256, 0, stream>>>(w_in, Wtin, 128, 128,
            0, 0, 0);
        wprep_kernel<<<dim3(4, 3, 1), 256, 0, stream>>>(w_out, Wtout, 128, OUTN,
            0, 0, 0);
        biaspack_kernel<<<(6 * 384 + 255) / 256, 256, 0, stream>>>(kbias, qbias, vbias, bkqv);
    }

    // ---- batched CSR build ----
    {
        const int NB = (NTOT + 1023) / 1024;
        hipMemsetAsync(deg, 0, (size_t)NTOT * 4, stream);
        hist4_kernel<<<dim3(64, 4), 256, 0, stream>>>(
            edst[0], edst[1], edst[2], edst[3], deg);
        scanA_kernel<<<NB, 256, 0, stream>>>(deg, part, NTOT);
        scanB_kernel<<<1, 128, 0, stream>>>(part, NB);
        scanC_kernel<<<NB, 256, 0, stream>>>(deg, part,
            rowptr[0], rowptr[1], rowptr[2], rowptr[3], cursor, NTOT);
        scatter_pack_kernel<<<dim3(64, 4), 256, 0, stream>>>(
            esrc[0], edst[0], esrc[1], edst[1], esrc[2], edst[2], esrc[3], edst[3],
            cursor, esbig);
    }

    // ---- input projections ----
    gemm(x_patient, 1, 128, Wtin, b_in, xb[0], 0, 128, NPAT, 128, 1, nullptr, 0, nullptr, 0);
    gather_relu_kernel<<<(NICD * CDIM + 255) / 256, 256, 0, stream>>>(emb_icd, x_icd, xb[1], NICD);
    gather_relu_kernel<<<(NNDC * CDIM + 255) / 256, 256, 0, stream>>>(emb_ndc, x_ndc, xb[2], NNDC);

    // ---- layers ----
    for (int l = 0; l < NLAYER; l++) {
        for (int t = 0; t < 3; t++) {
            int wi = l * 3 + t;
            gemm(xb[t], 0, 128, Wtkqv + (size_t)wi * 384 * 128, bkqv + (size_t)wi * 384,
                 kqv[t], 0, 384, sizes[t], 384, 0, nullptr, 0, nullptr, 0);
        }
        hipMemsetAsync(aggbase, 0, (size_t)(NPAT + NICD + NNDC) * CDIM * 4, stream);
        for (int r = 0; r < 4; r++) {
            int s = st_[r], d = dt_[r];
            int ns = sizes[s], nd = sizes[d];
            int grid_rt = min((ns + 1) / 2, 2048);
            rel_transform_kernel<<<dim3(grid_rt, 2), 256, 0, stream>>>(
                kqv[s], a_rel + (size_t)(l * 4 + r) * 2048,
                m_rel + (size_t)(l * 4 + r) * 2048, krbuf, vrbuf, ns);
            if (d == 0) {
                // patient-dst: fully fused logits+softmax+aggregation
                edge_softmax_agg_kernel<<<(nd + 3) / 4, 256, 0, stream>>>(
                    rowptr[r], esRel[r], kqv[d] + 128, 384, krbuf, vrbuf,
                    p_rel + (size_t)(l * 4 + r) * NHEAD, agg[d], nd);
            } else {
                edge_logits_kernel<<<(NEDGE * NHEAD + 255) / 256, 256, 0, stream>>>(
                    esRel[r], kqv[d] + 128, 384, krbuf,
                    p_rel + (size_t)(l * 4 + r) * NHEAD, alphabuf);
                seg_stats_kernel<<<(nd + 3) / 4, 256, 0, stream>>>(
                    rowptr[r], alphabuf, statsbuf, nd);
                seg_agg_kernel<<<(NEDGE + EPB - 1) / EPB, 128, 0, stream>>>(
                    esRel[r], alphabuf, statsbuf, vrbuf, agg[d], NEDGE);
            }
        }
        for (int t = 0; t < 3; t++) {
            int wi = l * 3 + t;
            gemm(agg[t], 2, 128, Wtaw + (size_t)wi * 128 * 128, abias + (size_t)wi * 128,
                 xb[t], 0, 128, sizes[t], 128, 0, xb[t], 128, skip, wi);
        }
    }

    // ---- output head (fp32 out) ----
    gemm(xb[0], 0, 128, Wtout, b_out, d_out, 1, OUTN, NPAT, OUTN, 2, nullptr, 0, nullptr, 0);
}

// Round 10
// 974.181 us; speedup vs baseline: 1.9599x; 1.0765x over previous
//
#include <hip/hip_runtime.h>
#include <math.h>

#define CDIM  128
#define NHEAD 8
#define DHEAD 16
#define NPAT  50000
#define NICD  591
#define NNDC  2042
#define OUTN  90
#define NEDGE 250000
#define NLAYER 2
#define EPB   64   // edges per block in seg_agg (64 -> 3907 blocks, ~95% grid occupancy)

// concat offsets for CSR build (relation order: pi, ip, pn, np; dst sizes)
#define OFF0  0
#define OFF1  (NICD)
#define OFF2  (NICD + NPAT)
#define OFF3  (NICD + NPAT + NNDC)
#define NTOT  (NICD + NPAT + NNDC + NPAT)

#define LDP 40   // LDS row stride (bf16 elems): 80B rows -> 16B aligned, 2-way-free banks

typedef __attribute__((ext_vector_type(8))) short bf16x8;
typedef __attribute__((ext_vector_type(4))) float f32x4;

__device__ __forceinline__ float gelu_tanh(float x) {
    float x3 = x * x * x;
    return 0.5f * x * (1.0f + tanhf(0.7978845608028654f * (x + 0.044715f * x3)));
}
__device__ __forceinline__ float b2f(unsigned short u) {
    union { unsigned int i; float f; } v; v.i = ((unsigned int)u) << 16; return v.f;
}
__device__ __forceinline__ unsigned short f2b(float f) {
    union { float ff; unsigned int i; } v; v.ff = f;
    unsigned int i = v.i;
    return (unsigned short)((i + 0x7FFFu + ((i >> 16) & 1u)) >> 16);  // RNE
}
__device__ __forceinline__ float2 b2x2(unsigned int u) {
    union { unsigned int i; float f; } lo, hi;
    lo.i = u << 16; hi.i = u & 0xFFFF0000u;
    return make_float2(lo.f, hi.f);
}

// ---------------------------------------------------------------------------
// bf16 MFMA GEMM: D = act(A @ Wt^T + bias), Wt [N][128] bf16.
// ---------------------------------------------------------------------------
__global__ __launch_bounds__(256) void gemm_mfma(
    const void* __restrict__ Ap, int a_mode, int lda,
    const unsigned short* __restrict__ Wt, const float* __restrict__ bias,
    void* __restrict__ Cp, int c_mode, int ldc,
    int M, int N, int act,
    const unsigned short* __restrict__ xold, int ldx,
    const float* __restrict__ skipv, int skipidx)
{
    __shared__ unsigned short Al[64 * LDP];
    __shared__ unsigned short Bl[64 * LDP];
    int bm = blockIdx.x * 64, bn = blockIdx.y * 64;
    int t = threadIdx.x;
    int lane = t & 63, w = t >> 6;
    int wr = w >> 1, wc = w & 1;
    int quad = lane >> 4, lm = lane & 15;
    f32x4 acc[2][2] = {};
    const int srow = t >> 2;
    const int skq  = (t & 3) * 8;

    for (int k0 = 0; k0 < 128; k0 += 32) {
        {
            int row = bm + srow;
            uint4 u = make_uint4(0, 0, 0, 0);
            if (a_mode == 0) {
                if (row < M)
                    u = *(const uint4*)((const unsigned short*)Ap + (size_t)row * lda + k0 + skq);
            } else {
                float f[8] = {0.f,0.f,0.f,0.f,0.f,0.f,0.f,0.f};
                if (row < M) {
                    const float4* ap = (const float4*)((const float*)Ap + (size_t)row * lda + k0 + skq);
                    float4 u0 = ap[0], u1 = ap[1];
                    f[0]=u0.x; f[1]=u0.y; f[2]=u0.z; f[3]=u0.w;
                    f[4]=u1.x; f[5]=u1.y; f[6]=u1.z; f[7]=u1.w;
                    if (a_mode == 2)
                        for (int i = 0; i < 8; i++) f[i] = gelu_tanh(f[i]);
                }
                unsigned short v[8];
                for (int i = 0; i < 8; i++) v[i] = f2b(f[i]);
                u = *(uint4*)v;
            }
            *(uint4*)&Al[srow * LDP + skq] = u;
        }
        {
            int n = bn + srow;
            uint4 u = make_uint4(0, 0, 0, 0);
            if (n < N) u = *(const uint4*)(Wt + (size_t)n * 128 + k0 + skq);
            *(uint4*)&Bl[srow * LDP + skq] = u;
        }
        __syncthreads();
        bf16x8 af[2], bfr[2];
        #pragma unroll
        for (int i = 0; i < 2; i++) {
            af[i]  = *(const bf16x8*)&Al[(wr * 32 + i * 16 + lm) * LDP + quad * 8];
            bfr[i] = *(const bf16x8*)&Bl[(wc * 32 + i * 16 + lm) * LDP + quad * 8];
        }
        acc[0][0] = __builtin_amdgcn_mfma_f32_16x16x32_bf16(af[0], bfr[0], acc[0][0], 0, 0, 0);
        acc[0][1] = __builtin_amdgcn_mfma_f32_16x16x32_bf16(af[0], bfr[1], acc[0][1], 0, 0, 0);
        acc[1][0] = __builtin_amdgcn_mfma_f32_16x16x32_bf16(af[1], bfr[0], acc[1][0], 0, 0, 0);
        acc[1][1] = __builtin_amdgcn_mfma_f32_16x16x32_bf16(af[1], bfr[1], acc[1][1], 0, 0, 0);
        __syncthreads();
    }

    float aSk = 0.f, oneM = 0.f;
    if (skipv) {
        float sv = skipv[skipidx];
        aSk = 1.0f / (1.0f + expf(-sv));
        oneM = 1.0f - aSk;
    }
    #pragma unroll
    for (int tm = 0; tm < 2; tm++)
    #pragma unroll
    for (int tn = 0; tn < 2; tn++)
    #pragma unroll
    for (int r = 0; r < 4; r++) {
        int row = bm + wr * 32 + tm * 16 + quad * 4 + r;
        int col = bn + wc * 32 + tn * 16 + lm;
        if (row >= M || col >= N) continue;
        float v = acc[tm][tn][r] + (bias ? bias[col] : 0.f);
        if (act == 1) v = fmaxf(v, 0.f);
        else if (act == 2) v = 1.0f / (1.0f + expf(-v));
        if (skipv) v = aSk * v + oneM * b2f(xold[(size_t)row * ldx + col]);
        if (c_mode == 0) ((unsigned short*)Cp)[(size_t)row * ldc + col] = f2b(v);
        else             ((float*)Cp)[(size_t)row * ldc + col] = v;
    }
}

// ---------------------------------------------------------------------------
// Weight prep: transpose+convert fp32 [g][K][N] -> bf16 [n+nofs][128]
// ---------------------------------------------------------------------------
__global__ __launch_bounds__(256) void wprep_kernel(
    const float* __restrict__ src, unsigned short* __restrict__ dst,
    int K, int N, size_t sstride, size_t gstride, int nofs)
{
    __shared__ float tile[32][33];
    int g = blockIdx.z;
    int k0 = blockIdx.x * 32, n0 = blockIdx.y * 32;
    int tx = threadIdx.x & 31, ty = threadIdx.x >> 5;
    const float* s = src + (size_t)g * sstride;
    for (int i = 0; i < 32; i += 8) {
        int k = k0 + ty + i, n = n0 + tx;
        tile[ty + i][tx] = (k < K && n < N) ? s[(size_t)k * N + n] : 0.f;
    }
    __syncthreads();
    unsigned short* d = dst + (size_t)g * gstride;
    for (int i = 0; i < 32; i += 8) {
        int n = n0 + ty + i, k = k0 + tx;
        if (n < N && k < K) d[(size_t)(n + nofs) * 128 + k] = f2b(tile[tx][ty + i]);
    }
}

__global__ void biaspack_kernel(const float* __restrict__ kb, const float* __restrict__ qb,
                                const float* __restrict__ vb, float* __restrict__ out) {
    int t = blockIdx.x * blockDim.x + threadIdx.x;
    if (t >= 6 * 384) return;
    int g = t / 384, c = t - g * 384;
    float v = (c < 128) ? kb[g * 128 + c]
            : (c < 256) ? qb[g * 128 + c - 128]
                        : vb[g * 128 + c - 256];
    out[t] = v;
}

// ---------------------------------------------------------------------------
// Histogram: grid (64, 4). icd/ndc relations pre-aggregate in LDS.
// ---------------------------------------------------------------------------
__global__ __launch_bounds__(256) void hist4_kernel(
    const int* __restrict__ d0, const int* __restrict__ d1,
    const int* __restrict__ d2, const int* __restrict__ d3,
    int* __restrict__ deg)
{
    __shared__ int lh[2048];
    int rel = blockIdx.y;
    int t = threadIdx.x;
    const int* dp = (rel == 0) ? d0 : (rel == 1) ? d1 : (rel == 2) ? d2 : d3;
    int off = (rel == 0) ? OFF0 : (rel == 1) ? OFF1 : (rel == 2) ? OFF2 : OFF3;
    if (rel == 1 || rel == 3) {
        for (int e = blockIdx.x * 256 + t; e < NEDGE; e += gridDim.x * 256)
            atomicAdd(&deg[off + dp[e]], 1);
    } else {
        int nb = (rel == 0) ? NICD : NNDC;
        for (int i = t; i < nb; i += 256) lh[i] = 0;
        __syncthreads();
        for (int e = blockIdx.x * 256 + t; e < NEDGE; e += gridDim.x * 256)
            atomicAdd(&lh[dp[e]], 1);
        __syncthreads();
        for (int i = t; i < nb; i += 256) {
            int v = lh[i];
            if (v) atomicAdd(&deg[off + i], v);
        }
    }
}

__global__ __launch_bounds__(256) void scanA_kernel(
    const int* __restrict__ deg, int* __restrict__ part, int n)
{
    __shared__ int red[256];
    int b = blockIdx.x, t = threadIdx.x;
    int base = b * 1024 + t * 4;
    int s = 0;
    if (base + 3 < n) {
        int4 v = *(const int4*)(deg + base);
        s = v.x + v.y + v.z + v.w;
    } else {
        for (int i = 0; i < 4; i++) if (base + i < n) s += deg[base + i];
    }
    red[t] = s;
    __syncthreads();
    for (int o = 128; o; o >>= 1) { if (t < o) red[t] += red[t + o]; __syncthreads(); }
    if (t == 0) part[b] = red[0];
}

__global__ __launch_bounds__(128) void scanB_kernel(int* __restrict__ part, int nb)
{
    __shared__ int s[256];
    int t = threadIdx.x;
    for (int i = t; i < nb; i += 128) s[i] = part[i];
    __syncthreads();
    if (t == 0) { int run = 0; for (int i = 0; i < nb; i++) { int v = s[i]; s[i] = run; run += v; } }
    __syncthreads();
    for (int i = t; i < nb; i += 128) part[i] = s[i];
}

__global__ __launch_bounds__(256) void scanC_kernel(
    const int* __restrict__ deg, const int* __restrict__ part,
    int* __restrict__ rp0, int* __restrict__ rp1,
    int* __restrict__ rp2, int* __restrict__ rp3,
    int* __restrict__ cursor, int n)
{
    __shared__ int red[256];
    int b = blockIdx.x, t = threadIdx.x;
    int base = b * 1024 + t * 4;
    int v[4] = {0, 0, 0, 0};
    if (base + 3 < n) {
        int4 q = *(const int4*)(deg + base);
        v[0] = q.x; v[1] = q.y; v[2] = q.z; v[3] = q.w;
    } else {
        for (int i = 0; i < 4; i++) if (base + i < n) v[i] = deg[base + i];
    }
    red[t] = v[0] + v[1] + v[2] + v[3];
    __syncthreads();
    for (int off = 1; off < 256; off <<= 1) {
        int y = (t >= off) ? red[t - off] : 0;
        __syncthreads();
        red[t] += y;
        __syncthreads();
    }
    int run = part[b] + ((t == 0) ? 0 : red[t - 1]);
    for (int i = 0; i < 4; i++) {
        int g = base + i;
        if (g < n) {
            cursor[g] = run;
            int r, loc;
            if      (g < OFF1) { r = 0; loc = g; }
            else if (g < OFF2) { r = 1; loc = g - OFF1; }
            else if (g < OFF3) { r = 2; loc = g - OFF2; }
            else               { r = 3; loc = g - OFF3; }
            int Sl = run - r * NEDGE;
            ((r == 0) ? rp0 : (r == 1) ? rp1 : (r == 2) ? rp2 : rp3)[loc] = Sl;
            run += v[i];
        }
    }
    if (b == 0 && t == 0) {
        rp0[NICD] = NEDGE; rp1[NPAT] = NEDGE; rp2[NNDC] = NEDGE; rp3[NPAT] = NEDGE;
    }
}

// ---------------------------------------------------------------------------
// Scatter, grid (64, 4). Patient relations: plain. icd/ndc: LDS reservation.
// ---------------------------------------------------------------------------
__global__ __launch_bounds__(256) void scatter_pack_kernel(
    const int* __restrict__ s0, const int* __restrict__ d0,
    const int* __restrict__ s1, const int* __restrict__ d1,
    const int* __restrict__ s2, const int* __restrict__ d2,
    const int* __restrict__ s3, const int* __restrict__ d3,
    int* __restrict__ cursor, unsigned int* __restrict__ es)
{
    __shared__ int lcnt[2048];
    __shared__ int lbase[2048];
    int rel = blockIdx.y;
    int t = threadIdx.x;
    const int* sp = (rel == 0) ? s0 : (rel == 1) ? s1 : (rel == 2) ? s2 : s3;
    const int* dp = (rel == 0) ? d0 : (rel == 1) ? d1 : (rel == 2) ? d2 : d3;
    int off = (rel == 0) ? OFF0 : (rel == 1) ? OFF1 : (rel == 2) ? OFF2 : OFF3;
    if (rel == 1 || rel == 3) {
        for (int e = blockIdx.x * 256 + t; e < NEDGE; e += gridDim.x * 256) {
            int d = dp[e];
            int p = atomicAdd(&cursor[off + d], 1);
            es[p] = ((unsigned int)sp[e] << 16) | (unsigned int)d;
        }
    } else {
        int nb = (rel == 0) ? NICD : NNDC;
        int per = (NEDGE + gridDim.x - 1) / gridDim.x;
        int e0 = blockIdx.x * per, e1 = min(e0 + per, NEDGE);
        for (int i = t; i < nb; i += 256) lcnt[i] = 0;
        __syncthreads();
        for (int e = e0 + t; e < e1; e += 256) atomicAdd(&lcnt[dp[e]], 1);
        __syncthreads();
        for (int i = t; i < nb; i += 256) {
            int c = lcnt[i];
            lbase[i] = c ? atomicAdd(&cursor[off + i], c) : 0;
            lcnt[i] = 0;
        }
        __syncthreads();
        for (int e = e0 + t; e < e1; e += 256) {
            int d = dp[e];
            int p = lbase[d] + atomicAdd(&lcnt[d], 1);
            es[p] = ((unsigned int)sp[e] << 16) | (unsigned int)d;
        }
    }
}

// ---------------------------------------------------------------------------
// x = relu(emb[idx]) gather -> bf16
// ---------------------------------------------------------------------------
__global__ void gather_relu_kernel(const float* __restrict__ emb,
                                   const int* __restrict__ idx,
                                   unsigned short* __restrict__ out, int n) {
    int t = blockIdx.x * blockDim.x + threadIdx.x;
    if (t < n * CDIM) {
        int r = t >> 7, c = t & 127;
        out[t] = f2b(fmaxf(emb[(size_t)idx[r] * CDIM + c], 0.f));
    }
}

// ---------------------------------------------------------------------------
// Fused relation transform
// ---------------------------------------------------------------------------
__global__ __launch_bounds__(256) void rel_transform_kernel(
    const unsigned short* __restrict__ kqv,
    const float* __restrict__ arel, const float* __restrict__ mrel,
    unsigned short* __restrict__ kr, unsigned short* __restrict__ vr, int n)
{
    __shared__ float aS[2048];
    __shared__ float rowS[2][CDIM];
    int which = blockIdx.y;
    const unsigned short* src = kqv + (which ? 256 : 0);
    const float* am = which ? mrel : arel;
    unsigned short* out = which ? vr : kr;
    int t = threadIdx.x;
    for (int i = t; i < 2048; i += 256) aS[i] = am[i];
    __syncthreads();
    int rl = t >> 7, c = t & 127;
    int h = c >> 4, e = c & 15;
    const float* ah = &aS[h * 256 + e];
    for (int row0 = blockIdx.x * 2; row0 < n; row0 += gridDim.x * 2) {
        int row = row0 + rl;
        rowS[rl][c] = (row < n) ? b2f(src[(size_t)row * 384 + c]) : 0.f;
        __syncthreads();
        float acc = 0.f;
        const float* rp = &rowS[rl][h * 16];
        #pragma unroll
        for (int dd = 0; dd < 16; ++dd) acc += rp[dd] * ah[dd * 16];
        if (row < n) out[(size_t)row * CDIM + c] = f2b(acc);
        __syncthreads();
    }
}

__device__ __forceinline__ float dot16_bf(const unsigned short* a,
                                          const unsigned short* b) {
    const uint4* ap = (const uint4*)a;
    const uint4* bp = (const uint4*)b;
    uint4 a0 = ap[0], a1 = ap[1], b0 = bp[0], b1 = bp[1];
    unsigned int au[8] = {a0.x, a0.y, a0.z, a0.w, a1.x, a1.y, a1.z, a1.w};
    unsigned int bu[8] = {b0.x, b0.y, b0.z, b0.w, b1.x, b1.y, b1.z, b1.w};
    float acc = 0.f;
    #pragma unroll
    for (int j = 0; j < 8; j++) {
        float2 x = b2x2(au[j]), y = b2x2(bu[j]);
        acc += x.x * y.x + x.y * y.y;
    }
    return acc;
}

// ---------------------------------------------------------------------------
// Per-edge logits (icd/ndc-dst path)
// ---------------------------------------------------------------------------
__global__ __launch_bounds__(256) void edge_logits_kernel(
    const unsigned int* __restrict__ es,
    const unsigned short* __restrict__ q, int ldq,
    const unsigned short* __restrict__ kr,
    const float* __restrict__ prel, float* __restrict__ alpha_s)
{
    int t = blockIdx.x * blockDim.x + threadIdx.x;
    if (t >= NEDGE * NHEAD) return;
    int i = t >> 3, h = t & 7;
    unsigned int ed = es[i];
    int dn = ed & 0xFFFFu, sn = ed >> 16;
    float acc = dot16_bf(q + (size_t)dn * ldq + h * DHEAD,
                         kr + (size_t)sn * CDIM + h * DHEAD);
    alpha_s[t] = acc * prel[h] * 0.25f;
}

__global__ __launch_bounds__(256) void seg_stats_kernel(
    const int* __restrict__ rowptr, const float* __restrict__ alpha_s,
    float2* __restrict__ stats, int nd)
{
    int wid = (blockIdx.x * 256 + threadIdx.x) >> 6;
    int lane = threadIdx.x & 63;
    if (wid >= nd) return;
    int r0 = rowptr[wid], r1 = rowptr[wid + 1];
    int h = lane & 7, j = lane >> 3;
    float mx = -1e30f;
    for (int i = r0 + j; i < r1; i += 8)
        mx = fmaxf(mx, alpha_s[(size_t)i * NHEAD + h]);
    mx = fmaxf(mx, __shfl_xor(mx, 8));
    mx = fmaxf(mx, __shfl_xor(mx, 16));
    mx = fmaxf(mx, __shfl_xor(mx, 32));
    float sm = 0.f;
    for (int i = r0 + j; i < r1; i += 8)
        sm += expf(alpha_s[(size_t)i * NHEAD + h] - mx);
    sm += __shfl_xor(sm, 8);
    sm += __shfl_xor(sm, 16);
    sm += __shfl_xor(sm, 32);
    if (j == 0)
        stats[(size_t)wid * NHEAD + h] = make_float2(mx, (sm > 0.f) ? 1.0f / sm : 0.f);
}

// ---------------------------------------------------------------------------
// FULLY FUSED patient-dst path (unchanged from round 8)
// ---------------------------------------------------------------------------
__global__ __launch_bounds__(256) void edge_softmax_agg_kernel(
    const int* __restrict__ rowptr, const unsigned int* __restrict__ es,
    const unsigned short* __restrict__ q, int ldq,
    const unsigned short* __restrict__ kr, const unsigned short* __restrict__ vr,
    const float* __restrict__ prel, float* __restrict__ agg, int nd)
{
    __shared__ float wls[4][64 * NHEAD];   // 8 KB
    int wv  = threadIdx.x >> 6;
    int wid = (blockIdx.x * 256 + threadIdx.x) >> 6;   // wave id == dst node
    int lane = threadIdx.x & 63;
    if (wid >= nd) return;
    int r0 = rowptr[wid], r1 = rowptr[wid + 1];
    int deg = r1 - r0;
    if (deg <= 0) return;
    float* wl = wls[wv];
    int h = lane & 7, j = lane >> 3;
    const unsigned short* qrow = q + (size_t)wid * ldq + h * DHEAD;
    float ph = prel[h] * 0.25f;
    bool small = (deg <= 64);

    float m = -1e30f;
    for (int i = j; i < deg; i += 8) {
        int sn = es[r0 + i] >> 16;
        float a = dot16_bf(qrow, kr + (size_t)sn * CDIM + h * DHEAD) * ph;
        if (small) wl[i * NHEAD + h] = a;
        m = fmaxf(m, a);
    }
    m = fmaxf(m, __shfl_xor(m, 8));
    m = fmaxf(m, __shfl_xor(m, 16));
    m = fmaxf(m, __shfl_xor(m, 32));
    float s = 0.f;
    for (int i = j; i < deg; i += 8) {
        float a;
        if (small) a = wl[i * NHEAD + h];
        else {
            int sn = es[r0 + i] >> 16;
            a = dot16_bf(qrow, kr + (size_t)sn * CDIM + h * DHEAD) * ph;
        }
        float e = expf(a - m);
        if (small) wl[i * NHEAD + h] = e;
        s += e;
    }
    s += __shfl_xor(s, 8);
    s += __shfl_xor(s, 16);
    s += __shfl_xor(s, 32);
    float si = (s > 0.f) ? 1.0f / s : 0.f;
    if (small)
        for (int i = j; i < deg; i += 8)
            wl[i * NHEAD + h] *= si;

    int hc = lane >> 3;
    float m_hc  = __shfl(m, hc);
    float si_hc = __shfl(si, hc);
    float ph_hc = __shfl(ph, hc);
    const unsigned short* qrow_hc = q + (size_t)wid * ldq + hc * DHEAD;
    float acc0 = 0.f, acc1 = 0.f;
    for (int i = 0; i < deg; i++) {
        unsigned int sv = es[r0 + i] >> 16;
        unsigned int pv = *(const unsigned int*)(vr + (size_t)sv * CDIM + 2 * lane);
        float2 v = b2x2(pv);
        float wgt;
        if (small) wgt = wl[i * NHEAD + hc];
        else {
            float a = dot16_bf(qrow_hc, kr + (size_t)sv * CDIM + hc * DHEAD) * ph_hc;
            wgt = expf(a - m_hc) * si_hc;
        }
        acc0 += wgt * v.x;
        acc1 += wgt * v.y;
    }
    float2* ap = (float2*)(agg + (size_t)wid * CDIM + 2 * lane);
    float2 old = *ap;
    *ap = make_float2(old.x + acc0, old.y + acc1);
}

// ---------------------------------------------------------------------------
// Edge-chunk weighted segment sum — stats variant (icd/ndc-dst path).
// EPB=64: 3907 blocks (95% grid occupancy), 64-iter gather chain, sW padded
// to 9 floats to kill 4-way LDS write conflicts.
// ---------------------------------------------------------------------------
__global__ __launch_bounds__(128) void seg_agg_kernel(
    const unsigned int* __restrict__ es,
    const float* __restrict__ alpha_s, const float2* __restrict__ stats,
    const unsigned short* __restrict__ vr, float* __restrict__ agg, int ne)
{
    __shared__ unsigned int sE[EPB];
    __shared__ float sW[EPB][NHEAD + 1];
    int i0 = blockIdx.x * EPB;
    int t  = threadIdx.x;
    int cnt = min(EPB, ne - i0);
    if (t < cnt) {
        unsigned int ed = es[i0 + t];
        sE[t] = ed;
        int dn = ed & 0xFFFFu;
        const float4* ap = (const float4*)(alpha_s + (size_t)(i0 + t) * NHEAD);
        float4 a0 = ap[0], a1 = ap[1];
        float wv[8] = {a0.x, a0.y, a0.z, a0.w, a1.x, a1.y, a1.z, a1.w};
        const float2* st = stats + (size_t)dn * NHEAD;
        #pragma unroll
        for (int h = 0; h < NHEAD; h++) {
            float2 ms = st[h];
            sW[t][h] = expf(wv[h] - ms.x) * ms.y;
        }
    }
    __syncthreads();
    int h = t >> 4;
    float acc = 0.f;
    int curd = (int)(sE[0] & 0xFFFFu);
    for (int i = 0; i < cnt; i++) {
        unsigned int ed = sE[i];
        int d = (int)(ed & 0xFFFFu);
        if (d != curd) {
            atomicAdd(&agg[(size_t)curd * CDIM + t], acc);
            acc = 0.f;
            curd = d;
        }
        acc += b2f(vr[(size_t)(ed >> 16) * CDIM + t]) * sW[i][h];
    }
    atomicAdd(&agg[(size_t)curd * CDIM + t], acc);
}

// ---------------------------------------------------------------------------
extern "C" void kernel_launch(void* const* d_in, const int* in_sizes, int n_in,
                              void* d_out, int out_size, void* d_ws, size_t ws_size,
                              hipStream_t stream)
{
    const float* x_patient = (const float*)d_in[0];
    const float* w_in      = (const float*)d_in[1];
    const float* b_in      = (const float*)d_in[2];
    const float* emb_icd   = (const float*)d_in[3];
    const float* emb_ndc   = (const float*)d_in[4];
    const float* kw        = (const float*)d_in[5];
    const float* kbias     = (const float*)d_in[6];
    const float* qw        = (const float*)d_in[7];
    const float* qbias     = (const float*)d_in[8];
    const float* vw        = (const float*)d_in[9];
    const float* vbias     = (const float*)d_in[10];
    const float* aw        = (const float*)d_in[11];
    const float* abias     = (const float*)d_in[12];
    const float* skip      = (const float*)d_in[13];
    const float* a_rel     = (const float*)d_in[14];
    const float* m_rel     = (const float*)d_in[15];
    const float* p_rel     = (const float*)d_in[16];
    const float* w_out     = (const float*)d_in[17];
    const float* b_out     = (const float*)d_in[18];
    const int*   x_icd     = (const int*)d_in[19];
    const int*   x_ndc     = (const int*)d_in[20];
    const int* esrc[4] = {(const int*)d_in[21], (const int*)d_in[23],
                          (const int*)d_in[25], (const int*)d_in[27]};
    const int* edst[4] = {(const int*)d_in[22], (const int*)d_in[24],
                          (const int*)d_in[26], (const int*)d_in[28]};

    const int st_[4] = {0, 1, 0, 2};
    const int dt_[4] = {1, 0, 2, 0};
    const int sizes[3] = {NPAT, NICD, NNDC};

    char* p = (char*)d_ws;
    auto alloc = [&](size_t bytes) -> void* {
        void* r = (void*)p;
        p += (bytes + 255) & ~(size_t)255;
        return r;
    };

    unsigned short *xb[3], *kqv[3];
    for (int t = 0; t < 3; t++) xb[t]  = (unsigned short*)alloc((size_t)sizes[t] * CDIM * 2);
    for (int t = 0; t < 3; t++) kqv[t] = (unsigned short*)alloc((size_t)sizes[t] * 384 * 2);
    float* aggbase = (float*)alloc((size_t)(NPAT + NICD + NNDC) * CDIM * 4);
    float* agg[3];
    agg[0] = aggbase;
    agg[1] = aggbase + (size_t)NPAT * CDIM;
    agg[2] = agg[1] + (size_t)NICD * CDIM;
    unsigned short* krbuf = (unsigned short*)alloc((size_t)NPAT * CDIM * 2);
    unsigned short* vrbuf = (unsigned short*)alloc((size_t)NPAT * CDIM * 2);
    float*  alphabuf = (float*)alloc((size_t)NEDGE * NHEAD * 4);
    float2* statsbuf = (float2*)alloc((size_t)NPAT * NHEAD * 8);
    unsigned int* esbig = (unsigned int*)alloc((size_t)4 * NEDGE * 4);
    int* rowptr[4];
    rowptr[0] = (int*)alloc((size_t)(NICD + 1) * 4);
    rowptr[1] = (int*)alloc((size_t)(NPAT + 1) * 4);
    rowptr[2] = (int*)alloc((size_t)(NNDC + 1) * 4);
    rowptr[3] = (int*)alloc((size_t)(NPAT + 1) * 4);
    int* deg    = (int*)alloc((size_t)NTOT * 4);
    int* cursor = (int*)alloc((size_t)NTOT * 4);
    int* part   = (int*)alloc((size_t)256 * 4);
    unsigned short* Wtkqv = (unsigned short*)alloc((size_t)6 * 384 * 128 * 2);
    unsigned short* Wtaw  = (unsigned short*)alloc((size_t)6 * 128 * 128 * 2);
    unsigned short* Wtin  = (unsigned short*)alloc((size_t)128 * 128 * 2);
    unsigned short* Wtout = (unsigned short*)alloc((size_t)OUTN * 128 * 2);
    float* bkqv = (float*)alloc((size_t)6 * 384 * 4);
    unsigned int* esRel[4];
    for (int r = 0; r < 4; r++) esRel[r] = esbig + (size_t)r * NEDGE;

    auto gemm = [&](const void* A, int a_mode, int lda,
                    const unsigned short* Wt, const float* bias,
                    void* C, int c_mode, int ldc, int M, int N, int act,
                    const unsigned short* xold, int ldx,
                    const float* skipv, int skipidx) {
        dim3 grid((M + 63) / 64, (N + 63) / 64);
        gemm_mfma<<<grid, dim3(256), 0, stream>>>(A, a_mode, lda, Wt, bias,
            C, c_mode, ldc, M, N, act, xold, ldx, skipv, skipidx);
    };

    // ---- weight prep (bf16 transposed) ----
    {
        dim3 g(4, 4, 6);
        wprep_kernel<<<g, 256, 0, stream>>>(kw, Wtkqv, 128, 128,
            (size_t)128 * 128, (size_t)384 * 128, 0);
        wprep_kernel<<<g, 256, 0, stream>>>(qw, Wtkqv, 128, 128,
            (size_t)128 * 128, (size_t)384 * 128, 128);
        wprep_kernel<<<g, 256, 0, stream>>>(vw, Wtkqv, 128, 128,
            (size_t)128 * 128, (size_t)384 * 128, 256);
        wprep_kernel<<<g, 256, 0, stream>>>(aw, Wtaw, 128, 128,
            (size_t)128 * 128, (size_t)128 * 128, 0);
        wprep_kernel<<<dim3(4, 4, 1), 256, 0, stream>>>(w_in, Wtin, 128, 128,
            0, 0, 0);
        wprep_kernel<<<dim3(4, 3, 1), 256, 0, stream>>>(w_out, Wtout, 128, OUTN,
            0, 0, 0);
        biaspack_kernel<<<(6 * 384 + 255) / 256, 256, 0, stream>>>(kbias, qbias, vbias, bkqv);
    }

    // ---- batched CSR build ----
    {
        const int NB = (NTOT + 1023) / 1024;
        hipMemsetAsync(deg, 0, (size_t)NTOT * 4, stream);
        hist4_kernel<<<dim3(64, 4), 256, 0, stream>>>(
            edst[0], edst[1], edst[2], edst[3], deg);
        scanA_kernel<<<NB, 256, 0, stream>>>(deg, part, NTOT);
        scanB_kernel<<<1, 128, 0, stream>>>(part, NB);
        scanC_kernel<<<NB, 256, 0, stream>>>(deg, part,
            rowptr[0], rowptr[1], rowptr[2], rowptr[3], cursor, NTOT);
        scatter_pack_kernel<<<dim3(64, 4), 256, 0, stream>>>(
            esrc[0], edst[0], esrc[1], edst[1], esrc[2], edst[2], esrc[3], edst[3],
            cursor, esbig);
    }

    // ---- input projections ----
    gemm(x_patient, 1, 128, Wtin, b_in, xb[0], 0, 128, NPAT, 128, 1, nullptr, 0, nullptr, 0);
    gather_relu_kernel<<<(NICD * CDIM + 255) / 256, 256, 0, stream>>>(emb_icd, x_icd, xb[1], NICD);
    gather_relu_kernel<<<(NNDC * CDIM + 255) / 256, 256, 0, stream>>>(emb_ndc, x_ndc, xb[2], NNDC);

    // ---- layers ----
    for (int l = 0; l < NLAYER; l++) {
        for (int t = 0; t < 3; t++) {
            int wi = l * 3 + t;
            gemm(xb[t], 0, 128, Wtkqv + (size_t)wi * 384 * 128, bkqv + (size_t)wi * 384,
                 kqv[t], 0, 384, sizes[t], 384, 0, nullptr, 0, nullptr, 0);
        }
        hipMemsetAsync(aggbase, 0, (size_t)(NPAT + NICD + NNDC) * CDIM * 4, stream);
        for (int r = 0; r < 4; r++) {
            int s = st_[r], d = dt_[r];
            int ns = sizes[s], nd = sizes[d];
            int grid_rt = min((ns + 1) / 2, 2048);
            rel_transform_kernel<<<dim3(grid_rt, 2), 256, 0, stream>>>(
                kqv[s], a_rel + (size_t)(l * 4 + r) * 2048,
                m_rel + (size_t)(l * 4 + r) * 2048, krbuf, vrbuf, ns);
            if (d == 0) {
                edge_softmax_agg_kernel<<<(nd + 3) / 4, 256, 0, stream>>>(
                    rowptr[r], esRel[r], kqv[d] + 128, 384, krbuf, vrbuf,
                    p_rel + (size_t)(l * 4 + r) * NHEAD, agg[d], nd);
            } else {
                edge_logits_kernel<<<(NEDGE * NHEAD + 255) / 256, 256, 0, stream>>>(
                    esRel[r], kqv[d] + 128, 384, krbuf,
                    p_rel + (size_t)(l * 4 + r) * NHEAD, alphabuf);
                seg_stats_kernel<<<(nd + 3) / 4, 256, 0, stream>>>(
                    rowptr[r], alphabuf, statsbuf, nd);
                seg_agg_kernel<<<(NEDGE + EPB - 1) / EPB, 128, 0, stream>>>(
                    esRel[r], alphabuf, statsbuf, vrbuf, agg[d], NEDGE);
            }
        }
        for (int t = 0; t < 3; t++) {
            int wi = l * 3 + t;
            gemm(agg[t], 2, 128, Wtaw + (size_t)wi * 128 * 128, abias + (size_t)wi * 128,
                 xb[t], 0, 128, sizes[t], 128, 0, xb[t], 128, skip, wi);
        }
    }

    // ---- output head (fp32 out) ----
    gemm(xb[0], 0, 128, Wtout, b_out, d_out, 1, OUTN, NPAT, OUTN, 2, nullptr, 0, nullptr, 0);
}

// Round 11
// 826.996 us; speedup vs baseline: 2.3087x; 1.1780x over previous
//
#include <hip/hip_runtime.h>
#include <math.h>

#define CDIM  128
#define NHEAD 8
#define DHEAD 16
#define NPAT  50000
#define NICD  591
#define NNDC  2042
#define OUTN  90
#define NEDGE 250000
#define NLAYER 2
#define EPB   64

// concat offsets for CSR build (relation order: pi, ip, pn, np; dst sizes)
#define OFF0  0
#define OFF1  (NICD)
#define OFF2  (NICD + NPAT)
#define OFF3  (NICD + NPAT + NNDC)
#define NTOT  (NICD + NPAT + NNDC + NPAT)

#define LDP 40   // GEMM LDS row stride (bf16 elems)

typedef __attribute__((ext_vector_type(8))) short bf16x8;
typedef __attribute__((ext_vector_type(4))) float f32x4;

__device__ __forceinline__ float gelu_tanh(float x) {
    float x3 = x * x * x;
    return 0.5f * x * (1.0f + tanhf(0.7978845608028654f * (x + 0.044715f * x3)));
}
__device__ __forceinline__ float b2f(unsigned short u) {
    union { unsigned int i; float f; } v; v.i = ((unsigned int)u) << 16; return v.f;
}
__device__ __forceinline__ unsigned short f2b(float f) {
    union { float ff; unsigned int i; } v; v.ff = f;
    unsigned int i = v.i;
    return (unsigned short)((i + 0x7FFFu + ((i >> 16) & 1u)) >> 16);  // RNE
}
__device__ __forceinline__ float2 b2x2(unsigned int u) {
    union { unsigned int i; float f; } lo, hi;
    lo.i = u << 16; hi.i = u & 0xFFFF0000u;
    return make_float2(lo.f, hi.f);
}

// ---------------------------------------------------------------------------
// bf16 MFMA GEMM: D = act(A @ Wt^T + bias), Wt [N][128] bf16.
// ---------------------------------------------------------------------------
__global__ __launch_bounds__(256) void gemm_mfma(
    const void* __restrict__ Ap, int a_mode, int lda,
    const unsigned short* __restrict__ Wt, const float* __restrict__ bias,
    void* __restrict__ Cp, int c_mode, int ldc,
    int M, int N, int act,
    const unsigned short* __restrict__ xold, int ldx,
    const float* __restrict__ skipv, int skipidx)
{
    __shared__ unsigned short Al[64 * LDP];
    __shared__ unsigned short Bl[64 * LDP];
    int bm = blockIdx.x * 64, bn = blockIdx.y * 64;
    int t = threadIdx.x;
    int lane = t & 63, w = t >> 6;
    int wr = w >> 1, wc = w & 1;
    int quad = lane >> 4, lm = lane & 15;
    f32x4 acc[2][2] = {};
    const int srow = t >> 2;
    const int skq  = (t & 3) * 8;

    for (int k0 = 0; k0 < 128; k0 += 32) {
        {
            int row = bm + srow;
            uint4 u = make_uint4(0, 0, 0, 0);
            if (a_mode == 0) {
                if (row < M)
                    u = *(const uint4*)((const unsigned short*)Ap + (size_t)row * lda + k0 + skq);
            } else {
                float f[8] = {0.f,0.f,0.f,0.f,0.f,0.f,0.f,0.f};
                if (row < M) {
                    const float4* ap = (const float4*)((const float*)Ap + (size_t)row * lda + k0 + skq);
                    float4 u0 = ap[0], u1 = ap[1];
                    f[0]=u0.x; f[1]=u0.y; f[2]=u0.z; f[3]=u0.w;
                    f[4]=u1.x; f[5]=u1.y; f[6]=u1.z; f[7]=u1.w;
                    if (a_mode == 2)
                        for (int i = 0; i < 8; i++) f[i] = gelu_tanh(f[i]);
                }
                unsigned short v[8];
                for (int i = 0; i < 8; i++) v[i] = f2b(f[i]);
                u = *(uint4*)v;
            }
            *(uint4*)&Al[srow * LDP + skq] = u;
        }
        {
            int n = bn + srow;
            uint4 u = make_uint4(0, 0, 0, 0);
            if (n < N) u = *(const uint4*)(Wt + (size_t)n * 128 + k0 + skq);
            *(uint4*)&Bl[srow * LDP + skq] = u;
        }
        __syncthreads();
        bf16x8 af[2], bfr[2];
        #pragma unroll
        for (int i = 0; i < 2; i++) {
            af[i]  = *(const bf16x8*)&Al[(wr * 32 + i * 16 + lm) * LDP + quad * 8];
            bfr[i] = *(const bf16x8*)&Bl[(wc * 32 + i * 16 + lm) * LDP + quad * 8];
        }
        acc[0][0] = __builtin_amdgcn_mfma_f32_16x16x32_bf16(af[0], bfr[0], acc[0][0], 0, 0, 0);
        acc[0][1] = __builtin_amdgcn_mfma_f32_16x16x32_bf16(af[0], bfr[1], acc[0][1], 0, 0, 0);
        acc[1][0] = __builtin_amdgcn_mfma_f32_16x16x32_bf16(af[1], bfr[0], acc[1][0], 0, 0, 0);
        acc[1][1] = __builtin_amdgcn_mfma_f32_16x16x32_bf16(af[1], bfr[1], acc[1][1], 0, 0, 0);
        __syncthreads();
    }

    float aSk = 0.f, oneM = 0.f;
    if (skipv) {
        float sv = skipv[skipidx];
        aSk = 1.0f / (1.0f + expf(-sv));
        oneM = 1.0f - aSk;
    }
    #pragma unroll
    for (int tm = 0; tm < 2; tm++)
    #pragma unroll
    for (int tn = 0; tn < 2; tn++)
    #pragma unroll
    for (int r = 0; r < 4; r++) {
        int row = bm + wr * 32 + tm * 16 + quad * 4 + r;
        int col = bn + wc * 32 + tn * 16 + lm;
        if (row >= M || col >= N) continue;
        float v = acc[tm][tn][r] + (bias ? bias[col] : 0.f);
        if (act == 1) v = fmaxf(v, 0.f);
        else if (act == 2) v = 1.0f / (1.0f + expf(-v));
        if (skipv) v = aSk * v + oneM * b2f(xold[(size_t)row * ldx + col]);
        if (c_mode == 0) ((unsigned short*)Cp)[(size_t)row * ldc + col] = f2b(v);
        else             ((float*)Cp)[(size_t)row * ldc + col] = v;
    }
}

// ---------------------------------------------------------------------------
// Weight prep: transpose+convert fp32 [g][K][N] -> bf16 [n+nofs][128]
// ---------------------------------------------------------------------------
__global__ __launch_bounds__(256) void wprep_kernel(
    const float* __restrict__ src, unsigned short* __restrict__ dst,
    int K, int N, size_t sstride, size_t gstride, int nofs)
{
    __shared__ float tile[32][33];
    int g = blockIdx.z;
    int k0 = blockIdx.x * 32, n0 = blockIdx.y * 32;
    int tx = threadIdx.x & 31, ty = threadIdx.x >> 5;
    const float* s = src + (size_t)g * sstride;
    for (int i = 0; i < 32; i += 8) {
        int k = k0 + ty + i, n = n0 + tx;
        tile[ty + i][tx] = (k < K && n < N) ? s[(size_t)k * N + n] : 0.f;
    }
    __syncthreads();
    unsigned short* d = dst + (size_t)g * gstride;
    for (int i = 0; i < 32; i += 8) {
        int n = n0 + ty + i, k = k0 + tx;
        if (n < N && k < K) d[(size_t)(n + nofs) * 128 + k] = f2b(tile[tx][ty + i]);
    }
}

// ---------------------------------------------------------------------------
// Composed relation weights: dst[n][k] = sum_d W[k][h*16+d] * A[h][d][e]
// (n = h*16+e), plus composed bias. 16 blocks = (layer, slot).
// Slots per layer: 0..3 -> Wb0 rows 128/256/384/512 (kr0,vr0,kr2,vr2);
// 4,5 -> Wb1 rows 128/256 (kr1,vr1); 6,7 -> Wb2 rows 128/256 (kr3,vr3).
// ---------------------------------------------------------------------------
__global__ __launch_bounds__(256) void wcomp_kernel(
    const float* __restrict__ kw, const float* __restrict__ vw,
    const float* __restrict__ a_rel, const float* __restrict__ m_rel,
    const float* __restrict__ kb, const float* __restrict__ vb,
    unsigned short* __restrict__ Wb0, unsigned short* __restrict__ Wb1,
    unsigned short* __restrict__ Wb2,
    float* __restrict__ bb0, float* __restrict__ bb1, float* __restrict__ bb2)
{
    int s = blockIdx.x;
    int l = s >> 3, j = s & 7;
    int t, isV, r, rowoff, nw;
    unsigned short* Wb; float* bb;
    switch (j) {
      case 0: t=0; isV=0; r=0; Wb=Wb0; bb=bb0; rowoff=128; nw=640; break;
      case 1: t=0; isV=1; r=0; Wb=Wb0; bb=bb0; rowoff=256; nw=640; break;
      case 2: t=0; isV=0; r=2; Wb=Wb0; bb=bb0; rowoff=384; nw=640; break;
      case 3: t=0; isV=1; r=2; Wb=Wb0; bb=bb0; rowoff=512; nw=640; break;
      case 4: t=1; isV=0; r=1; Wb=Wb1; bb=bb1; rowoff=128; nw=384; break;
      case 5: t=1; isV=1; r=1; Wb=Wb1; bb=bb1; rowoff=256; nw=384; break;
      case 6: t=2; isV=0; r=3; Wb=Wb2; bb=bb2; rowoff=128; nw=384; break;
      default:t=2; isV=1; r=3; Wb=Wb2; bb=bb2; rowoff=256; nw=384; break;
    }
    const float* W = (isV ? vw : kw) + (size_t)(l * 3 + t) * 16384;
    const float* A = (isV ? m_rel : a_rel) + (size_t)(l * 4 + r) * 2048;
    const float* B = (isV ? vb : kb) + (size_t)(l * 3 + t) * 128;
    unsigned short* dst = Wb + (size_t)l * nw * 128 + (size_t)rowoff * 128;
    float* bdst = bb + (size_t)l * nw + rowoff;
    int n = threadIdx.x & 127;
    int kh = threadIdx.x >> 7;
    int h = n >> 4, e = n & 15;
    float Ar[16];
    #pragma unroll
    for (int d = 0; d < 16; d++) Ar[d] = A[h * 256 + d * 16 + e];
    for (int k = kh * 64; k < kh * 64 + 64; k++) {
        float acc = 0.f;
        const float* wr = W + (size_t)k * 128 + h * 16;
        #pragma unroll
        for (int d = 0; d < 16; d++) acc += wr[d] * Ar[d];
        dst[(size_t)n * 128 + k] = f2b(acc);
    }
    if (kh == 0) {
        float acc = 0.f;
        const float* br = B + h * 16;
        #pragma unroll
        for (int d = 0; d < 16; d++) acc += br[d] * Ar[d];
        bdst[n] = acc;
    }
}

__global__ void biasq_kernel(const float* __restrict__ qb,
                             float* __restrict__ bb0, float* __restrict__ bb1,
                             float* __restrict__ bb2) {
    int t = blockIdx.x * blockDim.x + threadIdx.x;
    if (t >= 6 * 128) return;
    int g = t >> 7, c = t & 127;
    int l = g / 3, ty = g % 3;
    float v = qb[g * 128 + c];
    if (ty == 0) bb0[l * 640 + c] = v;
    else if (ty == 1) bb1[l * 384 + c] = v;
    else bb2[l * 384 + c] = v;
}

// ---------------------------------------------------------------------------
// Histogram: grid (64, 4). icd/ndc relations pre-aggregate in LDS.
// ---------------------------------------------------------------------------
__global__ __launch_bounds__(256) void hist4_kernel(
    const int* __restrict__ d0, const int* __restrict__ d1,
    const int* __restrict__ d2, const int* __restrict__ d3,
    int* __restrict__ deg)
{
    __shared__ int lh[2048];
    int rel = blockIdx.y;
    int t = threadIdx.x;
    const int* dp = (rel == 0) ? d0 : (rel == 1) ? d1 : (rel == 2) ? d2 : d3;
    int off = (rel == 0) ? OFF0 : (rel == 1) ? OFF1 : (rel == 2) ? OFF2 : OFF3;
    if (rel == 1 || rel == 3) {
        for (int e = blockIdx.x * 256 + t; e < NEDGE; e += gridDim.x * 256)
            atomicAdd(&deg[off + dp[e]], 1);
    } else {
        int nb = (rel == 0) ? NICD : NNDC;
        for (int i = t; i < nb; i += 256) lh[i] = 0;
        __syncthreads();
        for (int e = blockIdx.x * 256 + t; e < NEDGE; e += gridDim.x * 256)
            atomicAdd(&lh[dp[e]], 1);
        __syncthreads();
        for (int i = t; i < nb; i += 256) {
            int v = lh[i];
            if (v) atomicAdd(&deg[off + i], v);
        }
    }
}

__global__ __launch_bounds__(256) void scanA_kernel(
    const int* __restrict__ deg, int* __restrict__ part, int n)
{
    __shared__ int red[256];
    int b = blockIdx.x, t = threadIdx.x;
    int base = b * 1024 + t * 4;
    int s = 0;
    if (base + 3 < n) {
        int4 v = *(const int4*)(deg + base);
        s = v.x + v.y + v.z + v.w;
    } else {
        for (int i = 0; i < 4; i++) if (base + i < n) s += deg[base + i];
    }
    red[t] = s;
    __syncthreads();
    for (int o = 128; o; o >>= 1) { if (t < o) red[t] += red[t + o]; __syncthreads(); }
    if (t == 0) part[b] = red[0];
}

__global__ __launch_bounds__(128) void scanB_kernel(int* __restrict__ part, int nb)
{
    __shared__ int s[256];
    int t = threadIdx.x;
    for (int i = t; i < nb; i += 128) s[i] = part[i];
    __syncthreads();
    if (t == 0) { int run = 0; for (int i = 0; i < nb; i++) { int v = s[i]; s[i] = run; run += v; } }
    __syncthreads();
    for (int i = t; i < nb; i += 128) part[i] = s[i];
}

__global__ __launch_bounds__(256) void scanC_kernel(
    const int* __restrict__ deg, const int* __restrict__ part,
    int* __restrict__ rp0, int* __restrict__ rp1,
    int* __restrict__ rp2, int* __restrict__ rp3,
    int* __restrict__ cursor, int n)
{
    __shared__ int red[256];
    int b = blockIdx.x, t = threadIdx.x;
    int base = b * 1024 + t * 4;
    int v[4] = {0, 0, 0, 0};
    if (base + 3 < n) {
        int4 q = *(const int4*)(deg + base);
        v[0] = q.x; v[1] = q.y; v[2] = q.z; v[3] = q.w;
    } else {
        for (int i = 0; i < 4; i++) if (base + i < n) v[i] = deg[base + i];
    }
    red[t] = v[0] + v[1] + v[2] + v[3];
    __syncthreads();
    for (int off = 1; off < 256; off <<= 1) {
        int y = (t >= off) ? red[t - off] : 0;
        __syncthreads();
        red[t] += y;
        __syncthreads();
    }
    int run = part[b] + ((t == 0) ? 0 : red[t - 1]);
    for (int i = 0; i < 4; i++) {
        int g = base + i;
        if (g < n) {
            cursor[g] = run;
            int r, loc;
            if      (g < OFF1) { r = 0; loc = g; }
            else if (g < OFF2) { r = 1; loc = g - OFF1; }
            else if (g < OFF3) { r = 2; loc = g - OFF2; }
            else               { r = 3; loc = g - OFF3; }
            int Sl = run - r * NEDGE;
            ((r == 0) ? rp0 : (r == 1) ? rp1 : (r == 2) ? rp2 : rp3)[loc] = Sl;
            run += v[i];
        }
    }
    if (b == 0 && t == 0) {
        rp0[NICD] = NEDGE; rp1[NPAT] = NEDGE; rp2[NNDC] = NEDGE; rp3[NPAT] = NEDGE;
    }
}

// ---------------------------------------------------------------------------
// Scatter, grid (64, 4). Patient relations: plain. icd/ndc: LDS reservation.
// ---------------------------------------------------------------------------
__global__ __launch_bounds__(256) void scatter_pack_kernel(
    const int* __restrict__ s0, const int* __restrict__ d0,
    const int* __restrict__ s1, const int* __restrict__ d1,
    const int* __restrict__ s2, const int* __restrict__ d2,
    const int* __restrict__ s3, const int* __restrict__ d3,
    int* __restrict__ cursor, unsigned int* __restrict__ es)
{
    __shared__ int lcnt[2048];
    __shared__ int lbase[2048];
    int rel = blockIdx.y;
    int t = threadIdx.x;
    const int* sp = (rel == 0) ? s0 : (rel == 1) ? s1 : (rel == 2) ? s2 : s3;
    const int* dp = (rel == 0) ? d0 : (rel == 1) ? d1 : (rel == 2) ? d2 : d3;
    int off = (rel == 0) ? OFF0 : (rel == 1) ? OFF1 : (rel == 2) ? OFF2 : OFF3;
    if (rel == 1 || rel == 3) {
        for (int e = blockIdx.x * 256 + t; e < NEDGE; e += gridDim.x * 256) {
            int d = dp[e];
            int p = atomicAdd(&cursor[off + d], 1);
            es[p] = ((unsigned int)sp[e] << 16) | (unsigned int)d;
        }
    } else {
        int nb = (rel == 0) ? NICD : NNDC;
        int per = (NEDGE + gridDim.x - 1) / gridDim.x;
        int e0 = blockIdx.x * per, e1 = min(e0 + per, NEDGE);
        for (int i = t; i < nb; i += 256) lcnt[i] = 0;
        __syncthreads();
        for (int e = e0 + t; e < e1; e += 256) atomicAdd(&lcnt[dp[e]], 1);
        __syncthreads();
        for (int i = t; i < nb; i += 256) {
            int c = lcnt[i];
            lbase[i] = c ? atomicAdd(&cursor[off + i], c) : 0;
            lcnt[i] = 0;
        }
        __syncthreads();
        for (int e = e0 + t; e < e1; e += 256) {
            int d = dp[e];
            int p = lbase[d] + atomicAdd(&lcnt[d], 1);
            es[p] = ((unsigned int)sp[e] << 16) | (unsigned int)d;
        }
    }
}

// ---------------------------------------------------------------------------
// x = relu(emb[idx]) gather -> bf16
// ---------------------------------------------------------------------------
__global__ void gather_relu_kernel(const float* __restrict__ emb,
                                   const int* __restrict__ idx,
                                   unsigned short* __restrict__ out, int n) {
    int t = blockIdx.x * blockDim.x + threadIdx.x;
    if (t < n * CDIM) {
        int r = t >> 7, c = t & 127;
        out[t] = f2b(fmaxf(emb[(size_t)idx[r] * CDIM + c], 0.f));
    }
}

__device__ __forceinline__ float dot16_bf(const unsigned short* a,
                                          const unsigned short* b) {
    const uint4* ap = (const uint4*)a;
    const uint4* bp = (const uint4*)b;
    uint4 a0 = ap[0], a1 = ap[1], b0 = bp[0], b1 = bp[1];
    unsigned int au[8] = {a0.x, a0.y, a0.z, a0.w, a1.x, a1.y, a1.z, a1.w};
    unsigned int bu[8] = {b0.x, b0.y, b0.z, b0.w, b1.x, b1.y, b1.z, b1.w};
    float acc = 0.f;
    #pragma unroll
    for (int j = 0; j < 8; j++) {
        float2 x = b2x2(au[j]), y = b2x2(bu[j]);
        acc += x.x * y.x + x.y * y.y;
    }
    return acc;
}

// ---------------------------------------------------------------------------
// Per-edge logits (icd/ndc-dst path); kr lives inside the wide P0 buffer.
// ---------------------------------------------------------------------------
__global__ __launch_bounds__(256) void edge_logits_kernel(
    const unsigned int* __restrict__ es,
    const unsigned short* __restrict__ q, int ldq,
    const unsigned short* __restrict__ kr, int ldk,
    const float* __restrict__ prel, float* __restrict__ alpha_s)
{
    int t = blockIdx.x * blockDim.x + threadIdx.x;
    if (t >= NEDGE * NHEAD) return;
    int i = t >> 3, h = t & 7;
    unsigned int ed = es[i];
    int dn = ed & 0xFFFFu, sn = ed >> 16;
    float acc = dot16_bf(q + (size_t)dn * ldq + h * DHEAD,
                         kr + (size_t)sn * ldk + h * DHEAD);
    alpha_s[t] = acc * prel[h] * 0.25f;
}

__global__ __launch_bounds__(256) void seg_stats_kernel(
    const int* __restrict__ rowptr, const float* __restrict__ alpha_s,
    float2* __restrict__ stats, int nd)
{
    int wid = (blockIdx.x * 256 + threadIdx.x) >> 6;
    int lane = threadIdx.x & 63;
    if (wid >= nd) return;
    int r0 = rowptr[wid], r1 = rowptr[wid + 1];
    int h = lane & 7, j = lane >> 3;
    float mx = -1e30f;
    for (int i = r0 + j; i < r1; i += 8)
        mx = fmaxf(mx, alpha_s[(size_t)i * NHEAD + h]);
    mx = fmaxf(mx, __shfl_xor(mx, 8));
    mx = fmaxf(mx, __shfl_xor(mx, 16));
    mx = fmaxf(mx, __shfl_xor(mx, 32));
    float sm = 0.f;
    for (int i = r0 + j; i < r1; i += 8)
        sm += expf(alpha_s[(size_t)i * NHEAD + h] - mx);
    sm += __shfl_xor(sm, 8);
    sm += __shfl_xor(sm, 16);
    sm += __shfl_xor(sm, 32);
    if (j == 0)
        stats[(size_t)wid * NHEAD + h] = make_float2(mx, (sm > 0.f) ? 1.0f / sm : 0.f);
}

// ---------------------------------------------------------------------------
// FUSED patient-dst path for BOTH relations (icd->pat, ndc->pat): one wave
// per patient computes logits+softmax+aggregation for each relation's segment
// and does a single PURE STORE of agg[0] (sole owner -> no memset, no RMW).
// ---------------------------------------------------------------------------
__global__ __launch_bounds__(256) void edge_softmax_agg2_kernel(
    const int* __restrict__ rp1, const unsigned int* __restrict__ es1,
    const int* __restrict__ rp3, const unsigned int* __restrict__ es3,
    const unsigned short* __restrict__ q, int ldq,
    const unsigned short* __restrict__ kr1, const unsigned short* __restrict__ vr1, int ld1,
    const unsigned short* __restrict__ kr3, const unsigned short* __restrict__ vr3, int ld3,
    const float* __restrict__ prel1, const float* __restrict__ prel3,
    float* __restrict__ agg, int nd)
{
    __shared__ float wls[4][64 * NHEAD];   // 8 KB
    int wv  = threadIdx.x >> 6;
    int wid = (blockIdx.x * 256 + threadIdx.x) >> 6;
    int lane = threadIdx.x & 63;
    if (wid >= nd) return;
    float* wl = wls[wv];
    int h = lane & 7, j = lane >> 3;
    int hc = lane >> 3;
    const unsigned short* qbase = q + (size_t)wid * ldq;
    float acc0 = 0.f, acc1 = 0.f;

    #pragma unroll
    for (int rr = 0; rr < 2; rr++) {
        const int* rp = rr ? rp3 : rp1;
        const unsigned int* es = rr ? es3 : es1;
        const unsigned short* kr = rr ? kr3 : kr1;
        const unsigned short* vr = rr ? vr3 : vr1;
        int ld = rr ? ld3 : ld1;
        const float* prel = rr ? prel3 : prel1;
        int r0 = rp[wid], r1 = rp[wid + 1];
        int deg = r1 - r0;
        if (deg <= 0) continue;
        const unsigned short* qrow = qbase + h * DHEAD;
        float ph = prel[h] * 0.25f;
        bool small = (deg <= 64);

        float m = -1e30f;
        for (int i = j; i < deg; i += 8) {
            int sn = es[r0 + i] >> 16;
            float a = dot16_bf(qrow, kr + (size_t)sn * ld + h * DHEAD) * ph;
            if (small) wl[i * NHEAD + h] = a;
            m = fmaxf(m, a);
        }
        m = fmaxf(m, __shfl_xor(m, 8));
        m = fmaxf(m, __shfl_xor(m, 16));
        m = fmaxf(m, __shfl_xor(m, 32));
        float s = 0.f;
        for (int i = j; i < deg; i += 8) {
            float a;
            if (small) a = wl[i * NHEAD + h];
            else {
                int sn = es[r0 + i] >> 16;
                a = dot16_bf(qrow, kr + (size_t)sn * ld + h * DHEAD) * ph;
            }
            float e = expf(a - m);
            if (small) wl[i * NHEAD + h] = e;
            s += e;
        }
        s += __shfl_xor(s, 8);
        s += __shfl_xor(s, 16);
        s += __shfl_xor(s, 32);
        float si = (s > 0.f) ? 1.0f / s : 0.f;
        if (small)
            for (int i = j; i < deg; i += 8)
                wl[i * NHEAD + h] *= si;

        float m_hc  = __shfl(m, hc);
        float si_hc = __shfl(si, hc);
        float ph_hc = __shfl(ph, hc);
        const unsigned short* qrow_hc = qbase + hc * DHEAD;
        for (int i = 0; i < deg; i++) {
            unsigned int sv = es[r0 + i] >> 16;
            unsigned int pv = *(const unsigned int*)(vr + (size_t)sv * ld + 2 * lane);
            float2 v = b2x2(pv);
            float wgt;
            if (small) wgt = wl[i * NHEAD + hc];
            else {
                float a = dot16_bf(qrow_hc, kr + (size_t)sv * ld + hc * DHEAD) * ph_hc;
                wgt = expf(a - m_hc) * si_hc;
            }
            acc0 += wgt * v.x;
            acc1 += wgt * v.y;
        }
    }
    float2* ap = (float2*)(agg + (size_t)wid * CDIM + 2 * lane);
    *ap = make_float2(acc0, acc1);
}

// ---------------------------------------------------------------------------
// Edge-chunk weighted segment sum — stats variant (icd/ndc-dst path)
// ---------------------------------------------------------------------------
__global__ __launch_bounds__(128) void seg_agg_kernel(
    const unsigned int* __restrict__ es,
    const float* __restrict__ alpha_s, const float2* __restrict__ stats,
    const unsigned short* __restrict__ vr, int ldv,
    float* __restrict__ agg, int ne)
{
    __shared__ unsigned int sE[EPB];
    __shared__ float sW[EPB][NHEAD + 1];
    int i0 = blockIdx.x * EPB;
    int t  = threadIdx.x;
    int cnt = min(EPB, ne - i0);
    if (t < cnt) {
        unsigned int ed = es[i0 + t];
        sE[t] = ed;
        int dn = ed & 0xFFFFu;
        const float4* ap = (const float4*)(alpha_s + (size_t)(i0 + t) * NHEAD);
        float4 a0 = ap[0], a1 = ap[1];
        float wv[8] = {a0.x, a0.y, a0.z, a0.w, a1.x, a1.y, a1.z, a1.w};
        const float2* st = stats + (size_t)dn * NHEAD;
        #pragma unroll
        for (int h = 0; h < NHEAD; h++) {
            float2 ms = st[h];
            sW[t][h] = expf(wv[h] - ms.x) * ms.y;
        }
    }
    __syncthreads();
    int h = t >> 4;
    float acc = 0.f;
    int curd = (int)(sE[0] & 0xFFFFu);
    for (int i = 0; i < cnt; i++) {
        unsigned int ed = sE[i];
        int d = (int)(ed & 0xFFFFu);
        if (d != curd) {
            atomicAdd(&agg[(size_t)curd * CDIM + t], acc);
            acc = 0.f;
            curd = d;
        }
        acc += b2f(vr[(size_t)(ed >> 16) * ldv + t]) * sW[i][h];
    }
    atomicAdd(&agg[(size_t)curd * CDIM + t], acc);
}

// ---------------------------------------------------------------------------
extern "C" void kernel_launch(void* const* d_in, const int* in_sizes, int n_in,
                              void* d_out, int out_size, void* d_ws, size_t ws_size,
                              hipStream_t stream)
{
    const float* x_patient = (const float*)d_in[0];
    const float* w_in      = (const float*)d_in[1];
    const float* b_in      = (const float*)d_in[2];
    const float* emb_icd   = (const float*)d_in[3];
    const float* emb_ndc   = (const float*)d_in[4];
    const float* kw        = (const float*)d_in[5];
    const float* kbias     = (const float*)d_in[6];
    const float* qw        = (const float*)d_in[7];
    const float* qbias     = (const float*)d_in[8];
    const float* vw        = (const float*)d_in[9];
    const float* vbias     = (const float*)d_in[10];
    const float* aw        = (const float*)d_in[11];
    const float* abias     = (const float*)d_in[12];
    const float* skip      = (const float*)d_in[13];
    const float* a_rel     = (const float*)d_in[14];
    const float* m_rel     = (const float*)d_in[15];
    const float* p_rel     = (const float*)d_in[16];
    const float* w_out     = (const float*)d_in[17];
    const float* b_out     = (const float*)d_in[18];
    const int*   x_icd     = (const int*)d_in[19];
    const int*   x_ndc     = (const int*)d_in[20];
    const int* esrc[4] = {(const int*)d_in[21], (const int*)d_in[23],
                          (const int*)d_in[25], (const int*)d_in[27]};
    const int* edst[4] = {(const int*)d_in[22], (const int*)d_in[24],
                          (const int*)d_in[26], (const int*)d_in[28]};

    const int sizes[3] = {NPAT, NICD, NNDC};

    char* p = (char*)d_ws;
    auto alloc = [&](size_t bytes) -> void* {
        void* r = (void*)p;
        p += (bytes + 255) & ~(size_t)255;
        return r;
    };

    unsigned short *xb[3];
    for (int t = 0; t < 3; t++) xb[t] = (unsigned short*)alloc((size_t)sizes[t] * CDIM * 2);
    // wide projection buffers: P0 [NPAT][640] = q|kr0|vr0|kr2|vr2; P1/P2 [n][384] = q|kr|vr
    unsigned short* P0 = (unsigned short*)alloc((size_t)NPAT * 640 * 2);
    unsigned short* P1 = (unsigned short*)alloc((size_t)NICD * 384 * 2);
    unsigned short* P2 = (unsigned short*)alloc((size_t)NNDC * 384 * 2);
    float* aggbase = (float*)alloc((size_t)(NPAT + NICD + NNDC) * CDIM * 4);
    float* agg[3];
    agg[0] = aggbase;
    agg[1] = aggbase + (size_t)NPAT * CDIM;
    agg[2] = agg[1] + (size_t)NICD * CDIM;
    float*  alphabuf = (float*)alloc((size_t)NEDGE * NHEAD * 4);
    float2* statsbuf = (float2*)alloc((size_t)NNDC * NHEAD * 8);
    unsigned int* esbig = (unsigned int*)alloc((size_t)4 * NEDGE * 4);
    int* rowptr[4];
    rowptr[0] = (int*)alloc((size_t)(NICD + 1) * 4);
    rowptr[1] = (int*)alloc((size_t)(NPAT + 1) * 4);
    rowptr[2] = (int*)alloc((size_t)(NNDC + 1) * 4);
    rowptr[3] = (int*)alloc((size_t)(NPAT + 1) * 4);
    int* deg    = (int*)alloc((size_t)NTOT * 4);
    int* cursor = (int*)alloc((size_t)NTOT * 4);
    int* part   = (int*)alloc((size_t)256 * 4);
    // prepped weights
    unsigned short* Wb0   = (unsigned short*)alloc((size_t)2 * 640 * 128 * 2);
    unsigned short* Wb1   = (unsigned short*)alloc((size_t)2 * 384 * 128 * 2);
    unsigned short* Wb2   = (unsigned short*)alloc((size_t)2 * 384 * 128 * 2);
    unsigned short* Wtaw  = (unsigned short*)alloc((size_t)6 * 128 * 128 * 2);
    unsigned short* Wtin  = (unsigned short*)alloc((size_t)128 * 128 * 2);
    unsigned short* Wtout = (unsigned short*)alloc((size_t)OUTN * 128 * 2);
    float* bb0 = (float*)alloc((size_t)2 * 640 * 4);
    float* bb1 = (float*)alloc((size_t)2 * 384 * 4);
    float* bb2 = (float*)alloc((size_t)2 * 384 * 4);
    unsigned int* esRel[4];
    for (int r = 0; r < 4; r++) esRel[r] = esbig + (size_t)r * NEDGE;

    auto gemm = [&](const void* A, int a_mode, int lda,
                    const unsigned short* Wt, const float* bias,
                    void* C, int c_mode, int ldc, int M, int N, int act,
                    const unsigned short* xold, int ldx,
                    const float* skipv, int skipidx) {
        dim3 grid((M + 63) / 64, (N + 63) / 64);
        gemm_mfma<<<grid, dim3(256), 0, stream>>>(A, a_mode, lda, Wt, bias,
            C, c_mode, ldc, M, N, act, xold, ldx, skipv, skipidx);
    };

    // ---- weight prep ----
    {
        // q transposes into the wide weight blocks (rows 0..127)
        wprep_kernel<<<dim3(4, 4, 2), 256, 0, stream>>>(qw, Wb0, 128, 128,
            (size_t)3 * 16384, (size_t)640 * 128, 0);
        wprep_kernel<<<dim3(4, 4, 2), 256, 0, stream>>>(qw + 16384, Wb1, 128, 128,
            (size_t)3 * 16384, (size_t)384 * 128, 0);
        wprep_kernel<<<dim3(4, 4, 2), 256, 0, stream>>>(qw + 2 * 16384, Wb2, 128, 128,
            (size_t)3 * 16384, (size_t)384 * 128, 0);
        // composed kr/vr weights + biases
        wcomp_kernel<<<16, 256, 0, stream>>>(kw, vw, a_rel, m_rel, kbias, vbias,
            Wb0, Wb1, Wb2, bb0, bb1, bb2);
        biasq_kernel<<<3, 256, 0, stream>>>(qbias, bb0, bb1, bb2);
        // plain weights
        wprep_kernel<<<dim3(4, 4, 6), 256, 0, stream>>>(aw, Wtaw, 128, 128,
            (size_t)128 * 128, (size_t)128 * 128, 0);
        wprep_kernel<<<dim3(4, 4, 1), 256, 0, stream>>>(w_in, Wtin, 128, 128, 0, 0, 0);
        wprep_kernel<<<dim3(4, 3, 1), 256, 0, stream>>>(w_out, Wtout, 128, OUTN, 0, 0, 0);
    }

    // ---- batched CSR build ----
    {
        const int NB = (NTOT + 1023) / 1024;
        hipMemsetAsync(deg, 0, (size_t)NTOT * 4, stream);
        hist4_kernel<<<dim3(64, 4), 256, 0, stream>>>(
            edst[0], edst[1], edst[2], edst[3], deg);
        scanA_kernel<<<NB, 256, 0, stream>>>(deg, part, NTOT);
        scanB_kernel<<<1, 128, 0, stream>>>(part, NB);
        scanC_kernel<<<NB, 256, 0, stream>>>(deg, part,
            rowptr[0], rowptr[1], rowptr[2], rowptr[3], cursor, NTOT);
        scatter_pack_kernel<<<dim3(64, 4), 256, 0, stream>>>(
            esrc[0], edst[0], esrc[1], edst[1], esrc[2], edst[2], esrc[3], edst[3],
            cursor, esbig);
    }

    // ---- input projections ----
    gemm(x_patient, 1, 128, Wtin, b_in, xb[0], 0, 128, NPAT, 128, 1, nullptr, 0, nullptr, 0);
    gather_relu_kernel<<<(NICD * CDIM + 255) / 256, 256, 0, stream>>>(emb_icd, x_icd, xb[1], NICD);
    gather_relu_kernel<<<(NNDC * CDIM + 255) / 256, 256, 0, stream>>>(emb_ndc, x_ndc, xb[2], NNDC);

    // ---- layers ----
    for (int l = 0; l < NLAYER; l++) {
        // fused projection GEMMs (q + composed kr/vr per relation)
        gemm(xb[0], 0, 128, Wb0 + (size_t)l * 640 * 128, bb0 + (size_t)l * 640,
             P0, 0, 640, NPAT, 640, 0, nullptr, 0, nullptr, 0);
        gemm(xb[1], 0, 128, Wb1 + (size_t)l * 384 * 128, bb1 + (size_t)l * 384,
             P1, 0, 384, NICD, 384, 0, nullptr, 0, nullptr, 0);
        gemm(xb[2], 0, 128, Wb2 + (size_t)l * 384 * 128, bb2 + (size_t)l * 384,
             P2, 0, 384, NNDC, 384, 0, nullptr, 0, nullptr, 0);
        // only icd/ndc agg needs zeroing (patient agg is pure-stored)
        hipMemsetAsync(agg[1], 0, (size_t)(NICD + NNDC) * CDIM * 4, stream);

        // r=0: patient -> icd
        edge_logits_kernel<<<(NEDGE * NHEAD + 255) / 256, 256, 0, stream>>>(
            esRel[0], P1, 384, P0 + 128, 640,
            p_rel + (size_t)(l * 4 + 0) * NHEAD, alphabuf);
        seg_stats_kernel<<<(NICD + 3) / 4, 256, 0, stream>>>(
            rowptr[0], alphabuf, statsbuf, NICD);
        seg_agg_kernel<<<(NEDGE + EPB - 1) / EPB, 128, 0, stream>>>(
            esRel[0], alphabuf, statsbuf, P0 + 256, 640, agg[1], NEDGE);

        // r=2: patient -> ndc
        edge_logits_kernel<<<(NEDGE * NHEAD + 255) / 256, 256, 0, stream>>>(
            esRel[2], P2, 384, P0 + 384, 640,
            p_rel + (size_t)(l * 4 + 2) * NHEAD, alphabuf);
        seg_stats_kernel<<<(NNDC + 3) / 4, 256, 0, stream>>>(
            rowptr[2], alphabuf, statsbuf, NNDC);
        seg_agg_kernel<<<(NEDGE + EPB - 1) / EPB, 128, 0, stream>>>(
            esRel[2], alphabuf, statsbuf, P0 + 512, 640, agg[2], NEDGE);

        // r=1 + r=3 fused: icd->patient and ndc->patient, pure store
        edge_softmax_agg2_kernel<<<(NPAT + 3) / 4, 256, 0, stream>>>(
            rowptr[1], esRel[1], rowptr[3], esRel[3],
            P0, 640, P1 + 128, P1 + 256, 384, P2 + 128, P2 + 256, 384,
            p_rel + (size_t)(l * 4 + 1) * NHEAD, p_rel + (size_t)(l * 4 + 3) * NHEAD,
            agg[0], NPAT);

        // gelu + skip output projections
        for (int t = 0; t < 3; t++) {
            int wi = l * 3 + t;
            gemm(agg[t], 2, 128, Wtaw + (size_t)wi * 128 * 128, abias + (size_t)wi * 128,
                 xb[t], 0, 128, sizes[t], 128, 0, xb[t], 128, skip, wi);
        }
    }

    // ---- output head (fp32 out) ----
    gemm(xb[0], 0, 128, Wtout, b_out, d_out, 1, OUTN, NPAT, OUTN, 2, nullptr, 0, nullptr, 0);
}